// Round 1
// baseline (6785.561 us; speedup 1.0000x reference)
//
#include <hip/hip_runtime.h>
#include <stdint.h>

// SRTKAN v2: GRU recurrence restructured to eliminate the per-step cross-block LLC
// exchange (old srt_gru: 8 us/step, all latency). Input projections are precomputed
// as large parallel GEMMs (gi = x@Wih^T + bias, bf16); the sequential part keeps only
// h@Whh^T with Whh fully ON-CHIP per block (96 KB LDS + ~288 VGPR/lane of fragments),
// one block per 16-row batch group computing ALL 256 features -> the per-step exchange
// is a single intra-block LDS transpose + one barrier. Host picks T-chunking by
// ws_size; falls back to the old exchange kernel if the workspace is too small.

constexpr int B_  = 512;
constexpr int T_  = 512;
constexpr int IN_ = 128;
constexpr int H_  = 256;
constexpr int GR_ = 32;                   // batch groups (old path)
constexpr int PL_ = GR_ * 2 * 4096;       // elements per parity plane (old path)

typedef __attribute__((ext_vector_type(8))) short bf16x8;
typedef __attribute__((ext_vector_type(4))) float f32x4;

#define MFMA16(a, b, c) __builtin_amdgcn_mfma_f32_16x16x32_bf16((a), (b), (c), 0, 0, 0)

__device__ __forceinline__ float bf2f(unsigned short u){
    union { unsigned int i; float f; } v; v.i = ((unsigned int)u) << 16; return v.f;
}
__device__ __forceinline__ unsigned short f2bf(float f){
    union { float f; unsigned int i; } v; v.f = f;
    return (unsigned short)((v.i + 0x7FFFu + ((v.i >> 16) & 1u)) >> 16); // RNE
}
__device__ __forceinline__ float sig_(float x){
    return __builtin_amdgcn_rcpf(1.0f + __expf(-x));
}
__device__ __forceinline__ float tanh_(float x){
    return 1.0f - 2.0f * __builtin_amdgcn_rcpf(1.0f + __expf(2.0f * x));
}
__device__ __forceinline__ bf16x8 ldb8g(const unsigned short* p){ return *(const bf16x8*)p; }

union U64x2 { unsigned long long q[2]; bf16x8 v; };

__device__ __forceinline__ void gl2lds16(const void* g, void* l){
    __builtin_amdgcn_global_load_lds(
        (const __attribute__((address_space(1))) unsigned int*)g,
        (__attribute__((address_space(3))) unsigned int*)l, 16, 0, 0);
}

// ---------------------------------------------------------------------------
// dtype detect: low 16 bits of fp32 words of x. bf16-packed -> real bf16 exponents.
// ---------------------------------------------------------------------------
__global__ void srt_detect(const unsigned int* __restrict__ xw, unsigned int* __restrict__ flag){
    int cnt = 0;
    for (int i = threadIdx.x; i < 1024; i += 64){
        const unsigned int lo = xw[i] & 0xFFFFu;
        const int e = (int)((lo >> 7) & 0xFFu);
        if (e >= 100 && e <= 140) cnt++;
    }
    #pragma unroll
    for (int o = 32; o > 0; o >>= 1) cnt += __shfl_down(cnt, o);
    if (threadIdx.x == 0) *flag = (cnt > 614) ? 1u : 0u;   // 1 = bf16 inputs
}

// ---------------------------------------------------------------------------
// stage all weight/bias tensors as bf16 into d_ws (copy if bf16, RNE-convert if fp32)
// ---------------------------------------------------------------------------
struct ConvTab { const void* src[26]; int n[26]; int off[26]; };

__global__ __launch_bounds__(256) void srt_conv(ConvTab ct, unsigned short* __restrict__ wb,
                                                const unsigned int* __restrict__ flag){
    const bool isb = (*flag != 0);
    const int gsz = gridDim.x * blockDim.x;
    const int gid = blockIdx.x * blockDim.x + threadIdx.x;
    for (int j = 0; j < 26; ++j){
        const int n = ct.n[j];
        unsigned short* o = wb + ct.off[j];
        if (isb){
            const unsigned short* s = (const unsigned short*)ct.src[j];
            for (int i = gid; i < n; i += gsz) o[i] = s[i];
        } else {
            const float* s = (const float*)ct.src[j];
            for (int i = gid; i < n; i += gsz) o[i] = f2bf(s[i]);
        }
    }
}

// ---------------------------------------------------------------------------
// prep: zero h states + old-path seq counters; build folded gate biases:
// bias[n] = bih[n] + (n<512 ? bhh[n] : 0)   (bhh of n-gate stays with h-term)
// ---------------------------------------------------------------------------
__global__ __launch_bounds__(256) void srt_prep(
    float* __restrict__ h0s, float* __restrict__ h1s,
    float* __restrict__ bias0, float* __restrict__ bias1,
    const unsigned short* __restrict__ b0ih, const unsigned short* __restrict__ b0hh,
    const unsigned short* __restrict__ b1ih, const unsigned short* __restrict__ b1hh,
    unsigned int* __restrict__ seq)
{
    const int gid = blockIdx.x * blockDim.x + threadIdx.x;  // grid 512*256 = 131072
    h0s[gid] = 0.f;
    h1s[gid] = 0.f;
    if (gid < 768){
        bias0[gid] = bf2f(b0ih[gid]) + (gid < 512 ? bf2f(b0hh[gid]) : 0.f);
        bias1[gid] = bf2f(b1ih[gid]) + (gid < 512 ? bf2f(b1hh[gid]) : 0.f);
    }
    if (gid < 1024) seq[gid] = 0u;
}

// ---------------------------------------------------------------------------
// x -> bf16, chunk [t0, t0+TC): xb[b*TC+tc][128]
// ---------------------------------------------------------------------------
__global__ __launch_bounds__(256) void srt_xconv(
    const void* __restrict__ xv, unsigned short* __restrict__ xb,
    const unsigned int* __restrict__ flagp, const int t0, const int TC)
{
    const bool isb = (*flagp != 0);
    const int total = 512 * TC * 16;       // 16-byte granules
    const int per_b = TC * 16;
    const int gsz = gridDim.x * blockDim.x;
    for (int g_ = blockIdx.x * blockDim.x + threadIdx.x; g_ < total; g_ += gsz){
        const int b = g_ / per_b;
        const int rem = g_ - b * per_b;
        const long long s8 = ((long long)b * 512 + t0) * 16 + rem;
        bf16x8 v;
        if (isb){
            v = ((const bf16x8*)xv)[s8];
        } else {
            const float* p = (const float*)xv + s8 * 8;
            const float4 f0 = *(const float4*)p;
            const float4 f1 = *(const float4*)(p + 4);
            v[0] = (short)f2bf(f0.x); v[1] = (short)f2bf(f0.y);
            v[2] = (short)f2bf(f0.z); v[3] = (short)f2bf(f0.w);
            v[4] = (short)f2bf(f1.x); v[5] = (short)f2bf(f1.y);
            v[6] = (short)f2bf(f1.z); v[7] = (short)f2bf(f1.w);
        }
        ((bf16x8*)xb)[g_] = v;
    }
}

// ---------------------------------------------------------------------------
// GEMM: C[M][768] = A[M][K] @ W[768][K]^T + bias  (bf16 in/out, fp32 accum)
// block 256 thr / 4 waves, tile M128 x N128, K staged in 128-chunks via
// global_load_lds with source-XOR granule swizzle (bank-conflict-free frag reads).
// 2 blocks/CU (64 KB LDS, <=256 VGPR).
// ---------------------------------------------------------------------------
__global__ __launch_bounds__(256, 2) void srt_gemm(
    const unsigned short* __restrict__ A,
    const unsigned short* __restrict__ W,
    const float* __restrict__ bias,
    unsigned short* __restrict__ C,
    const int M, const int K)
{
    __shared__ __align__(16) unsigned short As[128 * 128];
    __shared__ __align__(16) unsigned short Bs[128 * 128];
    const int tid = threadIdx.x, lane = tid & 63, wv = tid >> 6;
    const int l15 = lane & 15, quad = lane >> 4;
    const int Mb = blockIdx.x / 6, Nb = blockIdx.x % 6;

    const f32x4 z4 = {0.f, 0.f, 0.f, 0.f};
    f32x4 acc[2][8];
    #pragma unroll
    for (int tm = 0; tm < 2; ++tm)
        #pragma unroll
        for (int tn = 0; tn < 8; ++tn) acc[tm][tn] = z4;

    const int nkk = K >> 7;
    for (int kk = 0; kk < nkk; ++kk){
        if (kk) __syncthreads();
        #pragma unroll
        for (int i = 0; i < 8; ++i){
            const int g_ = i * 256 + tid;
            const int row = g_ >> 4, c = g_ & 15;
            gl2lds16(A + (size_t)(Mb * 128 + row) * K + kk * 128 + ((c ^ (row & 7)) << 3),
                     &As[g_ * 8]);
        }
        #pragma unroll
        for (int i = 0; i < 8; ++i){
            const int g_ = i * 256 + tid;
            const int row = g_ >> 4, c = g_ & 15;
            gl2lds16(W + (size_t)(Nb * 128 + row) * K + kk * 128 + ((c ^ (row & 7)) << 3),
                     &Bs[g_ * 8]);
        }
        __syncthreads();

        bf16x8 af[2][4];
        #pragma unroll
        for (int tm = 0; tm < 2; ++tm)
            #pragma unroll
            for (int kc = 0; kc < 4; ++kc){
                const int row = wv * 32 + tm * 16 + l15;
                af[tm][kc] = *(const bf16x8*)((const char*)As +
                    row * 256 + (((quad + kc * 4) ^ (row & 7)) << 4));
            }
        #pragma unroll
        for (int tn = 0; tn < 8; ++tn){
            bf16x8 bfr[4];
            #pragma unroll
            for (int kc = 0; kc < 4; ++kc){
                const int row = tn * 16 + l15;
                bfr[kc] = *(const bf16x8*)((const char*)Bs +
                    row * 256 + (((quad + kc * 4) ^ (row & 7)) << 4));
            }
            #pragma unroll
            for (int kc = 0; kc < 4; ++kc){
                acc[0][tn] = MFMA16(af[0][kc], bfr[kc], acc[0][tn]);
                acc[1][tn] = MFMA16(af[1][kc], bfr[kc], acc[1][tn]);
            }
        }
    }
    __syncthreads();
    // repack C tile through LDS for wide coalesced stores
    #pragma unroll
    for (int tm = 0; tm < 2; ++tm)
        #pragma unroll
        for (int tn = 0; tn < 8; ++tn)
            #pragma unroll
            for (int j = 0; j < 4; ++j)
                As[(wv * 32 + tm * 16 + quad * 4 + j) * 128 + tn * 16 + l15] =
                    f2bf(acc[tm][tn][j]);
    __syncthreads();

    const int cg = tid & 15;
    float bs[8];
    #pragma unroll
    for (int jj = 0; jj < 8; ++jj) bs[jj] = bias[Nb * 128 + cg * 8 + jj];
    #pragma unroll
    for (int i = 0; i < 8; ++i){
        const int g_ = i * 256 + tid;
        const int row = g_ >> 4;
        const bf16x8 v = *(const bf16x8*)&As[g_ * 8];
        bf16x8 o;
        #pragma unroll
        for (int jj = 0; jj < 8; ++jj)
            o[jj] = (short)f2bf(bf2f((unsigned short)v[jj]) + bs[jj]);
        *(bf16x8*)(C + (size_t)(Mb * 128 + row) * 768 + Nb * 128 + cg * 8) = o;
    }
}

// ---------------------------------------------------------------------------
// Sequential GRU layer, NO cross-block traffic. grid=32 (one block per 16 rows),
// block=256 (4 waves, 1/SIMD, 512-VGPR budget). Whh (768x256) on-chip:
// 9 col-tiles/wave in VGPRs + 3 col-tiles/wave in LDS (96 KB, frag-contiguous).
// Per step: h(t-1) -> swizzled LDS -> A-frags; 96 MFMAs/wave; gates; done.
// gi streamed via double-buffered global_load_lds (source-XOR swizzled slabs).
//   h' = (1-z)*n + z*h ;  r=sig(giR+hWr) z=sig(giZ+hWz) n=tanh(giN + r*(hWn+bhhN))
// ---------------------------------------------------------------------------
__device__ __forceinline__ int gib_off(int r, int n){
    // slab [16 rows][768] bf16, 16B granules XOR-swizzled by row
    return r * 1536 + ((((n >> 3) ^ r) << 4) | ((n & 7) << 1));
}

__global__ __launch_bounds__(256, 1) void srt_seq(
    const unsigned short* __restrict__ gi,    // [512*TC][768] bf16
    const unsigned short* __restrict__ whh,   // [768][256]  bf16
    const unsigned short* __restrict__ bhh,   // [768] bf16 (n-slice used)
    float* __restrict__ hstate,               // [512][256] fp32 in/out
    unsigned short* __restrict__ h_all,       // [512*TC][256] bf16 or null
    const int TC)
{
    __shared__ __align__(16) unsigned short wL[12 * 8 * 512];   // 96 KB
    __shared__ __align__(16) unsigned short hb2[2][16 * 256];   // 16 KB, swizzled
    __shared__ __align__(16) unsigned short gib[2][16 * 768];   // 48 KB, swizzled

    const int tid  = threadIdx.x;
    const int lane = tid & 63;
    const int wv   = tid >> 6;
    const int l15  = lane & 15;
    const int quad = lane >> 4;
    const int m0   = blockIdx.x * 16;

    // ---- weight fragments: fi = u*4+i (u gate, i 16-col tile); fi<9 VGPR, fi>=9 LDS
    bf16x8 wr[9][8];
    #pragma unroll
    for (int fi = 0; fi < 12; ++fi){
        const int u = fi >> 2, ii = fi & 3;
        const unsigned short* wp =
            whh + (size_t)(u * 256 + wv * 64 + ii * 16 + l15) * 256 + quad * 8;
        if (fi < 9){
            #pragma unroll
            for (int kc = 0; kc < 8; ++kc) wr[fi][kc] = ldb8g(wp + kc * 32);
        } else {
            #pragma unroll
            for (int kc = 0; kc < 8; ++kc)
                *(bf16x8*)&wL[(((wv * 3 + fi - 9) * 8 + kc) << 9) + lane * 8] =
                    ldb8g(wp + kc * 32);
        }
    }

    float bn[4];
    #pragma unroll
    for (int ii = 0; ii < 4; ++ii) bn[ii] = bf2f(bhh[512 + wv * 64 + ii * 16 + l15]);

    float hr[4][4];
    #pragma unroll
    for (int ii = 0; ii < 4; ++ii)
        #pragma unroll
        for (int j = 0; j < 4; ++j)
            hr[ii][j] = hstate[(size_t)(m0 + quad * 4 + j) * 256 + wv * 64 + ii * 16 + l15];

    // gi staging: 24 KB slab = 1536 granules = 6 per thread; source-XOR by row
    const unsigned short* gp[6];
    int go[6];
    #pragma unroll
    for (int i = 0; i < 6; ++i){
        const int g_  = i * 256 + tid;
        const int row = g_ / 96;
        const int cg  = g_ - row * 96;
        gp[i] = gi + (size_t)(m0 + row) * TC * 768 + (size_t)(cg ^ row) * 8;
        go[i] = g_ * 8;
    }
    #pragma unroll
    for (int i = 0; i < 6; ++i) gl2lds16(gp[i], &gib[0][go[i]]);

    #pragma unroll 1
    for (int t = 0; t < TC; ++t){
        const int par = t & 1;
        // publish h(t-1) (swizzled by row)
        #pragma unroll
        for (int ii = 0; ii < 4; ++ii)
            #pragma unroll
            for (int j = 0; j < 4; ++j){
                const int r = quad * 4 + j;
                const int off = ((r * 256 + wv * 64 + ii * 16 + l15) * 2) ^ (r << 4);
                *(unsigned short*)((char*)hb2[par] + off) = f2bf(hr[ii][j]);
            }
        __syncthreads();   // also completes gi slab t (loads issued last step)

        if (h_all && t > 0){
            #pragma unroll
            for (int k = 0; k < 2; ++k){
                const int gidx = k * 256 + tid;
                const int r = gidx >> 5, c = gidx & 31;
                const bf16x8 v = *(const bf16x8*)((const char*)hb2[par] +
                                                  r * 512 + ((c ^ r) << 4));
                *(bf16x8*)(h_all + ((size_t)(m0 + r) * TC + (t - 1)) * 256 + c * 8) = v;
            }
        }

        // A-fragments of h(t-1)
        bf16x8 hA[8];
        #pragma unroll
        for (int kc = 0; kc < 8; ++kc)
            hA[kc] = *(const bf16x8*)((const char*)hb2[par] +
                     (((l15 * 256 + quad * 8 + kc * 32) * 2) ^ (l15 << 4)));

        // prefetch gi(t+1) — issued here so it drains well before next barrier
        if (t + 1 < TC){
            #pragma unroll
            for (int i = 0; i < 6; ++i)
                gl2lds16(gp[i] + (size_t)(t + 1) * 768, &gib[par ^ 1][go[i]]);
        }

        f32x4 aR[4], aZ[4], aN[4];
        #pragma unroll
        for (int ii = 0; ii < 4; ++ii)
            #pragma unroll
            for (int j = 0; j < 4; ++j){
                const int r = quad * 4 + j;
                const int n = wv * 64 + ii * 16 + l15;
                aR[ii][j] = bf2f(*(const unsigned short*)((const char*)gib[par] + gib_off(r, n)));
                aZ[ii][j] = bf2f(*(const unsigned short*)((const char*)gib[par] + gib_off(r, 256 + n)));
                aN[ii][j] = bn[ii];
            }

        #pragma unroll
        for (int kc = 0; kc < 8; ++kc){
            const bf16x8 a = hA[kc];
            aN[0] = MFMA16(a, wr[8][kc], aN[0]);
            #pragma unroll
            for (int ii = 1; ii < 4; ++ii){
                const bf16x8 wf = *(const bf16x8*)&wL[(((wv * 3 + ii - 1) * 8 + kc) << 9) + lane * 8];
                aN[ii] = MFMA16(a, wf, aN[ii]);
            }
            #pragma unroll
            for (int ii = 0; ii < 4; ++ii) aR[ii] = MFMA16(a, wr[ii][kc], aR[ii]);
            #pragma unroll
            for (int ii = 0; ii < 4; ++ii) aZ[ii] = MFMA16(a, wr[4 + ii][kc], aZ[ii]);
        }

        #pragma unroll
        for (int ii = 0; ii < 4; ++ii)
            #pragma unroll
            for (int j = 0; j < 4; ++j){
                const int r = quad * 4 + j;
                const int n = wv * 64 + ii * 16 + l15;
                const float gN = bf2f(*(const unsigned short*)((const char*)gib[par] + gib_off(r, 512 + n)));
                const float rr = sig_(aR[ii][j]);
                const float zz = sig_(aZ[ii][j]);
                const float nn = tanh_(gN + rr * aN[ii][j]);
                hr[ii][j] = (1.0f - zz) * nn + zz * hr[ii][j];
            }
    }

    #pragma unroll
    for (int ii = 0; ii < 4; ++ii)
        #pragma unroll
        for (int j = 0; j < 4; ++j)
            hstate[(size_t)(m0 + quad * 4 + j) * 256 + wv * 64 + ii * 16 + l15] = hr[ii][j];

    if (h_all){
        const int par = TC & 1;
        __syncthreads();
        #pragma unroll
        for (int ii = 0; ii < 4; ++ii)
            #pragma unroll
            for (int j = 0; j < 4; ++j){
                const int r = quad * 4 + j;
                const int off = ((r * 256 + wv * 64 + ii * 16 + l15) * 2) ^ (r << 4);
                *(unsigned short*)((char*)hb2[par] + off) = f2bf(hr[ii][j]);
            }
        __syncthreads();
        #pragma unroll
        for (int k = 0; k < 2; ++k){
            const int gidx = k * 256 + tid;
            const int r = gidx >> 5, c = gidx & 31;
            const bf16x8 v = *(const bf16x8*)((const char*)hb2[par] +
                                              r * 512 + ((c ^ r) << 4));
            *(bf16x8*)(h_all + ((size_t)(m0 + r) * TC + (TC - 1)) * 256 + c * 8) = v;
        }
    }
}

// ---------------------------------------------------------------------------
// OLD PATH (fallback when ws_size is too small): persistent GRU with per-step
// LLC exchange. Verified correct at 4410 us in previous session.
// ---------------------------------------------------------------------------
__global__ __launch_bounds__(256, 1) void srt_gru(
    const void* __restrict__ xv,
    const unsigned short* __restrict__ w0ih,
    const unsigned short* __restrict__ w0hh,
    const unsigned short* __restrict__ b0ih,
    const unsigned short* __restrict__ b0hh,
    const unsigned short* __restrict__ w1ih,
    const unsigned short* __restrict__ w1hh,
    const unsigned short* __restrict__ b1ih,
    const unsigned short* __restrict__ b1hh,
    float* __restrict__ s_out,
    const unsigned int* __restrict__ flagp,
    unsigned int* __restrict__ seq,
    unsigned short* __restrict__ hb)
{
    __shared__ __align__(16) unsigned short w0hhL[4 * 24 * 512];

    const bool isb = (*flagp != 0);
    const int tid  = threadIdx.x;
    const int lane = tid & 63;
    const int wv   = tid >> 6;
    const int l15  = lane & 15;
    const int quad = lane >> 4;
    const int q    = blockIdx.x >> 5;
    const int g    = blockIdx.x & 31;
    const int m0   = g * 16;
    const int c    = q * 64 + wv * 16 + l15;

    bf16x8 w0ihr[3][4];
    #pragma unroll
    for (int u = 0; u < 3; ++u)
        #pragma unroll
        for (int kc = 0; kc < 4; ++kc)
            w0ihr[u][kc] = ldb8g(w0ih + (u * 256 + c) * IN_ + kc * 32 + quad * 8);

    bf16x8 w1ihr[3][8], w1hhr[3][8];
    #pragma unroll
    for (int u = 0; u < 3; ++u)
        #pragma unroll
        for (int kc = 0; kc < 8; ++kc){
            w1ihr[u][kc] = ldb8g(w1ih + (u * 256 + c) * H_ + kc * 32 + quad * 8);
            w1hhr[u][kc] = ldb8g(w1hh + (u * 256 + c) * H_ + kc * 32 + quad * 8);
        }

    const int wl = wv * 12288 + lane * 8;
    #pragma unroll
    for (int u = 0; u < 3; ++u)
        #pragma unroll
        for (int kc = 0; kc < 8; ++kc){
            const bf16x8 f = ldb8g(w0hh + (u * 256 + c) * H_ + kc * 32 + quad * 8);
            *(bf16x8*)&w0hhL[wl + (u * 8 + kc) * 512] = f;
        }

    const float brz0a = bf2f(b0ih[c])       + bf2f(b0hh[c]);
    const float brz0b = bf2f(b0ih[256 + c]) + bf2f(b0hh[256 + c]);
    const float bni0v = bf2f(b0ih[512 + c]);
    const float bnh0v = bf2f(b0hh[512 + c]);
    const float brz1a = bf2f(b1ih[c])       + bf2f(b1hh[c]);
    const float brz1b = bf2f(b1ih[256 + c]) + bf2f(b1hh[256 + c]);
    const float bni1v = bf2f(b1ih[512 + c]);
    const float bnh1v = bf2f(b1hh[512 + c]);
    __syncthreads();

    float h0r[4] = {0.f, 0.f, 0.f, 0.f};
    float h1r[4] = {0.f, 0.f, 0.f, 0.f};

    const size_t xrow = (size_t)(m0 + l15) * (T_ * IN_) + quad * 8;
    const unsigned short* pxb = (const unsigned short*)xv + xrow;
    const float*          pxf = (const float*)xv + xrow;

    unsigned int* sq = seq + g * 32;
    const int wr_row[4] = {(quad * 4 + 0) * 256 + c, (quad * 4 + 1) * 256 + c,
                           (quad * 4 + 2) * 256 + c, (quad * 4 + 3) * 256 + c};

    const f32x4 z4 = {0.f, 0.f, 0.f, 0.f};
    bf16x8 h0A[8], h1A[8];
    #pragma unroll
    for (int kc = 0; kc < 8; ++kc){
        h0A[kc] = (bf16x8)(short)0;
        h1A[kc] = (bf16x8)(short)0;
    }

    #pragma unroll 1
    for (int t = 0; t < T_; ++t){
        const int par = t & 1;
        const unsigned int tgt = 4u * (unsigned)(t + 1);
        unsigned short* plane = hb + par * PL_ + g * (2 * 4096);

        #pragma unroll
        for (int j = 0; j < 4; ++j)
            __hip_atomic_store(&plane[4096 + wr_row[j]], f2bf(h1r[j]),
                               __ATOMIC_RELAXED, __HIP_MEMORY_SCOPE_AGENT);

        bf16x8 ax[4];
        if (isb){
            #pragma unroll
            for (int kc = 0; kc < 4; ++kc) ax[kc] = ldb8g(pxb + t * IN_ + kc * 32);
        } else {
            #pragma unroll
            for (int kc = 0; kc < 4; ++kc){
                const float* p = pxf + t * IN_ + kc * 32;
                const float4 f0 = *(const float4*)p;
                const float4 f1 = *(const float4*)(p + 4);
                bf16x8 a;
                a[0] = (short)f2bf(f0.x); a[1] = (short)f2bf(f0.y);
                a[2] = (short)f2bf(f0.z); a[3] = (short)f2bf(f0.w);
                a[4] = (short)f2bf(f1.x); a[5] = (short)f2bf(f1.y);
                a[6] = (short)f2bf(f1.z); a[7] = (short)f2bf(f1.w);
                ax[kc] = a;
            }
        }

        f32x4 Tr = z4, Tz = z4, Tni = z4, Tnh = z4;
        #pragma unroll
        for (int kc = 0; kc < 4; ++kc){
            Tr  = MFMA16(ax[kc], w0ihr[0][kc], Tr);
            Tz  = MFMA16(ax[kc], w0ihr[1][kc], Tz);
            Tni = MFMA16(ax[kc], w0ihr[2][kc], Tni);
        }
        #pragma unroll
        for (int kc = 0; kc < 8; ++kc){
            const bf16x8 a = h0A[kc];
            Tr  = MFMA16(a, *(const bf16x8*)&w0hhL[wl + (0 * 8 + kc) * 512], Tr);
            Tz  = MFMA16(a, *(const bf16x8*)&w0hhL[wl + (1 * 8 + kc) * 512], Tz);
            Tnh = MFMA16(a, *(const bf16x8*)&w0hhL[wl + (2 * 8 + kc) * 512], Tnh);
        }
        #pragma unroll
        for (int j = 0; j < 4; ++j){
            const float rr = sig_(Tr[j] + brz0a);
            const float zz = sig_(Tz[j] + brz0b);
            const float nn = tanh_(Tni[j] + bni0v + rr * (Tnh[j] + bnh0v));
            h0r[j] = (1.0f - zz) * nn + zz * h0r[j];
        }

        #pragma unroll
        for (int j = 0; j < 4; ++j)
            __hip_atomic_store(&plane[wr_row[j]], f2bf(h0r[j]),
                               __ATOMIC_RELAXED, __HIP_MEMORY_SCOPE_AGENT);

        __syncthreads();
        if (tid == 0)
            __hip_atomic_fetch_add(sq, 1u, __ATOMIC_RELAXED, __HIP_MEMORY_SCOPE_AGENT);
        if (lane == 0){
            while (__hip_atomic_load(sq, __ATOMIC_RELAXED, __HIP_MEMORY_SCOPE_AGENT) < tgt)
                __builtin_amdgcn_s_sleep(1);
        }
        __atomic_signal_fence(__ATOMIC_ACQ_REL);

        {
            const unsigned short* r0 = plane + l15 * 256 + quad * 8;
            #pragma unroll
            for (int kc = 0; kc < 8; ++kc){
                U64x2 u0, u1;
                u0.q[0] = __hip_atomic_load((const unsigned long long*)(r0 + kc * 32),
                                            __ATOMIC_RELAXED, __HIP_MEMORY_SCOPE_AGENT);
                u0.q[1] = __hip_atomic_load((const unsigned long long*)(r0 + kc * 32 + 4),
                                            __ATOMIC_RELAXED, __HIP_MEMORY_SCOPE_AGENT);
                u1.q[0] = __hip_atomic_load((const unsigned long long*)(r0 + 4096 + kc * 32),
                                            __ATOMIC_RELAXED, __HIP_MEMORY_SCOPE_AGENT);
                u1.q[1] = __hip_atomic_load((const unsigned long long*)(r0 + 4096 + kc * 32 + 4),
                                            __ATOMIC_RELAXED, __HIP_MEMORY_SCOPE_AGENT);
                h0A[kc] = u0.v;
                h1A[kc] = u1.v;
            }
        }

        Tr = z4; Tz = z4; Tni = z4; Tnh = z4;
        #pragma unroll
        for (int kc = 0; kc < 8; ++kc){
            const bf16x8 a0 = h0A[kc];
            const bf16x8 a1 = h1A[kc];
            Tr  = MFMA16(a0, w1ihr[0][kc], Tr);
            Tr  = MFMA16(a1, w1hhr[0][kc], Tr);
            Tz  = MFMA16(a0, w1ihr[1][kc], Tz);
            Tz  = MFMA16(a1, w1hhr[1][kc], Tz);
            Tni = MFMA16(a0, w1ihr[2][kc], Tni);
            Tnh = MFMA16(a1, w1hhr[2][kc], Tnh);
        }
        #pragma unroll
        for (int j = 0; j < 4; ++j){
            const float rr = sig_(Tr[j] + brz1a);
            const float zz = sig_(Tz[j] + brz1b);
            const float nn = tanh_(Tni[j] + bni1v + rr * (Tnh[j] + bnh1v));
            h1r[j] = (1.0f - zz) * nn + zz * h1r[j];
        }
    }

    #pragma unroll
    for (int j = 0; j < 4; ++j)
        s_out[(size_t)(m0 + quad * 4 + j) * H_ + c] = h1r[j];
}

// ---------------------------------------------------------------------------
// Single-step LSTM with zero init state, fwd+rev concat.
// ---------------------------------------------------------------------------
__global__ __launch_bounds__(256) void srt_lstm(
    const float* __restrict__ in,
    const unsigned short* __restrict__ wf, const unsigned short* __restrict__ bif,
    const unsigned short* __restrict__ bhf,
    const unsigned short* __restrict__ wr, const unsigned short* __restrict__ bir,
    const unsigned short* __restrict__ bhr,
    float* __restrict__ out)
{
    __shared__ float sx[256];
    const int b = blockIdx.x, tid = threadIdx.x;
    sx[tid] = in[b * 256 + tid];
    __syncthreads();

    const int dir = tid >> 7, uu = tid & 127;
    const unsigned short* w  = dir ? wr  : wf;
    const unsigned short* bi = dir ? bir : bif;
    const unsigned short* bh = dir ? bhr : bhf;

    const unsigned short* wi = w + (size_t)uu * 256;
    const unsigned short* wg = w + (size_t)(256 + uu) * 256;
    const unsigned short* wo = w + (size_t)(384 + uu) * 256;

    float ai = 0.f, ag = 0.f, ao = 0.f;
    for (int k = 0; k < 256; k += 8){
        const bf16x8 vi = ldb8g(wi + k);
        const bf16x8 vg = ldb8g(wg + k);
        const bf16x8 vo = ldb8g(wo + k);
        #pragma unroll
        for (int j = 0; j < 8; ++j){
            const float s = sx[k + j];
            ai += bf2f((unsigned short)vi[j]) * s;
            ag += bf2f((unsigned short)vg[j]) * s;
            ao += bf2f((unsigned short)vo[j]) * s;
        }
    }
    const float gi = ai + bf2f(bi[uu])       + bf2f(bh[uu]);
    const float gg = ag + bf2f(bi[256 + uu]) + bf2f(bh[256 + uu]);
    const float go = ao + bf2f(bi[384 + uu]) + bf2f(bh[384 + uu]);
    const float c  = sig_(gi) * tanh_(gg);
    out[b * 256 + tid] = sig_(go) * tanh_(c);
}

// ---------------------------------------------------------------------------
// B-spline basis (uniform grid, GRID_SIZE=5, ORDER=3)
// ---------------------------------------------------------------------------
__device__ __forceinline__ float knot_(int p){ return (float)(p - 3) * 0.4f - 1.0f; }

__device__ __forceinline__ void bspline8(float xv, float* bb8){
    float bb[11];
    #pragma unroll
    for (int p = 0; p < 11; ++p)
        bb[p] = (xv >= knot_(p) && xv < knot_(p + 1)) ? 1.f : 0.f;
    #pragma unroll
    for (int k = 1; k <= 3; ++k){
        #pragma unroll
        for (int p = 0; p <= 10 - k; ++p){
            const float tp = knot_(p), tpk = knot_(p + k);
            const float tp1 = knot_(p + 1), tpk1 = knot_(p + k + 1);
            bb[p] = (xv - tp) / (tpk - tp) * bb[p] + (tpk1 - xv) / (tpk1 - tp1) * bb[p + 1];
        }
    }
    #pragma unroll
    for (int j = 0; j < 8; ++j) bb8[j] = bb[j];
}

__global__ __launch_bounds__(256) void srt_kan1(
    const float* __restrict__ in,
    const unsigned short* __restrict__ bw,
    const unsigned short* __restrict__ sw,
    const unsigned short* __restrict__ sc,
    float* __restrict__ z)
{
    __shared__ float sil[256];
    __shared__ float spl[256][8];
    __shared__ float red[64][4];
    const int b = blockIdx.x, tid = threadIdx.x;

    const float xv = in[b * 256 + tid];
    sil[tid] = xv * sig_(xv);
    float bb[8];
    bspline8(xv, bb);
    #pragma unroll
    for (int j = 0; j < 8; ++j) spl[tid][j] = bb[j];
    __syncthreads();

    const int o = tid >> 2, qq = tid & 3;
    float acc = 0.f;
    for (int k = qq * 64; k < qq * 64 + 64; ++k){
        acc += sil[k] * bf2f(bw[o * 256 + k]);
        float t = 0.f;
        #pragma unroll
        for (int j = 0; j < 8; ++j) t += spl[k][j] * bf2f(sw[(o * 256 + k) * 8 + j]);
        acc += t * bf2f(sc[o * 256 + k]);
    }
    red[o][qq] = acc;
    __syncthreads();
    if (tid < 64) z[b * 64 + tid] = red[tid][0] + red[tid][1] + red[tid][2] + red[tid][3];
}

__global__ __launch_bounds__(64) void srt_kan2(
    const float* __restrict__ z,
    const unsigned short* __restrict__ bw,
    const unsigned short* __restrict__ sw,
    const unsigned short* __restrict__ sc,
    void* __restrict__ outp,
    const unsigned int* __restrict__ flagp)
{
    __shared__ float sil[64];
    __shared__ float spl[64][8];
    const int b = blockIdx.x, tid = threadIdx.x;

    const float xv = z[b * 64 + tid];
    sil[tid] = xv * sig_(xv);
    float bb[8];
    bspline8(xv, bb);
    #pragma unroll
    for (int j = 0; j < 8; ++j) spl[tid][j] = bb[j];
    __syncthreads();

    if (tid < 10){
        float acc = 0.f;
        for (int k = 0; k < 64; ++k){
            acc += sil[k] * bf2f(bw[tid * 64 + k]);
            float t = 0.f;
            #pragma unroll
            for (int j = 0; j < 8; ++j) t += spl[k][j] * bf2f(sw[(tid * 64 + k) * 8 + j]);
            acc += t * bf2f(sc[tid * 64 + k]);
        }
        if (*flagp) ((unsigned short*)outp)[b * 10 + tid] = f2bf(acc);
        else        ((float*)outp)[b * 10 + tid] = acc;
    }
}

extern "C" void kernel_launch(void* const* d_in, const int* in_sizes, int n_in,
                              void* d_out, int out_size, void* d_ws, size_t ws_size,
                              hipStream_t stream)
{
    unsigned int* flag = (unsigned int*)d_ws;
    float* s  = (float*)((char*)d_ws + 16);
    float* o0 = s  + 512 * 256;
    float* o1 = o0 + 512 * 256;
    float* zz = o1 + 512 * 256;
    unsigned short* wb = (unsigned short*)(zz + 512 * 64);

    const int idxs[26] = {1,2,3,4,5,6,7,8, 9,11,12, 13,15,16, 17,19,20, 21,23,24,
                          25,26,27, 28,29,30};
    ConvTab ct;
    int off = 0;
    int offs[26];
    for (int j = 0; j < 26; ++j){
        ct.src[j] = d_in[idxs[j]];
        ct.n[j]   = in_sizes[idxs[j]];
        ct.off[j] = off;
        offs[j]   = off;
        off += in_sizes[idxs[j]];
    }
    uintptr_t p = (uintptr_t)(wb + off);
    p = (p + 255) & ~(uintptr_t)255;
    unsigned int* seq = (unsigned int*)p;                 // old path counters
    unsigned short* hb = (unsigned short*)(seq + 1024);   // old path exchange buf
    p = (uintptr_t)(hb + 2 * 32 * 2 * 4096);
    p = (p + 255) & ~(uintptr_t)255;
    float* h0s   = (float*)p;                             // 512*256 fp32 layer-0 state
    float* bias0 = h0s + 512 * 256;                       // 768 fp32 folded biases
    float* bias1 = bias0 + 768;
    p = (uintptr_t)(bias1 + 768);
    p = (p + 255) & ~(uintptr_t)255;
    char* dyn = (char*)p;
    const size_t used = (size_t)(dyn - (char*)d_ws);

    // pick largest T-chunk that fits: xb + gi + h_all = 512*TC*2*(128+768+256) bytes
    int TC = 0;
    for (int nc = 1; nc <= 8; nc <<= 1){
        const int tc = 512 / nc;
        const size_t need = used + (size_t)512 * tc * 2 * (128 + 768 + 256);
        if (need <= ws_size){ TC = tc; break; }
    }

    const unsigned short *w0ih = wb + offs[0],  *w0hh = wb + offs[1];
    const unsigned short *b0ih = wb + offs[2],  *b0hh = wb + offs[3];
    const unsigned short *w1ih = wb + offs[4],  *w1hh = wb + offs[5];
    const unsigned short *b1ih = wb + offs[6],  *b1hh = wb + offs[7];
    const unsigned short *lwih0  = wb + offs[8],  *lbih0  = wb + offs[9],  *lbhh0  = wb + offs[10];
    const unsigned short *lwih0r = wb + offs[11], *lbih0r = wb + offs[12], *lbhh0r = wb + offs[13];
    const unsigned short *lwih1  = wb + offs[14], *lbih1  = wb + offs[15], *lbhh1  = wb + offs[16];
    const unsigned short *lwih1r = wb + offs[17], *lbih1r = wb + offs[18], *lbhh1r = wb + offs[19];
    const unsigned short *k1b = wb + offs[20], *k1s = wb + offs[21], *k1c = wb + offs[22];
    const unsigned short *k2b = wb + offs[23], *k2s = wb + offs[24], *k2c = wb + offs[25];

    srt_detect<<<1, 64, 0, stream>>>((const unsigned int*)d_in[0], flag);
    srt_conv<<<1024, 256, 0, stream>>>(ct, wb, flag);
    srt_prep<<<512, 256, 0, stream>>>(h0s, s, bias0, bias1, b0ih, b0hh, b1ih, b1hh, seq);

    if (TC > 0){
        unsigned short* xb = (unsigned short*)dyn;
        unsigned short* gi = xb + (size_t)512 * TC * 128;
        unsigned short* ha = gi + (size_t)512 * TC * 768;
        const int NC = 512 / TC;
        for (int c = 0; c < NC; ++c){
            srt_xconv<<<2048, 256, 0, stream>>>(d_in[0], xb, flag, c * TC, TC);
            srt_gemm<<<4 * TC * 6, 256, 0, stream>>>(xb, w0ih, bias0, gi, 512 * TC, 128);
            srt_seq<<<32, 256, 0, stream>>>(gi, w0hh, b0hh, h0s, ha, TC);
            srt_gemm<<<4 * TC * 6, 256, 0, stream>>>(ha, w1ih, bias1, gi, 512 * TC, 256);
            srt_seq<<<32, 256, 0, stream>>>(gi, w1hh, b1hh, s, nullptr, TC);
        }
    } else {
        srt_gru<<<128, 256, 0, stream>>>(d_in[0], w0ih, w0hh, b0ih, b0hh,
                                         w1ih, w1hh, b1ih, b1hh, s, flag, seq, hb);
    }

    srt_lstm<<<512, 256, 0, stream>>>(s,  lwih0, lbih0, lbhh0, lwih0r, lbih0r, lbhh0r, o0);
    srt_lstm<<<512, 256, 0, stream>>>(o0, lwih1, lbih1, lbhh1, lwih1r, lbih1r, lbhh1r, o1);
    srt_kan1<<<512, 256, 0, stream>>>(o1, k1b, k1s, k1c, zz);
    srt_kan2<<<512, 64, 0, stream>>>(zz, k2b, k2s, k2c, d_out, flag);
}

// Round 2
// 2566.356 us; speedup vs baseline: 2.6440x; 2.6440x over previous
//
#include <hip/hip_runtime.h>
#include <stdint.h>

// SRTKAN v3:
//  - srt_seq: operand-swapped MFMA (W as A-operand, h as B-operand) so the C-layout is
//    D[feature][row]; gi is then read as ds_read_b64 (4 consecutive cols) instead of 48
//    scalar u16 reads. 8 waves (2/SIMD -> TLP), 5/6 weight tiles in VGPR, 1 in LDS,
//    h double-buffered in 16KB swizzled LDS, h_all exported from registers. 1 barrier/step.
//  - srt_gemm: m97-proven shape: 128x128 tile, BK=64, 32KB LDS, ~3 blocks/CU for
//    cross-block latency overlap (old version: 2/CU, no overlap -> ~33TF pathological).
//  - gi/xb/h_all are TIME-MAJOR ([t*512+b][...]) for contiguous per-step streaming.

constexpr int B_  = 512;
constexpr int T_  = 512;
constexpr int IN_ = 128;
constexpr int H_  = 256;
constexpr int GR_ = 32;                   // batch groups (old fallback path)
constexpr int PL_ = GR_ * 2 * 4096;       // elements per parity plane (old path)

typedef __attribute__((ext_vector_type(8))) short bf16x8;
typedef __attribute__((ext_vector_type(4))) float f32x4;

#define MFMA16(a, b, c) __builtin_amdgcn_mfma_f32_16x16x32_bf16((a), (b), (c), 0, 0, 0)

__device__ __forceinline__ float bf2f(unsigned short u){
    union { unsigned int i; float f; } v; v.i = ((unsigned int)u) << 16; return v.f;
}
__device__ __forceinline__ unsigned short f2bf(float f){
    union { float f; unsigned int i; } v; v.f = f;
    return (unsigned short)((v.i + 0x7FFFu + ((v.i >> 16) & 1u)) >> 16); // RNE
}
__device__ __forceinline__ float sig_(float x){
    return __builtin_amdgcn_rcpf(1.0f + __expf(-x));
}
__device__ __forceinline__ float tanh_(float x){
    return 1.0f - 2.0f * __builtin_amdgcn_rcpf(1.0f + __expf(2.0f * x));
}
__device__ __forceinline__ bf16x8 ldb8g(const unsigned short* p){ return *(const bf16x8*)p; }

union U64x2 { unsigned long long q[2]; bf16x8 v; };

__device__ __forceinline__ void gl2lds16(const void* g, void* l){
    __builtin_amdgcn_global_load_lds(
        (const __attribute__((address_space(1))) unsigned int*)g,
        (__attribute__((address_space(3))) unsigned int*)l, 16, 0, 0);
}

// ---------------------------------------------------------------------------
// dtype detect
// ---------------------------------------------------------------------------
__global__ void srt_detect(const unsigned int* __restrict__ xw, unsigned int* __restrict__ flag){
    int cnt = 0;
    for (int i = threadIdx.x; i < 1024; i += 64){
        const unsigned int lo = xw[i] & 0xFFFFu;
        const int e = (int)((lo >> 7) & 0xFFu);
        if (e >= 100 && e <= 140) cnt++;
    }
    #pragma unroll
    for (int o = 32; o > 0; o >>= 1) cnt += __shfl_down(cnt, o);
    if (threadIdx.x == 0) *flag = (cnt > 614) ? 1u : 0u;   // 1 = bf16 inputs
}

// ---------------------------------------------------------------------------
// stage weights as bf16
// ---------------------------------------------------------------------------
struct ConvTab { const void* src[26]; int n[26]; int off[26]; };

__global__ __launch_bounds__(256) void srt_conv(ConvTab ct, unsigned short* __restrict__ wb,
                                                const unsigned int* __restrict__ flag){
    const bool isb = (*flag != 0);
    const int gsz = gridDim.x * blockDim.x;
    const int gid = blockIdx.x * blockDim.x + threadIdx.x;
    for (int j = 0; j < 26; ++j){
        const int n = ct.n[j];
        unsigned short* o = wb + ct.off[j];
        if (isb){
            const unsigned short* s = (const unsigned short*)ct.src[j];
            for (int i = gid; i < n; i += gsz) o[i] = s[i];
        } else {
            const float* s = (const float*)ct.src[j];
            for (int i = gid; i < n; i += gsz) o[i] = f2bf(s[i]);
        }
    }
}

// ---------------------------------------------------------------------------
// prep: zero states/counters; fold biases: bias[n] = bih[n] + (n<512 ? bhh[n] : 0)
// ---------------------------------------------------------------------------
__global__ __launch_bounds__(256) void srt_prep(
    float* __restrict__ h0s, float* __restrict__ h1s,
    float* __restrict__ bias0, float* __restrict__ bias1,
    const unsigned short* __restrict__ b0ih, const unsigned short* __restrict__ b0hh,
    const unsigned short* __restrict__ b1ih, const unsigned short* __restrict__ b1hh,
    unsigned int* __restrict__ seq)
{
    const int gid = blockIdx.x * blockDim.x + threadIdx.x;  // grid 512*256
    h0s[gid] = 0.f;
    h1s[gid] = 0.f;
    if (gid < 768){
        bias0[gid] = bf2f(b0ih[gid]) + (gid < 512 ? bf2f(b0hh[gid]) : 0.f);
        bias1[gid] = bf2f(b1ih[gid]) + (gid < 512 ? bf2f(b1hh[gid]) : 0.f);
    }
    if (gid < 1024) seq[gid] = 0u;
}

// ---------------------------------------------------------------------------
// x -> bf16, TIME-MAJOR chunk: xb[(t'*512 + b)*128 + c], t' in [0,TC)
// ---------------------------------------------------------------------------
__global__ __launch_bounds__(256) void srt_xconv(
    const void* __restrict__ xv, unsigned short* __restrict__ xb,
    const unsigned int* __restrict__ flagp, const int t0, const int TC)
{
    const bool isb = (*flagp != 0);
    const int total = 512 * TC * 16;       // 16B granules
    const int gsz = gridDim.x * blockDim.x;
    for (int g_ = blockIdx.x * blockDim.x + threadIdx.x; g_ < total; g_ += gsz){
        const int tt  = g_ >> 13;          // / (512*16)
        const int rem = g_ & 8191;
        const int b = rem >> 4, cg = rem & 15;
        const long long s8 = ((long long)b * 512 + (t0 + tt)) * 16 + cg;
        bf16x8 v;
        if (isb){
            v = ((const bf16x8*)xv)[s8];
        } else {
            const float* p = (const float*)xv + s8 * 8;
            const float4 f0 = *(const float4*)p;
            const float4 f1 = *(const float4*)(p + 4);
            v[0] = (short)f2bf(f0.x); v[1] = (short)f2bf(f0.y);
            v[2] = (short)f2bf(f0.z); v[3] = (short)f2bf(f0.w);
            v[4] = (short)f2bf(f1.x); v[5] = (short)f2bf(f1.y);
            v[6] = (short)f2bf(f1.z); v[7] = (short)f2bf(f1.w);
        }
        ((bf16x8*)xb)[g_] = v;
    }
}

// ---------------------------------------------------------------------------
// GEMM v2 (m97 shape): C[M][768] = A[M][K] @ W[768][K]^T + bias, bf16 io, fp32 acc.
// 128x128 tile, BK=64, 32KB LDS single-buffer 2-barrier loop, ~3 blocks/CU.
// Granule-XOR swizzle on both sides (source pre-swizzle + read swizzle).
// ---------------------------------------------------------------------------
__global__ __launch_bounds__(256) void srt_gemm(
    const unsigned short* __restrict__ A,
    const unsigned short* __restrict__ W,
    const float* __restrict__ bias,
    unsigned short* __restrict__ C,
    const int M, const int K)
{
    __shared__ __align__(16) unsigned short Ls[2 * 128 * 64];   // As | Bs ; epilogue: [128][128]
    unsigned short* As = Ls;
    unsigned short* Bs = Ls + 128 * 64;

    const int tid = threadIdx.x, lane = tid & 63, wv = tid >> 6;
    const int l15 = lane & 15, quad = lane >> 4;
    const int Mb = blockIdx.x / 6, Nb = blockIdx.x % 6;
    const int Moff = (wv & 1) * 64, Noff = (wv >> 1) * 64;

    const f32x4 z4 = {0.f, 0.f, 0.f, 0.f};
    f32x4 acc[4][4];
    #pragma unroll
    for (int mi = 0; mi < 4; ++mi)
        #pragma unroll
        for (int ni = 0; ni < 4; ++ni) acc[mi][ni] = z4;

    const unsigned short* pa[4]; const unsigned short* pw[4]; int dl[4];
    #pragma unroll
    for (int i = 0; i < 4; ++i){
        const int g_ = i * 256 + tid;
        const int row = g_ >> 3, cg = g_ & 7;
        pa[i] = A + (size_t)(Mb * 128 + row) * K + ((cg ^ (row & 7)) << 3);
        pw[i] = W + (size_t)(Nb * 128 + row) * K + ((cg ^ (row & 7)) << 3);
        dl[i] = g_ * 8;
    }

    for (int k0 = 0; k0 < K; k0 += 64){
        if (k0) __syncthreads();
        #pragma unroll
        for (int i = 0; i < 4; ++i) gl2lds16(pa[i] + k0, &As[dl[i]]);
        #pragma unroll
        for (int i = 0; i < 4; ++i) gl2lds16(pw[i] + k0, &Bs[dl[i]]);
        __syncthreads();

        bf16x8 am[4][2], bn[4][2];
        #pragma unroll
        for (int mi = 0; mi < 4; ++mi)
            #pragma unroll
            for (int kc = 0; kc < 2; ++kc){
                const int ra = Moff + mi * 16 + l15;
                am[mi][kc] = *(const bf16x8*)((const char*)As +
                    ra * 128 + ((kc * 64 + quad * 16) ^ ((ra & 7) << 4)));
                const int rb = Noff + mi * 16 + l15;
                bn[mi][kc] = *(const bf16x8*)((const char*)Bs +
                    rb * 128 + ((kc * 64 + quad * 16) ^ ((rb & 7) << 4)));
            }
        #pragma unroll
        for (int kc = 0; kc < 2; ++kc)
            #pragma unroll
            for (int mi = 0; mi < 4; ++mi)
                #pragma unroll
                for (int ni = 0; ni < 4; ++ni)
                    acc[mi][ni] = MFMA16(am[mi][kc], bn[ni][kc], acc[mi][ni]);
    }

    __syncthreads();
    #pragma unroll
    for (int mi = 0; mi < 4; ++mi)
        #pragma unroll
        for (int ni = 0; ni < 4; ++ni)
            #pragma unroll
            for (int j = 0; j < 4; ++j)
                Ls[(Moff + mi * 16 + quad * 4 + j) * 128 + Noff + ni * 16 + l15] =
                    f2bf(acc[mi][ni][j]);
    __syncthreads();

    const int cg = tid & 15;
    float bs[8];
    #pragma unroll
    for (int jj = 0; jj < 8; ++jj) bs[jj] = bias[Nb * 128 + cg * 8 + jj];
    #pragma unroll
    for (int i = 0; i < 8; ++i){
        const int g_ = i * 256 + tid;
        const int row = g_ >> 4;
        const bf16x8 v = *(const bf16x8*)&Ls[g_ * 8];
        bf16x8 o;
        #pragma unroll
        for (int jj = 0; jj < 8; ++jj)
            o[jj] = (short)f2bf(bf2f((unsigned short)v[jj]) + bs[jj]);
        *(bf16x8*)(C + (size_t)(Mb * 128 + row) * 768 + Nb * 128 + cg * 8) = o;
    }
}

// ---------------------------------------------------------------------------
// Sequential GRU layer v3. grid=32 (16 rows each), block=512 (8 waves, 2/SIMD).
// Operand-swapped MFMA: A = Whh fragment (lane m=l15 -> feature), B = h fragment
// (lane n=l15 -> batch row). D[m=feat quad*4+j][n=row l15] -> per-thread gi reads
// are 4 consecutive cols of one row (ds_read_b64). Per wave 32 feats x 3 gates =
// 6 tiles: wr[0..4] in VGPR, tile 5 (n-gate ii=1) in LDS. h double-buffered in
// 16KB XOR-swizzled LDS; gi double-buffered 48KB slabs staged via gl2lds with
// source pre-swizzle. One barrier per step. gi/h_all TIME-MAJOR.
// ---------------------------------------------------------------------------
__global__ __launch_bounds__(512, 1) void srt_seq(
    const unsigned short* __restrict__ gi,    // [TC*512][768] bf16 time-major
    const unsigned short* __restrict__ whh,   // [768][256]  bf16
    const unsigned short* __restrict__ bhh,   // [768] bf16 (n-slice used)
    float* __restrict__ hstate,               // [512][256] fp32 in/out
    unsigned short* __restrict__ h_all,       // [TC*512][256] bf16 time-major or null
    const int TC)
{
    __shared__ __align__(16) unsigned short wnL[8 * 8 * 512];    // 64 KB: [wv][kc][lane*8]
    __shared__ __align__(16) unsigned short hbuf[2][16 * 256];   // 16 KB, row-XOR swz
    __shared__ __align__(16) unsigned short gib[2][16 * 768];    // 48 KB, row-XOR swz

    const int tid  = threadIdx.x;
    const int lane = tid & 63;
    const int wv   = tid >> 6;     // 0..7
    const int l15  = lane & 15;
    const int quad = lane >> 4;
    const int m0   = blockIdx.x * 16;
    const int swz  = (l15 & 7) << 4;

    // ---- weight A-frags: tile fi = u*2+ii, feature = u*256 + wv*32 + ii*16 + l15
    bf16x8 wr[5][8];
    #pragma unroll
    for (int fi = 0; fi < 6; ++fi){
        const int u = fi >> 1, ii = fi & 1;
        const unsigned short* wp =
            whh + (size_t)(u * 256 + wv * 32 + ii * 16 + l15) * 256 + quad * 8;
        if (fi < 5){
            #pragma unroll
            for (int kc = 0; kc < 8; ++kc) wr[fi][kc] = ldb8g(wp + kc * 32);
        } else {
            #pragma unroll
            for (int kc = 0; kc < 8; ++kc)
                *(bf16x8*)&wnL[((wv * 8 + kc) << 9) + lane * 8] = ldb8g(wp + kc * 32);
        }
    }

    // ---- n-gate bhh as accumulator init (feat = wv*32 + ii*16 + quad*4 + j)
    f32x4 bn0[2];
    #pragma unroll
    for (int ii = 0; ii < 2; ++ii)
        #pragma unroll
        for (int j = 0; j < 4; ++j)
            bn0[ii][j] = bf2f(bhh[512 + wv * 32 + ii * 16 + quad * 4 + j]);

    // ---- h state (thread owns row m0+l15, feats wv*32+ii*16+quad*4+j)
    f32x4 hr[2];
    #pragma unroll
    for (int ii = 0; ii < 2; ++ii)
        hr[ii] = *(const f32x4*)&hstate[(size_t)(m0 + l15) * 256 + wv * 32 + ii * 16 + quad * 4];

    // ---- gi staging ptrs: slab 1536 granules, 3 per thread; source-XOR by row
    const unsigned short* gpp[3]; int gdl[3];
    #pragma unroll
    for (int i = 0; i < 3; ++i){
        const int g_  = i * 512 + tid;
        const int row = g_ / 96;
        const int cg  = g_ - row * 96;
        gpp[i] = gi + ((size_t)m0 + row) * 768 + ((cg ^ (row & 7)) << 3);
        gdl[i] = g_ * 8;
    }

    // ---- prologue: publish h(init) -> hbuf[0], stage gi(0) -> gib[0]
    #pragma unroll
    for (int ii = 0; ii < 2; ++ii){
        unsigned long long pk =
            (unsigned long long)f2bf(hr[ii][0])
          | ((unsigned long long)f2bf(hr[ii][1]) << 16)
          | ((unsigned long long)f2bf(hr[ii][2]) << 32)
          | ((unsigned long long)f2bf(hr[ii][3]) << 48);
        *(unsigned long long*)((char*)hbuf[0] + l15 * 512 +
            ((wv * 64 + ii * 32 + quad * 8) ^ swz)) = pk;
    }
    #pragma unroll
    for (int i = 0; i < 3; ++i) gl2lds16(gpp[i], &gib[0][gdl[i]]);
    __syncthreads();

    #pragma unroll 1
    for (int t = 0; t < TC; ++t){
        const int par = t & 1;

        // prefetch gi(t+1) early (drains by next barrier)
        if (t + 1 < TC){
            const size_t toff = (size_t)(t + 1) * (512 * 768);
            #pragma unroll
            for (int i = 0; i < 3; ++i) gl2lds16(gpp[i] + toff, &gib[par ^ 1][gdl[i]]);
        }

        // ---- MFMA: acc[fi] += W_tile(fi) @ h(t-1)
        f32x4 aR0 = {0,0,0,0}, aR1 = {0,0,0,0}, aZ0 = {0,0,0,0}, aZ1 = {0,0,0,0};
        f32x4 aN0 = bn0[0], aN1 = bn0[1];
        __builtin_amdgcn_s_setprio(1);
        #pragma unroll
        for (int kc = 0; kc < 8; ++kc){
            const bf16x8 hb = *(const bf16x8*)((const char*)hbuf[par] +
                l15 * 512 + ((kc * 64 + quad * 16) ^ swz));
            const bf16x8 w5 = *(const bf16x8*)&wnL[((wv * 8 + kc) << 9) + lane * 8];
            aR0 = MFMA16(wr[0][kc], hb, aR0);
            aR1 = MFMA16(wr[1][kc], hb, aR1);
            aZ0 = MFMA16(wr[2][kc], hb, aZ0);
            aZ1 = MFMA16(wr[3][kc], hb, aZ1);
            aN0 = MFMA16(wr[4][kc], hb, aN0);
            aN1 = MFMA16(w5,        hb, aN1);
        }
        __builtin_amdgcn_s_setprio(0);

        // ---- gates (gi from swizzled slab, b64 per (gate,ii))
        const char* gbase = (const char*)gib[par] + l15 * 1536;
        #pragma unroll
        for (int ii = 0; ii < 2; ++ii){
            const int cb = wv * 64 + ii * 32 + quad * 8;
            const unsigned long long qr = *(const unsigned long long*)(gbase + ((      cb) ^ swz));
            const unsigned long long qz = *(const unsigned long long*)(gbase + ((512 + cb) ^ swz));
            const unsigned long long qn = *(const unsigned long long*)(gbase + ((1024 + cb) ^ swz));
            const f32x4 aR = ii ? aR1 : aR0;
            const f32x4 aZ = ii ? aZ1 : aZ0;
            const f32x4 aN = ii ? aN1 : aN0;
            #pragma unroll
            for (int j = 0; j < 4; ++j){
                const float rr = sig_(aR[j] + bf2f((unsigned short)(qr >> (16 * j))));
                const float zz = sig_(aZ[j] + bf2f((unsigned short)(qz >> (16 * j))));
                const float nn = tanh_(bf2f((unsigned short)(qn >> (16 * j))) + rr * aN[j]);
                hr[ii][j] = (1.0f - zz) * nn + zz * hr[ii][j];
            }
        }

        // ---- publish h(t) -> hbuf[par^1]; export h_all from registers
        #pragma unroll
        for (int ii = 0; ii < 2; ++ii){
            const unsigned long long pk =
                (unsigned long long)f2bf(hr[ii][0])
              | ((unsigned long long)f2bf(hr[ii][1]) << 16)
              | ((unsigned long long)f2bf(hr[ii][2]) << 32)
              | ((unsigned long long)f2bf(hr[ii][3]) << 48);
            *(unsigned long long*)((char*)hbuf[par ^ 1] + l15 * 512 +
                ((wv * 64 + ii * 32 + quad * 8) ^ swz)) = pk;
            if (h_all)
                *(unsigned long long*)(h_all + ((size_t)t * 512 + m0 + l15) * 256 +
                    wv * 32 + ii * 16 + quad * 4) = pk;
        }

        __syncthreads();   // h(t) visible; gi(t+1) staged (vmcnt drain)
    }

    #pragma unroll
    for (int ii = 0; ii < 2; ++ii)
        *(f32x4*)&hstate[(size_t)(m0 + l15) * 256 + wv * 32 + ii * 16 + quad * 4] = hr[ii];
}

// ---------------------------------------------------------------------------
// OLD PATH (fallback when ws_size too small): persistent GRU with LLC exchange.
// ---------------------------------------------------------------------------
__global__ __launch_bounds__(256, 1) void srt_gru(
    const void* __restrict__ xv,
    const unsigned short* __restrict__ w0ih,
    const unsigned short* __restrict__ w0hh,
    const unsigned short* __restrict__ b0ih,
    const unsigned short* __restrict__ b0hh,
    const unsigned short* __restrict__ w1ih,
    const unsigned short* __restrict__ w1hh,
    const unsigned short* __restrict__ b1ih,
    const unsigned short* __restrict__ b1hh,
    float* __restrict__ s_out,
    const unsigned int* __restrict__ flagp,
    unsigned int* __restrict__ seq,
    unsigned short* __restrict__ hb)
{
    __shared__ __align__(16) unsigned short w0hhL[4 * 24 * 512];

    const bool isb = (*flagp != 0);
    const int tid  = threadIdx.x;
    const int lane = tid & 63;
    const int wv   = tid >> 6;
    const int l15  = lane & 15;
    const int quad = lane >> 4;
    const int q    = blockIdx.x >> 5;
    const int g    = blockIdx.x & 31;
    const int m0   = g * 16;
    const int c    = q * 64 + wv * 16 + l15;

    bf16x8 w0ihr[3][4];
    #pragma unroll
    for (int u = 0; u < 3; ++u)
        #pragma unroll
        for (int kc = 0; kc < 4; ++kc)
            w0ihr[u][kc] = ldb8g(w0ih + (u * 256 + c) * IN_ + kc * 32 + quad * 8);

    bf16x8 w1ihr[3][8], w1hhr[3][8];
    #pragma unroll
    for (int u = 0; u < 3; ++u)
        #pragma unroll
        for (int kc = 0; kc < 8; ++kc){
            w1ihr[u][kc] = ldb8g(w1ih + (u * 256 + c) * H_ + kc * 32 + quad * 8);
            w1hhr[u][kc] = ldb8g(w1hh + (u * 256 + c) * H_ + kc * 32 + quad * 8);
        }

    const int wl = wv * 12288 + lane * 8;
    #pragma unroll
    for (int u = 0; u < 3; ++u)
        #pragma unroll
        for (int kc = 0; kc < 8; ++kc){
            const bf16x8 f = ldb8g(w0hh + (u * 256 + c) * H_ + kc * 32 + quad * 8);
            *(bf16x8*)&w0hhL[wl + (u * 8 + kc) * 512] = f;
        }

    const float brz0a = bf2f(b0ih[c])       + bf2f(b0hh[c]);
    const float brz0b = bf2f(b0ih[256 + c]) + bf2f(b0hh[256 + c]);
    const float bni0v = bf2f(b0ih[512 + c]);
    const float bnh0v = bf2f(b0hh[512 + c]);
    const float brz1a = bf2f(b1ih[c])       + bf2f(b1hh[c]);
    const float brz1b = bf2f(b1ih[256 + c]) + bf2f(b1hh[256 + c]);
    const float bni1v = bf2f(b1ih[512 + c]);
    const float bnh1v = bf2f(b1hh[512 + c]);
    __syncthreads();

    float h0r[4] = {0.f, 0.f, 0.f, 0.f};
    float h1r[4] = {0.f, 0.f, 0.f, 0.f};

    const size_t xrow = (size_t)(m0 + l15) * (T_ * IN_) + quad * 8;
    const unsigned short* pxb = (const unsigned short*)xv + xrow;
    const float*          pxf = (const float*)xv + xrow;

    unsigned int* sq = seq + g * 32;
    const int wr_row[4] = {(quad * 4 + 0) * 256 + c, (quad * 4 + 1) * 256 + c,
                           (quad * 4 + 2) * 256 + c, (quad * 4 + 3) * 256 + c};

    const f32x4 z4 = {0.f, 0.f, 0.f, 0.f};
    bf16x8 h0A[8], h1A[8];
    #pragma unroll
    for (int kc = 0; kc < 8; ++kc){
        h0A[kc] = (bf16x8)(short)0;
        h1A[kc] = (bf16x8)(short)0;
    }

    #pragma unroll 1
    for (int t = 0; t < T_; ++t){
        const int par = t & 1;
        const unsigned int tgt = 4u * (unsigned)(t + 1);
        unsigned short* plane = hb + par * PL_ + g * (2 * 4096);

        #pragma unroll
        for (int j = 0; j < 4; ++j)
            __hip_atomic_store(&plane[4096 + wr_row[j]], f2bf(h1r[j]),
                               __ATOMIC_RELAXED, __HIP_MEMORY_SCOPE_AGENT);

        bf16x8 ax[4];
        if (isb){
            #pragma unroll
            for (int kc = 0; kc < 4; ++kc) ax[kc] = ldb8g(pxb + t * IN_ + kc * 32);
        } else {
            #pragma unroll
            for (int kc = 0; kc < 4; ++kc){
                const float* p = pxf + t * IN_ + kc * 32;
                const float4 f0 = *(const float4*)p;
                const float4 f1 = *(const float4*)(p + 4);
                bf16x8 a;
                a[0] = (short)f2bf(f0.x); a[1] = (short)f2bf(f0.y);
                a[2] = (short)f2bf(f0.z); a[3] = (short)f2bf(f0.w);
                a[4] = (short)f2bf(f1.x); a[5] = (short)f2bf(f1.y);
                a[6] = (short)f2bf(f1.z); a[7] = (short)f2bf(f1.w);
                ax[kc] = a;
            }
        }

        f32x4 Tr = z4, Tz = z4, Tni = z4, Tnh = z4;
        #pragma unroll
        for (int kc = 0; kc < 4; ++kc){
            Tr  = MFMA16(ax[kc], w0ihr[0][kc], Tr);
            Tz  = MFMA16(ax[kc], w0ihr[1][kc], Tz);
            Tni = MFMA16(ax[kc], w0ihr[2][kc], Tni);
        }
        #pragma unroll
        for (int kc = 0; kc < 8; ++kc){
            const bf16x8 a = h0A[kc];
            Tr  = MFMA16(a, *(const bf16x8*)&w0hhL[wl + (0 * 8 + kc) * 512], Tr);
            Tz  = MFMA16(a, *(const bf16x8*)&w0hhL[wl + (1 * 8 + kc) * 512], Tz);
            Tnh = MFMA16(a, *(const bf16x8*)&w0hhL[wl + (2 * 8 + kc) * 512], Tnh);
        }
        #pragma unroll
        for (int j = 0; j < 4; ++j){
            const float rr = sig_(Tr[j] + brz0a);
            const float zz = sig_(Tz[j] + brz0b);
            const float nn = tanh_(Tni[j] + bni0v + rr * (Tnh[j] + bnh0v));
            h0r[j] = (1.0f - zz) * nn + zz * h0r[j];
        }

        #pragma unroll
        for (int j = 0; j < 4; ++j)
            __hip_atomic_store(&plane[wr_row[j]], f2bf(h0r[j]),
                               __ATOMIC_RELAXED, __HIP_MEMORY_SCOPE_AGENT);

        __syncthreads();
        if (tid == 0)
            __hip_atomic_fetch_add(sq, 1u, __ATOMIC_RELAXED, __HIP_MEMORY_SCOPE_AGENT);
        if (lane == 0){
            while (__hip_atomic_load(sq, __ATOMIC_RELAXED, __HIP_MEMORY_SCOPE_AGENT) < tgt)
                __builtin_amdgcn_s_sleep(1);
        }
        __atomic_signal_fence(__ATOMIC_ACQ_REL);

        {
            const unsigned short* r0 = plane + l15 * 256 + quad * 8;
            #pragma unroll
            for (int kc = 0; kc < 8; ++kc){
                U64x2 u0, u1;
                u0.q[0] = __hip_atomic_load((const unsigned long long*)(r0 + kc * 32),
                                            __ATOMIC_RELAXED, __HIP_MEMORY_SCOPE_AGENT);
                u0.q[1] = __hip_atomic_load((const unsigned long long*)(r0 + kc * 32 + 4),
                                            __ATOMIC_RELAXED, __HIP_MEMORY_SCOPE_AGENT);
                u1.q[0] = __hip_atomic_load((const unsigned long long*)(r0 + 4096 + kc * 32),
                                            __ATOMIC_RELAXED, __HIP_MEMORY_SCOPE_AGENT);
                u1.q[1] = __hip_atomic_load((const unsigned long long*)(r0 + 4096 + kc * 32 + 4),
                                            __ATOMIC_RELAXED, __HIP_MEMORY_SCOPE_AGENT);
                h0A[kc] = u0.v;
                h1A[kc] = u1.v;
            }
        }

        Tr = z4; Tz = z4; Tni = z4; Tnh = z4;
        #pragma unroll
        for (int kc = 0; kc < 8; ++kc){
            const bf16x8 a0 = h0A[kc];
            const bf16x8 a1 = h1A[kc];
            Tr  = MFMA16(a0, w1ihr[0][kc], Tr);
            Tr  = MFMA16(a1, w1hhr[0][kc], Tr);
            Tz  = MFMA16(a0, w1ihr[1][kc], Tz);
            Tz  = MFMA16(a1, w1hhr[1][kc], Tz);
            Tni = MFMA16(a0, w1ihr[2][kc], Tni);
            Tnh = MFMA16(a1, w1hhr[2][kc], Tnh);
        }
        #pragma unroll
        for (int j = 0; j < 4; ++j){
            const float rr = sig_(Tr[j] + brz1a);
            const float zz = sig_(Tz[j] + brz1b);
            const float nn = tanh_(Tni[j] + bni1v + rr * (Tnh[j] + bnh1v));
            h1r[j] = (1.0f - zz) * nn + zz * h1r[j];
        }
    }

    #pragma unroll
    for (int j = 0; j < 4; ++j)
        s_out[(size_t)(m0 + quad * 4 + j) * H_ + c] = h1r[j];
}

// ---------------------------------------------------------------------------
// Single-step LSTM with zero init state, fwd+rev concat.
// ---------------------------------------------------------------------------
__global__ __launch_bounds__(256) void srt_lstm(
    const float* __restrict__ in,
    const unsigned short* __restrict__ wf, const unsigned short* __restrict__ bif,
    const unsigned short* __restrict__ bhf,
    const unsigned short* __restrict__ wr, const unsigned short* __restrict__ bir,
    const unsigned short* __restrict__ bhr,
    float* __restrict__ out)
{
    __shared__ float sx[256];
    const int b = blockIdx.x, tid = threadIdx.x;
    sx[tid] = in[b * 256 + tid];
    __syncthreads();

    const int dir = tid >> 7, uu = tid & 127;
    const unsigned short* w  = dir ? wr  : wf;
    const unsigned short* bi = dir ? bir : bif;
    const unsigned short* bh = dir ? bhr : bhf;

    const unsigned short* wi = w + (size_t)uu * 256;
    const unsigned short* wg = w + (size_t)(256 + uu) * 256;
    const unsigned short* wo = w + (size_t)(384 + uu) * 256;

    float ai = 0.f, ag = 0.f, ao = 0.f;
    for (int k = 0; k < 256; k += 8){
        const bf16x8 vi = ldb8g(wi + k);
        const bf16x8 vg = ldb8g(wg + k);
        const bf16x8 vo = ldb8g(wo + k);
        #pragma unroll
        for (int j = 0; j < 8; ++j){
            const float s = sx[k + j];
            ai += bf2f((unsigned short)vi[j]) * s;
            ag += bf2f((unsigned short)vg[j]) * s;
            ao += bf2f((unsigned short)vo[j]) * s;
        }
    }
    const float gi = ai + bf2f(bi[uu])       + bf2f(bh[uu]);
    const float gg = ag + bf2f(bi[256 + uu]) + bf2f(bh[256 + uu]);
    const float go = ao + bf2f(bi[384 + uu]) + bf2f(bh[384 + uu]);
    const float c  = sig_(gi) * tanh_(gg);
    out[b * 256 + tid] = sig_(go) * tanh_(c);
}

// ---------------------------------------------------------------------------
// B-spline basis (uniform grid, GRID_SIZE=5, ORDER=3)
// ---------------------------------------------------------------------------
__device__ __forceinline__ float knot_(int p){ return (float)(p - 3) * 0.4f - 1.0f; }

__device__ __forceinline__ void bspline8(float xv, float* bb8){
    float bb[11];
    #pragma unroll
    for (int p = 0; p < 11; ++p)
        bb[p] = (xv >= knot_(p) && xv < knot_(p + 1)) ? 1.f : 0.f;
    #pragma unroll
    for (int k = 1; k <= 3; ++k){
        #pragma unroll
        for (int p = 0; p <= 10 - k; ++p){
            const float tp = knot_(p), tpk = knot_(p + k);
            const float tp1 = knot_(p + 1), tpk1 = knot_(p + k + 1);
            bb[p] = (xv - tp) / (tpk - tp) * bb[p] + (tpk1 - xv) / (tpk1 - tp1) * bb[p + 1];
        }
    }
    #pragma unroll
    for (int j = 0; j < 8; ++j) bb8[j] = bb[j];
}

__global__ __launch_bounds__(256) void srt_kan1(
    const float* __restrict__ in,
    const unsigned short* __restrict__ bw,
    const unsigned short* __restrict__ sw,
    const unsigned short* __restrict__ sc,
    float* __restrict__ z)
{
    __shared__ float sil[256];
    __shared__ float spl[256][8];
    __shared__ float red[64][4];
    const int b = blockIdx.x, tid = threadIdx.x;

    const float xv = in[b * 256 + tid];
    sil[tid] = xv * sig_(xv);
    float bb[8];
    bspline8(xv, bb);
    #pragma unroll
    for (int j = 0; j < 8; ++j) spl[tid][j] = bb[j];
    __syncthreads();

    const int o = tid >> 2, qq = tid & 3;
    float acc = 0.f;
    for (int k = qq * 64; k < qq * 64 + 64; ++k){
        acc += sil[k] * bf2f(bw[o * 256 + k]);
        float t = 0.f;
        #pragma unroll
        for (int j = 0; j < 8; ++j) t += spl[k][j] * bf2f(sw[(o * 256 + k) * 8 + j]);
        acc += t * bf2f(sc[o * 256 + k]);
    }
    red[o][qq] = acc;
    __syncthreads();
    if (tid < 64) z[b * 64 + tid] = red[tid][0] + red[tid][1] + red[tid][2] + red[tid][3];
}

__global__ __launch_bounds__(64) void srt_kan2(
    const float* __restrict__ z,
    const unsigned short* __restrict__ bw,
    const unsigned short* __restrict__ sw,
    const unsigned short* __restrict__ sc,
    void* __restrict__ outp,
    const unsigned int* __restrict__ flagp)
{
    __shared__ float sil[64];
    __shared__ float spl[64][8];
    const int b = blockIdx.x, tid = threadIdx.x;

    const float xv = z[b * 64 + tid];
    sil[tid] = xv * sig_(xv);
    float bb[8];
    bspline8(xv, bb);
    #pragma unroll
    for (int j = 0; j < 8; ++j) spl[tid][j] = bb[j];
    __syncthreads();

    if (tid < 10){
        float acc = 0.f;
        for (int k = 0; k < 64; ++k){
            acc += sil[k] * bf2f(bw[tid * 64 + k]);
            float t = 0.f;
            #pragma unroll
            for (int j = 0; j < 8; ++j) t += spl[k][j] * bf2f(sw[(tid * 64 + k) * 8 + j]);
            acc += t * bf2f(sc[tid * 64 + k]);
        }
        if (*flagp) ((unsigned short*)outp)[b * 10 + tid] = f2bf(acc);
        else        ((float*)outp)[b * 10 + tid] = acc;
    }
}

extern "C" void kernel_launch(void* const* d_in, const int* in_sizes, int n_in,
                              void* d_out, int out_size, void* d_ws, size_t ws_size,
                              hipStream_t stream)
{
    unsigned int* flag = (unsigned int*)d_ws;
    float* s  = (float*)((char*)d_ws + 16);
    float* o0 = s  + 512 * 256;
    float* o1 = o0 + 512 * 256;
    float* zz = o1 + 512 * 256;
    unsigned short* wb = (unsigned short*)(zz + 512 * 64);

    const int idxs[26] = {1,2,3,4,5,6,7,8, 9,11,12, 13,15,16, 17,19,20, 21,23,24,
                          25,26,27, 28,29,30};
    ConvTab ct;
    int off = 0;
    int offs[26];
    for (int j = 0; j < 26; ++j){
        ct.src[j] = d_in[idxs[j]];
        ct.n[j]   = in_sizes[idxs[j]];
        ct.off[j] = off;
        offs[j]   = off;
        off += in_sizes[idxs[j]];
    }
    uintptr_t p = (uintptr_t)(wb + off);
    p = (p + 255) & ~(uintptr_t)255;
    unsigned int* seq = (unsigned int*)p;                 // old path counters
    unsigned short* hb = (unsigned short*)(seq + 1024);   // old path exchange buf
    p = (uintptr_t)(hb + 2 * 32 * 2 * 4096);
    p = (p + 255) & ~(uintptr_t)255;
    float* h0s   = (float*)p;                             // 512*256 fp32 layer-0 state
    float* bias0 = h0s + 512 * 256;                       // 768 fp32 folded biases
    float* bias1 = bias0 + 768;
    p = (uintptr_t)(bias1 + 768);
    p = (p + 255) & ~(uintptr_t)255;
    char* dyn = (char*)p;
    const size_t used = (size_t)(dyn - (char*)d_ws);

    // pick largest T-chunk that fits: xb + gi + h_all = 512*TC*2*(128+768+256) bytes
    int TC = 0;
    for (int nc = 1; nc <= 8; nc <<= 1){
        const int tc = 512 / nc;
        const size_t need = used + (size_t)512 * tc * 2 * (128 + 768 + 256);
        if (need <= ws_size){ TC = tc; break; }
    }

    const unsigned short *w0ih = wb + offs[0],  *w0hh = wb + offs[1];
    const unsigned short *b0ih = wb + offs[2],  *b0hh = wb + offs[3];
    const unsigned short *w1ih = wb + offs[4],  *w1hh = wb + offs[5];
    const unsigned short *b1ih = wb + offs[6],  *b1hh = wb + offs[7];
    const unsigned short *lwih0  = wb + offs[8],  *lbih0  = wb + offs[9],  *lbhh0  = wb + offs[10];
    const unsigned short *lwih0r = wb + offs[11], *lbih0r = wb + offs[12], *lbhh0r = wb + offs[13];
    const unsigned short *lwih1  = wb + offs[14], *lbih1  = wb + offs[15], *lbhh1  = wb + offs[16];
    const unsigned short *lwih1r = wb + offs[17], *lbih1r = wb + offs[18], *lbhh1r = wb + offs[19];
    const unsigned short *k1b = wb + offs[20], *k1s = wb + offs[21], *k1c = wb + offs[22];
    const unsigned short *k2b = wb + offs[23], *k2s = wb + offs[24], *k2c = wb + offs[25];

    srt_detect<<<1, 64, 0, stream>>>((const unsigned int*)d_in[0], flag);
    srt_conv<<<1024, 256, 0, stream>>>(ct, wb, flag);
    srt_prep<<<512, 256, 0, stream>>>(h0s, s, bias0, bias1, b0ih, b0hh, b1ih, b1hh, seq);

    if (TC > 0){
        unsigned short* xb = (unsigned short*)dyn;
        unsigned short* gi = xb + (size_t)512 * TC * 128;
        unsigned short* ha = gi + (size_t)512 * TC * 768;
        const int NC = 512 / TC;
        const int gblk = TC * 24;          // (TC*512/128) * 6
        for (int c = 0; c < NC; ++c){
            srt_xconv<<<2048, 256, 0, stream>>>(d_in[0], xb, flag, c * TC, TC);
            srt_gemm<<<gblk, 256, 0, stream>>>(xb, w0ih, bias0, gi, 512 * TC, 128);
            srt_seq<<<32, 512, 0, stream>>>(gi, w0hh, b0hh, h0s, ha, TC);
            srt_gemm<<<gblk, 256, 0, stream>>>(ha, w1ih, bias1, gi, 512 * TC, 256);
            srt_seq<<<32, 512, 0, stream>>>(gi, w1hh, b1hh, s, nullptr, TC);
        }
    } else {
        srt_gru<<<128, 256, 0, stream>>>(d_in[0], w0ih, w0hh, b0ih, b0hh,
                                         w1ih, w1hh, b1ih, b1hh, s, flag, seq, hb);
    }

    srt_lstm<<<512, 256, 0, stream>>>(s,  lwih0, lbih0, lbhh0, lwih0r, lbih0r, lbhh0r, o0);
    srt_lstm<<<512, 256, 0, stream>>>(o0, lwih1, lbih1, lbhh1, lwih1r, lbih1r, lbhh1r, o1);
    srt_kan1<<<512, 256, 0, stream>>>(o1, k1b, k1s, k1c, zz);
    srt_kan2<<<512, 64, 0, stream>>>(zz, k2b, k2s, k2c, d_out, flag);
}

// Round 3
// 2517.918 us; speedup vs baseline: 2.6949x; 1.0192x over previous
//
#include <hip/hip_runtime.h>
#include <stdint.h>

// SRTKAN v4:
//  - srt_gemmx: GEMM0 reads x DIRECTLY (dual-dtype staging: bf16 -> global_load_lds,
//    fp32 -> reg-stage + v_cvt_pk_bf16_f32 + swizzled ds_write). srt_xconv eliminated.
//  - srt_tail: lstm0+lstm1+kan1+kan2 fused into one row-local kernel (512 blocks);
//    o0/o1/z never leave LDS; 4 launches -> 1.
//  - srt_seq: all f2bf packing replaced with v_cvt_pk_bf16_f32 (2 inst / 4 floats),
//    trimming the VALU-issue-bound gate phase.

constexpr int B_  = 512;
constexpr int T_  = 512;
constexpr int IN_ = 128;
constexpr int H_  = 256;
constexpr int GR_ = 32;                   // batch groups (old fallback path)
constexpr int PL_ = GR_ * 2 * 4096;       // elements per parity plane (old path)

typedef __attribute__((ext_vector_type(8))) short bf16x8;
typedef __attribute__((ext_vector_type(4))) float f32x4;

#define MFMA16(a, b, c) __builtin_amdgcn_mfma_f32_16x16x32_bf16((a), (b), (c), 0, 0, 0)

__device__ __forceinline__ float bf2f(unsigned short u){
    union { unsigned int i; float f; } v; v.i = ((unsigned int)u) << 16; return v.f;
}
__device__ __forceinline__ unsigned short f2bf(float f){
    union { float f; unsigned int i; } v; v.f = f;
    return (unsigned short)((v.i + 0x7FFFu + ((v.i >> 16) & 1u)) >> 16); // RNE
}
// packed f32x2 -> bf16x2 (hardware RNE), lo = a, hi = b
__device__ __forceinline__ unsigned int cvtpk(float a, float b){
    unsigned int r;
    asm("v_cvt_pk_bf16_f32 %0, %1, %2" : "=v"(r) : "v"(a), "v"(b));
    return r;
}
__device__ __forceinline__ unsigned long long pk4(float a, float b, float c, float d){
    const unsigned int lo = cvtpk(a, b), hi = cvtpk(c, d);
    return (unsigned long long)lo | ((unsigned long long)hi << 32);
}
__device__ __forceinline__ float sig_(float x){
    return __builtin_amdgcn_rcpf(1.0f + __expf(-x));
}
__device__ __forceinline__ float tanh_(float x){
    return 1.0f - 2.0f * __builtin_amdgcn_rcpf(1.0f + __expf(2.0f * x));
}
__device__ __forceinline__ bf16x8 ldb8g(const unsigned short* p){ return *(const bf16x8*)p; }

union U64x2 { unsigned long long q[2]; bf16x8 v; };

__device__ __forceinline__ void gl2lds16(const void* g, void* l){
    __builtin_amdgcn_global_load_lds(
        (const __attribute__((address_space(1))) unsigned int*)g,
        (__attribute__((address_space(3))) unsigned int*)l, 16, 0, 0);
}

// ---------------------------------------------------------------------------
// dtype detect
// ---------------------------------------------------------------------------
__global__ void srt_detect(const unsigned int* __restrict__ xw, unsigned int* __restrict__ flag){
    int cnt = 0;
    for (int i = threadIdx.x; i < 1024; i += 64){
        const unsigned int lo = xw[i] & 0xFFFFu;
        const int e = (int)((lo >> 7) & 0xFFu);
        if (e >= 100 && e <= 140) cnt++;
    }
    #pragma unroll
    for (int o = 32; o > 0; o >>= 1) cnt += __shfl_down(cnt, o);
    if (threadIdx.x == 0) *flag = (cnt > 614) ? 1u : 0u;   // 1 = bf16 inputs
}

// ---------------------------------------------------------------------------
// stage weights as bf16
// ---------------------------------------------------------------------------
struct ConvTab { const void* src[26]; int n[26]; int off[26]; };

__global__ __launch_bounds__(256) void srt_conv(ConvTab ct, unsigned short* __restrict__ wb,
                                                const unsigned int* __restrict__ flag){
    const bool isb = (*flag != 0);
    const int gsz = gridDim.x * blockDim.x;
    const int gid = blockIdx.x * blockDim.x + threadIdx.x;
    for (int j = 0; j < 26; ++j){
        const int n = ct.n[j];
        unsigned short* o = wb + ct.off[j];
        if (isb){
            const unsigned short* s = (const unsigned short*)ct.src[j];
            for (int i = gid; i < n; i += gsz) o[i] = s[i];
        } else {
            const float* s = (const float*)ct.src[j];
            for (int i = gid; i < n; i += gsz) o[i] = f2bf(s[i]);
        }
    }
}

// ---------------------------------------------------------------------------
// prep: zero states/counters; fold biases: bias[n] = bih[n] + (n<512 ? bhh[n] : 0)
// ---------------------------------------------------------------------------
__global__ __launch_bounds__(256) void srt_prep(
    float* __restrict__ h0s, float* __restrict__ h1s,
    float* __restrict__ bias0, float* __restrict__ bias1,
    const unsigned short* __restrict__ b0ih, const unsigned short* __restrict__ b0hh,
    const unsigned short* __restrict__ b1ih, const unsigned short* __restrict__ b1hh,
    unsigned int* __restrict__ seq)
{
    const int gid = blockIdx.x * blockDim.x + threadIdx.x;  // grid 512*256
    h0s[gid] = 0.f;
    h1s[gid] = 0.f;
    if (gid < 768){
        bias0[gid] = bf2f(b0ih[gid]) + (gid < 512 ? bf2f(b0hh[gid]) : 0.f);
        bias1[gid] = bf2f(b1ih[gid]) + (gid < 512 ? bf2f(b1hh[gid]) : 0.f);
    }
    if (gid < 1024) seq[gid] = 0u;
}

// ---------------------------------------------------------------------------
// GEMM0 fused with x-conversion: gi0[r][768] = x_row(r) @ W^T + bias, r = t*512+b
// (time-major). A staged from x per dtype flag; W via gl2lds. 128x128 tile, BK=64.
// ---------------------------------------------------------------------------
__global__ __launch_bounds__(256, 3) void srt_gemmx(
    const void* __restrict__ xv,
    const unsigned int* __restrict__ flagp,
    const unsigned short* __restrict__ W,     // (768,128) bf16
    const float* __restrict__ bias,
    unsigned short* __restrict__ C,           // [M][768]
    const int t0)
{
    __shared__ __align__(16) unsigned short Ls[2 * 128 * 64];
    unsigned short* As = Ls;
    unsigned short* Bs = Ls + 128 * 64;

    const bool isb = (*flagp != 0);
    const int tid = threadIdx.x, lane = tid & 63, wv = tid >> 6;
    const int l15 = lane & 15, quad = lane >> 4;
    const int Mb = blockIdx.x / 6, Nb = blockIdx.x % 6;
    const int Moff = (wv & 1) * 64, Noff = (wv >> 1) * 64;

    const f32x4 z4 = {0.f, 0.f, 0.f, 0.f};
    f32x4 acc[4][4];
    #pragma unroll
    for (int mi = 0; mi < 4; ++mi)
        #pragma unroll
        for (int ni = 0; ni < 4; ++ni) acc[mi][ni] = z4;

    size_t asrc[4]; const unsigned short* pw[4]; int dl[4];
    #pragma unroll
    for (int i = 0; i < 4; ++i){
        const int g_ = i * 256 + tid;
        const int row = g_ >> 3, cg = g_ & 7;
        const int r = Mb * 128 + row;
        const int bb = r & 511, tt = r >> 9;
        asrc[i] = ((size_t)bb * 512 + (t0 + tt)) * 128 + ((cg ^ (row & 7)) << 3);
        pw[i] = W + (size_t)(Nb * 128 + row) * 128 + ((cg ^ (row & 7)) << 3);
        dl[i] = g_ * 8;
    }

    for (int k0 = 0; k0 < 128; k0 += 64){
        if (k0) __syncthreads();
        if (isb){
            #pragma unroll
            for (int i = 0; i < 4; ++i)
                gl2lds16((const unsigned short*)xv + asrc[i] + k0, &As[dl[i]]);
        } else {
            #pragma unroll
            for (int i = 0; i < 4; ++i){
                const float* p = (const float*)xv + asrc[i] + k0;
                const float4 f0 = *(const float4*)p;
                const float4 f1 = *(const float4*)(p + 4);
                uint4 u;
                u.x = cvtpk(f0.x, f0.y); u.y = cvtpk(f0.z, f0.w);
                u.z = cvtpk(f1.x, f1.y); u.w = cvtpk(f1.z, f1.w);
                *(uint4*)&As[dl[i]] = u;
            }
        }
        #pragma unroll
        for (int i = 0; i < 4; ++i) gl2lds16(pw[i] + k0, &Bs[dl[i]]);
        __syncthreads();

        bf16x8 am[4][2], bn[4][2];
        #pragma unroll
        for (int mi = 0; mi < 4; ++mi)
            #pragma unroll
            for (int kc = 0; kc < 2; ++kc){
                const int ra = Moff + mi * 16 + l15;
                am[mi][kc] = *(const bf16x8*)((const char*)As +
                    ra * 128 + ((kc * 64 + quad * 16) ^ ((ra & 7) << 4)));
                const int rb = Noff + mi * 16 + l15;
                bn[mi][kc] = *(const bf16x8*)((const char*)Bs +
                    rb * 128 + ((kc * 64 + quad * 16) ^ ((rb & 7) << 4)));
            }
        #pragma unroll
        for (int kc = 0; kc < 2; ++kc)
            #pragma unroll
            for (int mi = 0; mi < 4; ++mi)
                #pragma unroll
                for (int ni = 0; ni < 4; ++ni)
                    acc[mi][ni] = MFMA16(am[mi][kc], bn[ni][kc], acc[mi][ni]);
    }

    __syncthreads();
    #pragma unroll
    for (int mi = 0; mi < 4; ++mi)
        #pragma unroll
        for (int ni = 0; ni < 4; ++ni)
            #pragma unroll
            for (int j = 0; j < 4; ++j)
                Ls[(Moff + mi * 16 + quad * 4 + j) * 128 + Noff + ni * 16 + l15] =
                    f2bf(acc[mi][ni][j]);
    __syncthreads();

    const int cg = tid & 15;
    float bs[8];
    #pragma unroll
    for (int jj = 0; jj < 8; ++jj) bs[jj] = bias[Nb * 128 + cg * 8 + jj];
    #pragma unroll
    for (int i = 0; i < 8; ++i){
        const int g_ = i * 256 + tid;
        const int row = g_ >> 4;
        const bf16x8 v = *(const bf16x8*)&Ls[g_ * 8];
        bf16x8 o;
        #pragma unroll
        for (int jj = 0; jj < 8; ++jj)
            o[jj] = (short)f2bf(bf2f((unsigned short)v[jj]) + bs[jj]);
        *(bf16x8*)(C + (size_t)(Mb * 128 + row) * 768 + Nb * 128 + cg * 8) = o;
    }
}

// ---------------------------------------------------------------------------
// GEMM (bf16 A): C[M][768] = A[M][256] @ W[768][256]^T + bias. 128x128, BK=64.
// ---------------------------------------------------------------------------
__global__ __launch_bounds__(256, 3) void srt_gemm(
    const unsigned short* __restrict__ A,
    const unsigned short* __restrict__ W,
    const float* __restrict__ bias,
    unsigned short* __restrict__ C,
    const int M, const int K)
{
    __shared__ __align__(16) unsigned short Ls[2 * 128 * 64];
    unsigned short* As = Ls;
    unsigned short* Bs = Ls + 128 * 64;

    const int tid = threadIdx.x, lane = tid & 63, wv = tid >> 6;
    const int l15 = lane & 15, quad = lane >> 4;
    const int Mb = blockIdx.x / 6, Nb = blockIdx.x % 6;
    const int Moff = (wv & 1) * 64, Noff = (wv >> 1) * 64;

    const f32x4 z4 = {0.f, 0.f, 0.f, 0.f};
    f32x4 acc[4][4];
    #pragma unroll
    for (int mi = 0; mi < 4; ++mi)
        #pragma unroll
        for (int ni = 0; ni < 4; ++ni) acc[mi][ni] = z4;

    const unsigned short* pa[4]; const unsigned short* pw[4]; int dl[4];
    #pragma unroll
    for (int i = 0; i < 4; ++i){
        const int g_ = i * 256 + tid;
        const int row = g_ >> 3, cg = g_ & 7;
        pa[i] = A + (size_t)(Mb * 128 + row) * K + ((cg ^ (row & 7)) << 3);
        pw[i] = W + (size_t)(Nb * 128 + row) * K + ((cg ^ (row & 7)) << 3);
        dl[i] = g_ * 8;
    }

    for (int k0 = 0; k0 < K; k0 += 64){
        if (k0) __syncthreads();
        #pragma unroll
        for (int i = 0; i < 4; ++i) gl2lds16(pa[i] + k0, &As[dl[i]]);
        #pragma unroll
        for (int i = 0; i < 4; ++i) gl2lds16(pw[i] + k0, &Bs[dl[i]]);
        __syncthreads();

        bf16x8 am[4][2], bn[4][2];
        #pragma unroll
        for (int mi = 0; mi < 4; ++mi)
            #pragma unroll
            for (int kc = 0; kc < 2; ++kc){
                const int ra = Moff + mi * 16 + l15;
                am[mi][kc] = *(const bf16x8*)((const char*)As +
                    ra * 128 + ((kc * 64 + quad * 16) ^ ((ra & 7) << 4)));
                const int rb = Noff + mi * 16 + l15;
                bn[mi][kc] = *(const bf16x8*)((const char*)Bs +
                    rb * 128 + ((kc * 64 + quad * 16) ^ ((rb & 7) << 4)));
            }
        #pragma unroll
        for (int kc = 0; kc < 2; ++kc)
            #pragma unroll
            for (int mi = 0; mi < 4; ++mi)
                #pragma unroll
                for (int ni = 0; ni < 4; ++ni)
                    acc[mi][ni] = MFMA16(am[mi][kc], bn[ni][kc], acc[mi][ni]);
    }

    __syncthreads();
    #pragma unroll
    for (int mi = 0; mi < 4; ++mi)
        #pragma unroll
        for (int ni = 0; ni < 4; ++ni)
            #pragma unroll
            for (int j = 0; j < 4; ++j)
                Ls[(Moff + mi * 16 + quad * 4 + j) * 128 + Noff + ni * 16 + l15] =
                    f2bf(acc[mi][ni][j]);
    __syncthreads();

    const int cg = tid & 15;
    float bs[8];
    #pragma unroll
    for (int jj = 0; jj < 8; ++jj) bs[jj] = bias[Nb * 128 + cg * 8 + jj];
    #pragma unroll
    for (int i = 0; i < 8; ++i){
        const int g_ = i * 256 + tid;
        const int row = g_ >> 4;
        const bf16x8 v = *(const bf16x8*)&Ls[g_ * 8];
        bf16x8 o;
        #pragma unroll
        for (int jj = 0; jj < 8; ++jj)
            o[jj] = (short)f2bf(bf2f((unsigned short)v[jj]) + bs[jj]);
        *(bf16x8*)(C + (size_t)(Mb * 128 + row) * 768 + Nb * 128 + cg * 8) = o;
    }
}

// ---------------------------------------------------------------------------
// Sequential GRU layer. grid=32 (16 rows each), block=512 (8 waves, 2/SIMD).
// Operand-swapped MFMA (A=Whh, B=h). Packing via v_cvt_pk_bf16_f32.
// ---------------------------------------------------------------------------
__global__ __launch_bounds__(512, 1) void srt_seq(
    const unsigned short* __restrict__ gi,    // [TC*512][768] bf16 time-major
    const unsigned short* __restrict__ whh,   // [768][256]  bf16
    const unsigned short* __restrict__ bhh,   // [768] bf16 (n-slice used)
    float* __restrict__ hstate,               // [512][256] fp32 in/out
    unsigned short* __restrict__ h_all,       // [TC*512][256] bf16 time-major or null
    const int TC)
{
    __shared__ __align__(16) unsigned short wnL[8 * 8 * 512];    // 64 KB
    __shared__ __align__(16) unsigned short hbuf[2][16 * 256];   // 16 KB, row-XOR swz
    __shared__ __align__(16) unsigned short gib[2][16 * 768];    // 48 KB, row-XOR swz

    const int tid  = threadIdx.x;
    const int lane = tid & 63;
    const int wv   = tid >> 6;     // 0..7
    const int l15  = lane & 15;
    const int quad = lane >> 4;
    const int m0   = blockIdx.x * 16;
    const int swz  = (l15 & 7) << 4;

    bf16x8 wr[5][8];
    #pragma unroll
    for (int fi = 0; fi < 6; ++fi){
        const int u = fi >> 1, ii = fi & 1;
        const unsigned short* wp =
            whh + (size_t)(u * 256 + wv * 32 + ii * 16 + l15) * 256 + quad * 8;
        if (fi < 5){
            #pragma unroll
            for (int kc = 0; kc < 8; ++kc) wr[fi][kc] = ldb8g(wp + kc * 32);
        } else {
            #pragma unroll
            for (int kc = 0; kc < 8; ++kc)
                *(bf16x8*)&wnL[((wv * 8 + kc) << 9) + lane * 8] = ldb8g(wp + kc * 32);
        }
    }

    f32x4 bn0[2];
    #pragma unroll
    for (int ii = 0; ii < 2; ++ii)
        #pragma unroll
        for (int j = 0; j < 4; ++j)
            bn0[ii][j] = bf2f(bhh[512 + wv * 32 + ii * 16 + quad * 4 + j]);

    f32x4 hr[2];
    #pragma unroll
    for (int ii = 0; ii < 2; ++ii)
        hr[ii] = *(const f32x4*)&hstate[(size_t)(m0 + l15) * 256 + wv * 32 + ii * 16 + quad * 4];

    const unsigned short* gpp[3]; int gdl[3];
    #pragma unroll
    for (int i = 0; i < 3; ++i){
        const int g_  = i * 512 + tid;
        const int row = g_ / 96;
        const int cg  = g_ - row * 96;
        gpp[i] = gi + ((size_t)m0 + row) * 768 + ((cg ^ (row & 7)) << 3);
        gdl[i] = g_ * 8;
    }

    // prologue: publish h(init) -> hbuf[0], stage gi(0) -> gib[0]
    #pragma unroll
    for (int ii = 0; ii < 2; ++ii){
        const unsigned long long pk = pk4(hr[ii][0], hr[ii][1], hr[ii][2], hr[ii][3]);
        *(unsigned long long*)((char*)hbuf[0] + l15 * 512 +
            ((wv * 64 + ii * 32 + quad * 8) ^ swz)) = pk;
    }
    #pragma unroll
    for (int i = 0; i < 3; ++i) gl2lds16(gpp[i], &gib[0][gdl[i]]);
    __syncthreads();

    #pragma unroll 1
    for (int t = 0; t < TC; ++t){
        const int par = t & 1;

        if (t + 1 < TC){
            const size_t toff = (size_t)(t + 1) * (512 * 768);
            #pragma unroll
            for (int i = 0; i < 3; ++i) gl2lds16(gpp[i] + toff, &gib[par ^ 1][gdl[i]]);
        }

        f32x4 aR0 = {0,0,0,0}, aR1 = {0,0,0,0}, aZ0 = {0,0,0,0}, aZ1 = {0,0,0,0};
        f32x4 aN0 = bn0[0], aN1 = bn0[1];
        __builtin_amdgcn_s_setprio(1);
        #pragma unroll
        for (int kc = 0; kc < 8; ++kc){
            const bf16x8 hb = *(const bf16x8*)((const char*)hbuf[par] +
                l15 * 512 + ((kc * 64 + quad * 16) ^ swz));
            const bf16x8 w5 = *(const bf16x8*)&wnL[((wv * 8 + kc) << 9) + lane * 8];
            aR0 = MFMA16(wr[0][kc], hb, aR0);
            aR1 = MFMA16(wr[1][kc], hb, aR1);
            aZ0 = MFMA16(wr[2][kc], hb, aZ0);
            aZ1 = MFMA16(wr[3][kc], hb, aZ1);
            aN0 = MFMA16(wr[4][kc], hb, aN0);
            aN1 = MFMA16(w5,        hb, aN1);
        }
        __builtin_amdgcn_s_setprio(0);

        const char* gbase = (const char*)gib[par] + l15 * 1536;
        #pragma unroll
        for (int ii = 0; ii < 2; ++ii){
            const int cb = wv * 64 + ii * 32 + quad * 8;
            const unsigned long long qr = *(const unsigned long long*)(gbase + ((      cb) ^ swz));
            const unsigned long long qz = *(const unsigned long long*)(gbase + ((512 + cb) ^ swz));
            const unsigned long long qn = *(const unsigned long long*)(gbase + ((1024 + cb) ^ swz));
            const f32x4 aR = ii ? aR1 : aR0;
            const f32x4 aZ = ii ? aZ1 : aZ0;
            const f32x4 aN = ii ? aN1 : aN0;
            #pragma unroll
            for (int j = 0; j < 4; ++j){
                const float rr = sig_(aR[j] + bf2f((unsigned short)(qr >> (16 * j))));
                const float zz = sig_(aZ[j] + bf2f((unsigned short)(qz >> (16 * j))));
                const float nn = tanh_(bf2f((unsigned short)(qn >> (16 * j))) + rr * aN[j]);
                hr[ii][j] = (1.0f - zz) * nn + zz * hr[ii][j];
            }
        }

        #pragma unroll
        for (int ii = 0; ii < 2; ++ii){
            const unsigned long long pk = pk4(hr[ii][0], hr[ii][1], hr[ii][2], hr[ii][3]);
            *(unsigned long long*)((char*)hbuf[par ^ 1] + l15 * 512 +
                ((wv * 64 + ii * 32 + quad * 8) ^ swz)) = pk;
            if (h_all)
                *(unsigned long long*)(h_all + ((size_t)t * 512 + m0 + l15) * 256 +
                    wv * 32 + ii * 16 + quad * 4) = pk;
        }

        __syncthreads();
    }

    #pragma unroll
    for (int ii = 0; ii < 2; ++ii)
        *(f32x4*)&hstate[(size_t)(m0 + l15) * 256 + wv * 32 + ii * 16 + quad * 4] = hr[ii];
}

// ---------------------------------------------------------------------------
// OLD PATH (fallback when ws_size too small): persistent GRU with LLC exchange.
// ---------------------------------------------------------------------------
__global__ __launch_bounds__(256, 1) void srt_gru(
    const void* __restrict__ xv,
    const unsigned short* __restrict__ w0ih,
    const unsigned short* __restrict__ w0hh,
    const unsigned short* __restrict__ b0ih,
    const unsigned short* __restrict__ b0hh,
    const unsigned short* __restrict__ w1ih,
    const unsigned short* __restrict__ w1hh,
    const unsigned short* __restrict__ b1ih,
    const unsigned short* __restrict__ b1hh,
    float* __restrict__ s_out,
    const unsigned int* __restrict__ flagp,
    unsigned int* __restrict__ seq,
    unsigned short* __restrict__ hb)
{
    __shared__ __align__(16) unsigned short w0hhL[4 * 24 * 512];

    const bool isb = (*flagp != 0);
    const int tid  = threadIdx.x;
    const int lane = tid & 63;
    const int wv   = tid >> 6;
    const int l15  = lane & 15;
    const int quad = lane >> 4;
    const int q    = blockIdx.x >> 5;
    const int g    = blockIdx.x & 31;
    const int m0   = g * 16;
    const int c    = q * 64 + wv * 16 + l15;

    bf16x8 w0ihr[3][4];
    #pragma unroll
    for (int u = 0; u < 3; ++u)
        #pragma unroll
        for (int kc = 0; kc < 4; ++kc)
            w0ihr[u][kc] = ldb8g(w0ih + (u * 256 + c) * IN_ + kc * 32 + quad * 8);

    bf16x8 w1ihr[3][8], w1hhr[3][8];
    #pragma unroll
    for (int u = 0; u < 3; ++u)
        #pragma unroll
        for (int kc = 0; kc < 8; ++kc){
            w1ihr[u][kc] = ldb8g(w1ih + (u * 256 + c) * H_ + kc * 32 + quad * 8);
            w1hhr[u][kc] = ldb8g(w1hh + (u * 256 + c) * H_ + kc * 32 + quad * 8);
        }

    const int wl = wv * 12288 + lane * 8;
    #pragma unroll
    for (int u = 0; u < 3; ++u)
        #pragma unroll
        for (int kc = 0; kc < 8; ++kc){
            const bf16x8 f = ldb8g(w0hh + (u * 256 + c) * H_ + kc * 32 + quad * 8);
            *(bf16x8*)&w0hhL[wl + (u * 8 + kc) * 512] = f;
        }

    const float brz0a = bf2f(b0ih[c])       + bf2f(b0hh[c]);
    const float brz0b = bf2f(b0ih[256 + c]) + bf2f(b0hh[256 + c]);
    const float bni0v = bf2f(b0ih[512 + c]);
    const float bnh0v = bf2f(b0hh[512 + c]);
    const float brz1a = bf2f(b1ih[c])       + bf2f(b1hh[c]);
    const float brz1b = bf2f(b1ih[256 + c]) + bf2f(b1hh[256 + c]);
    const float bni1v = bf2f(b1ih[512 + c]);
    const float bnh1v = bf2f(b1hh[512 + c]);
    __syncthreads();

    float h0r[4] = {0.f, 0.f, 0.f, 0.f};
    float h1r[4] = {0.f, 0.f, 0.f, 0.f};

    const size_t xrow = (size_t)(m0 + l15) * (T_ * IN_) + quad * 8;
    const unsigned short* pxb = (const unsigned short*)xv + xrow;
    const float*          pxf = (const float*)xv + xrow;

    unsigned int* sq = seq + g * 32;
    const int wr_row[4] = {(quad * 4 + 0) * 256 + c, (quad * 4 + 1) * 256 + c,
                           (quad * 4 + 2) * 256 + c, (quad * 4 + 3) * 256 + c};

    const f32x4 z4 = {0.f, 0.f, 0.f, 0.f};
    bf16x8 h0A[8], h1A[8];
    #pragma unroll
    for (int kc = 0; kc < 8; ++kc){
        h0A[kc] = (bf16x8)(short)0;
        h1A[kc] = (bf16x8)(short)0;
    }

    #pragma unroll 1
    for (int t = 0; t < T_; ++t){
        const int par = t & 1;
        const unsigned int tgt = 4u * (unsigned)(t + 1);
        unsigned short* plane = hb + par * PL_ + g * (2 * 4096);

        #pragma unroll
        for (int j = 0; j < 4; ++j)
            __hip_atomic_store(&plane[4096 + wr_row[j]], f2bf(h1r[j]),
                               __ATOMIC_RELAXED, __HIP_MEMORY_SCOPE_AGENT);

        bf16x8 ax[4];
        if (isb){
            #pragma unroll
            for (int kc = 0; kc < 4; ++kc) ax[kc] = ldb8g(pxb + t * IN_ + kc * 32);
        } else {
            #pragma unroll
            for (int kc = 0; kc < 4; ++kc){
                const float* p = pxf + t * IN_ + kc * 32;
                const float4 f0 = *(const float4*)p;
                const float4 f1 = *(const float4*)(p + 4);
                bf16x8 a;
                a[0] = (short)f2bf(f0.x); a[1] = (short)f2bf(f0.y);
                a[2] = (short)f2bf(f0.z); a[3] = (short)f2bf(f0.w);
                a[4] = (short)f2bf(f1.x); a[5] = (short)f2bf(f1.y);
                a[6] = (short)f2bf(f1.z); a[7] = (short)f2bf(f1.w);
                ax[kc] = a;
            }
        }

        f32x4 Tr = z4, Tz = z4, Tni = z4, Tnh = z4;
        #pragma unroll
        for (int kc = 0; kc < 4; ++kc){
            Tr  = MFMA16(ax[kc], w0ihr[0][kc], Tr);
            Tz  = MFMA16(ax[kc], w0ihr[1][kc], Tz);
            Tni = MFMA16(ax[kc], w0ihr[2][kc], Tni);
        }
        #pragma unroll
        for (int kc = 0; kc < 8; ++kc){
            const bf16x8 a = h0A[kc];
            Tr  = MFMA16(a, *(const bf16x8*)&w0hhL[wl + (0 * 8 + kc) * 512], Tr);
            Tz  = MFMA16(a, *(const bf16x8*)&w0hhL[wl + (1 * 8 + kc) * 512], Tz);
            Tnh = MFMA16(a, *(const bf16x8*)&w0hhL[wl + (2 * 8 + kc) * 512], Tnh);
        }
        #pragma unroll
        for (int j = 0; j < 4; ++j){
            const float rr = sig_(Tr[j] + brz0a);
            const float zz = sig_(Tz[j] + brz0b);
            const float nn = tanh_(Tni[j] + bni0v + rr * (Tnh[j] + bnh0v));
            h0r[j] = (1.0f - zz) * nn + zz * h0r[j];
        }

        #pragma unroll
        for (int j = 0; j < 4; ++j)
            __hip_atomic_store(&plane[wr_row[j]], f2bf(h0r[j]),
                               __ATOMIC_RELAXED, __HIP_MEMORY_SCOPE_AGENT);

        __syncthreads();
        if (tid == 0)
            __hip_atomic_fetch_add(sq, 1u, __ATOMIC_RELAXED, __HIP_MEMORY_SCOPE_AGENT);
        if (lane == 0){
            while (__hip_atomic_load(sq, __ATOMIC_RELAXED, __HIP_MEMORY_SCOPE_AGENT) < tgt)
                __builtin_amdgcn_s_sleep(1);
        }
        __atomic_signal_fence(__ATOMIC_ACQ_REL);

        {
            const unsigned short* r0 = plane + l15 * 256 + quad * 8;
            #pragma unroll
            for (int kc = 0; kc < 8; ++kc){
                U64x2 u0, u1;
                u0.q[0] = __hip_atomic_load((const unsigned long long*)(r0 + kc * 32),
                                            __ATOMIC_RELAXED, __HIP_MEMORY_SCOPE_AGENT);
                u0.q[1] = __hip_atomic_load((const unsigned long long*)(r0 + kc * 32 + 4),
                                            __ATOMIC_RELAXED, __HIP_MEMORY_SCOPE_AGENT);
                u1.q[0] = __hip_atomic_load((const unsigned long long*)(r0 + 4096 + kc * 32),
                                            __ATOMIC_RELAXED, __HIP_MEMORY_SCOPE_AGENT);
                u1.q[1] = __hip_atomic_load((const unsigned long long*)(r0 + 4096 + kc * 32 + 4),
                                            __ATOMIC_RELAXED, __HIP_MEMORY_SCOPE_AGENT);
                h0A[kc] = u0.v;
                h1A[kc] = u1.v;
            }
        }

        Tr = z4; Tz = z4; Tni = z4; Tnh = z4;
        #pragma unroll
        for (int kc = 0; kc < 8; ++kc){
            const bf16x8 a0 = h0A[kc];
            const bf16x8 a1 = h1A[kc];
            Tr  = MFMA16(a0, w1ihr[0][kc], Tr);
            Tr  = MFMA16(a1, w1hhr[0][kc], Tr);
            Tz  = MFMA16(a0, w1ihr[1][kc], Tz);
            Tz  = MFMA16(a1, w1hhr[1][kc], Tz);
            Tni = MFMA16(a0, w1ihr[2][kc], Tni);
            Tnh = MFMA16(a1, w1hhr[2][kc], Tnh);
        }
        #pragma unroll
        for (int j = 0; j < 4; ++j){
            const float rr = sig_(Tr[j] + brz1a);
            const float zz = sig_(Tz[j] + brz1b);
            const float nn = tanh_(Tni[j] + bni1v + rr * (Tnh[j] + bnh1v));
            h1r[j] = (1.0f - zz) * nn + zz * h1r[j];
        }
    }

    #pragma unroll
    for (int j = 0; j < 4; ++j)
        s_out[(size_t)(m0 + quad * 4 + j) * H_ + c] = h1r[j];
}

// ---------------------------------------------------------------------------
// B-spline basis (uniform grid, GRID_SIZE=5, ORDER=3)
// ---------------------------------------------------------------------------
__device__ __forceinline__ float knot_(int p){ return (float)(p - 3) * 0.4f - 1.0f; }

__device__ __forceinline__ void bspline8(float xv, float* bb8){
    float bb[11];
    #pragma unroll
    for (int p = 0; p < 11; ++p)
        bb[p] = (xv >= knot_(p) && xv < knot_(p + 1)) ? 1.f : 0.f;
    #pragma unroll
    for (int k = 1; k <= 3; ++k){
        #pragma unroll
        for (int p = 0; p <= 10 - k; ++p){
            const float tp = knot_(p), tpk = knot_(p + k);
            const float tp1 = knot_(p + 1), tpk1 = knot_(p + k + 1);
            bb[p] = (xv - tp) / (tpk - tp) * bb[p] + (tpk1 - xv) / (tpk1 - tp1) * bb[p + 1];
        }
    }
    #pragma unroll
    for (int j = 0; j < 8; ++j) bb8[j] = bb[j];
}

// single-step zero-state LSTM unit (gate order i,f,g,o; f unused)
__device__ __forceinline__ float lstm_unit(const float* sxv, const unsigned short* w,
                                           const unsigned short* bi, const unsigned short* bh,
                                           int uu){
    const unsigned short* wi = w + (size_t)uu * 256;
    const unsigned short* wg = w + (size_t)(256 + uu) * 256;
    const unsigned short* wo = w + (size_t)(384 + uu) * 256;
    float ai = 0.f, ag = 0.f, ao = 0.f;
    for (int k = 0; k < 256; k += 8){
        const bf16x8 vi = ldb8g(wi + k);
        const bf16x8 vg = ldb8g(wg + k);
        const bf16x8 vo = ldb8g(wo + k);
        #pragma unroll
        for (int j = 0; j < 8; ++j){
            const float s = sxv[k + j];
            ai += bf2f((unsigned short)vi[j]) * s;
            ag += bf2f((unsigned short)vg[j]) * s;
            ao += bf2f((unsigned short)vo[j]) * s;
        }
    }
    const float gi = ai + bf2f(bi[uu])       + bf2f(bh[uu]);
    const float gg = ag + bf2f(bi[256 + uu]) + bf2f(bh[256 + uu]);
    const float go = ao + bf2f(bi[384 + uu]) + bf2f(bh[384 + uu]);
    return sig_(go) * tanh_(sig_(gi) * tanh_(gg));
}

// ---------------------------------------------------------------------------
// Fused tail: lstm0(fwd+rev) -> lstm1(fwd+rev) -> kan1 -> kan2, all row-local.
// grid = 512 (one block per batch row), block = 256.
// ---------------------------------------------------------------------------
__global__ __launch_bounds__(256) void srt_tail(
    const float* __restrict__ in,             // s (512,256) fp32
    const unsigned short* __restrict__ w0f, const unsigned short* __restrict__ bi0f,
    const unsigned short* __restrict__ bh0f,
    const unsigned short* __restrict__ w0r, const unsigned short* __restrict__ bi0r,
    const unsigned short* __restrict__ bh0r,
    const unsigned short* __restrict__ w1f, const unsigned short* __restrict__ bi1f,
    const unsigned short* __restrict__ bh1f,
    const unsigned short* __restrict__ w1r, const unsigned short* __restrict__ bi1r,
    const unsigned short* __restrict__ bh1r,
    const unsigned short* __restrict__ k1b, const unsigned short* __restrict__ k1s,
    const unsigned short* __restrict__ k1c,
    const unsigned short* __restrict__ k2b, const unsigned short* __restrict__ k2s,
    const unsigned short* __restrict__ k2c,
    void* __restrict__ outp,                  // (512,10) bf16 or fp32 per flag
    const unsigned int* __restrict__ flagp)
{
    __shared__ float sx[256];
    __shared__ float sy[256];
    __shared__ float sil[256];
    __shared__ float spl[256][8];
    __shared__ float red[64][4];
    __shared__ float sil2[64];
    __shared__ float spl2[64][8];

    const int b = blockIdx.x, tid = threadIdx.x;
    const int dir = tid >> 7, uu = tid & 127;

    sx[tid] = in[b * 256 + tid];
    __syncthreads();

    sy[tid] = lstm_unit(sx, dir ? w0r : w0f, dir ? bi0r : bi0f, dir ? bh0r : bh0f, uu);
    __syncthreads();

    const float o1v = lstm_unit(sy, dir ? w1r : w1f, dir ? bi1r : bi1f, dir ? bh1r : bh1f, uu);

    // kan1 prep (o1v stays in registers / LDS basis tables)
    sil[tid] = o1v * sig_(o1v);
    float bb[8];
    bspline8(o1v, bb);
    #pragma unroll
    for (int j = 0; j < 8; ++j) spl[tid][j] = bb[j];
    __syncthreads();

    const int o = tid >> 2, qq = tid & 3;
    float acc = 0.f;
    for (int k = qq * 64; k < qq * 64 + 64; ++k){
        acc += sil[k] * bf2f(k1b[o * 256 + k]);
        float t = 0.f;
        #pragma unroll
        for (int j = 0; j < 8; ++j) t += spl[k][j] * bf2f(k1s[(o * 256 + k) * 8 + j]);
        acc += t * bf2f(k1c[o * 256 + k]);
    }
    red[o][qq] = acc;
    __syncthreads();

    if (tid < 64){
        const float zv = red[tid][0] + red[tid][1] + red[tid][2] + red[tid][3];
        sil2[tid] = zv * sig_(zv);
        float b2[8];
        bspline8(zv, b2);
        #pragma unroll
        for (int j = 0; j < 8; ++j) spl2[tid][j] = b2[j];
    }
    __syncthreads();

    if (tid < 10){
        float a2 = 0.f;
        for (int k = 0; k < 64; ++k){
            a2 += sil2[k] * bf2f(k2b[tid * 64 + k]);
            float t = 0.f;
            #pragma unroll
            for (int j = 0; j < 8; ++j) t += spl2[k][j] * bf2f(k2s[(tid * 64 + k) * 8 + j]);
            a2 += t * bf2f(k2c[tid * 64 + k]);
        }
        if (*flagp) ((unsigned short*)outp)[b * 10 + tid] = f2bf(a2);
        else        ((float*)outp)[b * 10 + tid] = a2;
    }
}

extern "C" void kernel_launch(void* const* d_in, const int* in_sizes, int n_in,
                              void* d_out, int out_size, void* d_ws, size_t ws_size,
                              hipStream_t stream)
{
    unsigned int* flag = (unsigned int*)d_ws;
    float* s  = (float*)((char*)d_ws + 16);
    float* o0 = s  + 512 * 256;   // kept for layout stability (unused)
    float* o1 = o0 + 512 * 256;   // unused
    float* zz = o1 + 512 * 256;   // unused
    unsigned short* wb = (unsigned short*)(zz + 512 * 64);

    const int idxs[26] = {1,2,3,4,5,6,7,8, 9,11,12, 13,15,16, 17,19,20, 21,23,24,
                          25,26,27, 28,29,30};
    ConvTab ct;
    int off = 0;
    int offs[26];
    for (int j = 0; j < 26; ++j){
        ct.src[j] = d_in[idxs[j]];
        ct.n[j]   = in_sizes[idxs[j]];
        ct.off[j] = off;
        offs[j]   = off;
        off += in_sizes[idxs[j]];
    }
    uintptr_t p = (uintptr_t)(wb + off);
    p = (p + 255) & ~(uintptr_t)255;
    unsigned int* seq = (unsigned int*)p;                 // old path counters
    unsigned short* hb = (unsigned short*)(seq + 1024);   // old path exchange buf
    p = (uintptr_t)(hb + 2 * 32 * 2 * 4096);
    p = (p + 255) & ~(uintptr_t)255;
    float* h0s   = (float*)p;                             // 512*256 fp32 layer-0 state
    float* bias0 = h0s + 512 * 256;                       // 768 fp32 folded biases
    float* bias1 = bias0 + 768;
    p = (uintptr_t)(bias1 + 768);
    p = (p + 255) & ~(uintptr_t)255;
    char* dyn = (char*)p;
    const size_t used = (size_t)(dyn - (char*)d_ws);

    // pick largest T-chunk that fits: gi + h_all = 512*TC*2*(768+256) bytes
    int TC = 0;
    for (int nc = 1; nc <= 8; nc <<= 1){
        const int tc = 512 / nc;
        const size_t need = used + (size_t)512 * tc * 2 * (768 + 256);
        if (need <= ws_size){ TC = tc; break; }
    }

    const unsigned short *w0ih = wb + offs[0],  *w0hh = wb + offs[1];
    const unsigned short *b0ih = wb + offs[2],  *b0hh = wb + offs[3];
    const unsigned short *w1ih = wb + offs[4],  *w1hh = wb + offs[5];
    const unsigned short *b1ih = wb + offs[6],  *b1hh = wb + offs[7];
    const unsigned short *lwih0  = wb + offs[8],  *lbih0  = wb + offs[9],  *lbhh0  = wb + offs[10];
    const unsigned short *lwih0r = wb + offs[11], *lbih0r = wb + offs[12], *lbhh0r = wb + offs[13];
    const unsigned short *lwih1  = wb + offs[14], *lbih1  = wb + offs[15], *lbhh1  = wb + offs[16];
    const unsigned short *lwih1r = wb + offs[17], *lbih1r = wb + offs[18], *lbhh1r = wb + offs[19];
    const unsigned short *k1b = wb + offs[20], *k1s = wb + offs[21], *k1c = wb + offs[22];
    const unsigned short *k2b = wb + offs[23], *k2s = wb + offs[24], *k2c = wb + offs[25];

    srt_detect<<<1, 64, 0, stream>>>((const unsigned int*)d_in[0], flag);
    srt_conv<<<1024, 256, 0, stream>>>(ct, wb, flag);
    srt_prep<<<512, 256, 0, stream>>>(h0s, s, bias0, bias1, b0ih, b0hh, b1ih, b1hh, seq);

    if (TC > 0){
        unsigned short* gi = (unsigned short*)dyn;
        unsigned short* ha = gi + (size_t)512 * TC * 768;
        const int NC = 512 / TC;
        const int gblk = TC * 24;          // (TC*512/128) * 6
        for (int c = 0; c < NC; ++c){
            srt_gemmx<<<gblk, 256, 0, stream>>>(d_in[0], flag, w0ih, bias0, gi, c * TC);
            srt_seq<<<32, 512, 0, stream>>>(gi, w0hh, b0hh, h0s, ha, TC);
            srt_gemm<<<gblk, 256, 0, stream>>>(ha, w1ih, bias1, gi, 512 * TC, 256);
            srt_seq<<<32, 512, 0, stream>>>(gi, w1hh, b1hh, s, nullptr, TC);
        }
    } else {
        srt_gru<<<128, 256, 0, stream>>>(d_in[0], w0ih, w0hh, b0ih, b0hh,
                                         w1ih, w1hh, b1ih, b1hh, s, flag, seq, hb);
    }

    srt_tail<<<512, 256, 0, stream>>>(s,
        lwih0, lbih0, lbhh0, lwih0r, lbih0r, lbhh0r,
        lwih1, lbih1, lbhh1, lwih1r, lbih1r, lbhh1r,
        k1b, k1s, k1c, k2b, k2s, k2c, d_out, flag);
}

// Round 4
// 1773.758 us; speedup vs baseline: 3.8255x; 1.4195x over previous
//
#include <hip/hip_runtime.h>
#include <stdint.h>

// SRTKAN v5: phase-pipelined mega-kernel.
//  - GEMM v3: A resident in LDS (staged once), loop over all 6 N-tiles streaming W
//    (L2-hot) in 16KB chunks; operand-swapped MFMA -> D[feature][row] so C-stores are
//    packed b64 from acc (no LDS repack). 2048 blocks -> 256/chunk.
//  - srt_phase(p): 4 roles in one launch: seq0(c=p-1) | seq1(c=p-3) | gemmx(c=p) |
//    gemm1(c=p-2), chunks of TC=64 steps, ring-2 slabs. Dependencies are satisfied
//    across launch boundaries (stream order). seq0/seq1 overlap; gemms hide under seq.
//  - tail (lstm x2 + kan x2) stays fused; old LLC-exchange GRU kept as small-ws fallback.

constexpr int B_  = 512;
constexpr int T_  = 512;
constexpr int IN_ = 128;
constexpr int H_  = 256;
constexpr int GR_ = 32;                   // batch groups (fallback path)
constexpr int PL_ = GR_ * 2 * 4096;       // elements per parity plane (fallback path)
constexpr int TCp = 64;                   // pipeline chunk (T steps)
constexpr int NCp = 8;                    // chunks

typedef __attribute__((ext_vector_type(8))) short bf16x8;
typedef __attribute__((ext_vector_type(4))) float f32x4;

#define MFMA16(a, b, c) __builtin_amdgcn_mfma_f32_16x16x32_bf16((a), (b), (c), 0, 0, 0)

__device__ __forceinline__ float bf2f(unsigned short u){
    union { unsigned int i; float f; } v; v.i = ((unsigned int)u) << 16; return v.f;
}
__device__ __forceinline__ unsigned short f2bf(float f){
    union { float f; unsigned int i; } v; v.f = f;
    return (unsigned short)((v.i + 0x7FFFu + ((v.i >> 16) & 1u)) >> 16); // RNE
}
__device__ __forceinline__ unsigned int cvtpk(float a, float b){
    unsigned int r;
    asm("v_cvt_pk_bf16_f32 %0, %1, %2" : "=v"(r) : "v"(a), "v"(b));
    return r;
}
__device__ __forceinline__ unsigned long long pk4(float a, float b, float c, float d){
    const unsigned int lo = cvtpk(a, b), hi = cvtpk(c, d);
    return (unsigned long long)lo | ((unsigned long long)hi << 32);
}
__device__ __forceinline__ float sig_(float x){
    return __builtin_amdgcn_rcpf(1.0f + __expf(-x));
}
__device__ __forceinline__ float tanh_(float x){
    return 1.0f - 2.0f * __builtin_amdgcn_rcpf(1.0f + __expf(2.0f * x));
}
__device__ __forceinline__ bf16x8 ldb8g(const unsigned short* p){ return *(const bf16x8*)p; }

union U64x2 { unsigned long long q[2]; bf16x8 v; };

__device__ __forceinline__ void gl2lds16(const void* g, void* l){
    __builtin_amdgcn_global_load_lds(
        (const __attribute__((address_space(1))) unsigned int*)g,
        (__attribute__((address_space(3))) unsigned int*)l, 16, 0, 0);
}

// ---------------------------------------------------------------------------
// dtype detect
// ---------------------------------------------------------------------------
__global__ void srt_detect(const unsigned int* __restrict__ xw, unsigned int* __restrict__ flag){
    int cnt = 0;
    for (int i = threadIdx.x; i < 1024; i += 64){
        const unsigned int lo = xw[i] & 0xFFFFu;
        const int e = (int)((lo >> 7) & 0xFFu);
        if (e >= 100 && e <= 140) cnt++;
    }
    #pragma unroll
    for (int o = 32; o > 0; o >>= 1) cnt += __shfl_down(cnt, o);
    if (threadIdx.x == 0) *flag = (cnt > 614) ? 1u : 0u;   // 1 = bf16 inputs
}

// ---------------------------------------------------------------------------
// stage weights as bf16
// ---------------------------------------------------------------------------
struct ConvTab { const void* src[26]; int n[26]; int off[26]; };

__global__ __launch_bounds__(256) void srt_conv(ConvTab ct, unsigned short* __restrict__ wb,
                                                const unsigned int* __restrict__ flag){
    const bool isb = (*flag != 0);
    const int gsz = gridDim.x * blockDim.x;
    const int gid = blockIdx.x * blockDim.x + threadIdx.x;
    for (int j = 0; j < 26; ++j){
        const int n = ct.n[j];
        unsigned short* o = wb + ct.off[j];
        if (isb){
            const unsigned short* s = (const unsigned short*)ct.src[j];
            for (int i = gid; i < n; i += gsz) o[i] = s[i];
        } else {
            const float* s = (const float*)ct.src[j];
            for (int i = gid; i < n; i += gsz) o[i] = f2bf(s[i]);
        }
    }
}

// ---------------------------------------------------------------------------
// prep: zero states/counters; fold biases: bias[n] = bih[n] + (n<512 ? bhh[n] : 0)
// ---------------------------------------------------------------------------
__global__ __launch_bounds__(256) void srt_prep(
    float* __restrict__ h0s, float* __restrict__ h1s,
    float* __restrict__ bias0, float* __restrict__ bias1,
    const unsigned short* __restrict__ b0ih, const unsigned short* __restrict__ b0hh,
    const unsigned short* __restrict__ b1ih, const unsigned short* __restrict__ b1hh,
    unsigned int* __restrict__ seq)
{
    const int gid = blockIdx.x * blockDim.x + threadIdx.x;  // grid 512*256
    h0s[gid] = 0.f;
    h1s[gid] = 0.f;
    if (gid < 768){
        bias0[gid] = bf2f(b0ih[gid]) + (gid < 512 ? bf2f(b0hh[gid]) : 0.f);
        bias1[gid] = bf2f(b1ih[gid]) + (gid < 512 ? bf2f(b1hh[gid]) : 0.f);
    }
    if (gid < 1024) seq[gid] = 0u;
}

// ---------------------------------------------------------------------------
// seq role: one GRU layer, TC steps, 16 batch rows (group bg), 512 threads.
// Operand-swapped MFMA (A=Whh, B=h). Whh: 5 tiles/wave VGPR + 1 tile LDS (64KB).
// h double-buffered 16KB swizzled; gi double-buffered 48KB slabs via gl2lds.
// shm carve: wnL[32768] | hbuf[2*4096] | gib[2*12288]  (= 65536 shorts = 128KB)
// ---------------------------------------------------------------------------
__device__ void seq_dev(unsigned short* shm,
    const unsigned short* __restrict__ gi,    // [TC*512][768] bf16 time-major slab
    const unsigned short* __restrict__ whh,   // [768][256]
    const unsigned short* __restrict__ bhh,   // [768] (n-slice used)
    float* __restrict__ hstate,               // [512][256] fp32 in/out
    unsigned short* __restrict__ h_all,       // [TC*512][256] slab or null
    const int TC, const int bg)
{
    unsigned short* wnL   = shm;               // 32768 shorts
    unsigned short* hbufB = shm + 32768;       // 2 * 4096
    unsigned short* gibB  = shm + 32768 + 8192;// 2 * 12288

    const int tid  = threadIdx.x;
    const int lane = tid & 63;
    const int wv   = tid >> 6;     // 0..7
    const int l15  = lane & 15;
    const int quad = lane >> 4;
    const int m0   = bg * 16;
    const int swz  = (l15 & 7) << 4;

    bf16x8 wr[5][8];
    #pragma unroll
    for (int fi = 0; fi < 6; ++fi){
        const int u = fi >> 1, ii = fi & 1;
        const unsigned short* wp =
            whh + (size_t)(u * 256 + wv * 32 + ii * 16 + l15) * 256 + quad * 8;
        if (fi < 5){
            #pragma unroll
            for (int kc = 0; kc < 8; ++kc) wr[fi][kc] = ldb8g(wp + kc * 32);
        } else {
            #pragma unroll
            for (int kc = 0; kc < 8; ++kc)
                *(bf16x8*)&wnL[((wv * 8 + kc) << 9) + lane * 8] = ldb8g(wp + kc * 32);
        }
    }

    f32x4 bn0[2];
    #pragma unroll
    for (int ii = 0; ii < 2; ++ii)
        #pragma unroll
        for (int j = 0; j < 4; ++j)
            bn0[ii][j] = bf2f(bhh[512 + wv * 32 + ii * 16 + quad * 4 + j]);

    f32x4 hr[2];
    #pragma unroll
    for (int ii = 0; ii < 2; ++ii)
        hr[ii] = *(const f32x4*)&hstate[(size_t)(m0 + l15) * 256 + wv * 32 + ii * 16 + quad * 4];

    const unsigned short* gpp[3]; int gdl[3];
    #pragma unroll
    for (int i = 0; i < 3; ++i){
        const int g_  = i * 512 + tid;
        const int row = g_ / 96;
        const int cg  = g_ - row * 96;
        gpp[i] = gi + ((size_t)m0 + row) * 768 + ((cg ^ (row & 7)) << 3);
        gdl[i] = g_ * 8;
    }

    // prologue: publish h(init) -> hbuf[0], stage gi(0) -> gib[0]
    #pragma unroll
    for (int ii = 0; ii < 2; ++ii){
        const unsigned long long pk = pk4(hr[ii][0], hr[ii][1], hr[ii][2], hr[ii][3]);
        *(unsigned long long*)((char*)hbufB + l15 * 512 +
            ((wv * 64 + ii * 32 + quad * 8) ^ swz)) = pk;
    }
    #pragma unroll
    for (int i = 0; i < 3; ++i) gl2lds16(gpp[i], &gibB[gdl[i]]);
    __syncthreads();

    #pragma unroll 1
    for (int t = 0; t < TC; ++t){
        const int par = t & 1;
        unsigned short* hb_cur = hbufB + par * 4096;
        unsigned short* hb_nxt = hbufB + (par ^ 1) * 4096;
        unsigned short* gb_cur = gibB + par * 12288;
        unsigned short* gb_nxt = gibB + (par ^ 1) * 12288;

        if (t + 1 < TC){
            const size_t toff = (size_t)(t + 1) * (512 * 768);
            #pragma unroll
            for (int i = 0; i < 3; ++i) gl2lds16(gpp[i] + toff, &gb_nxt[gdl[i]]);
        }

        f32x4 aR0 = {0,0,0,0}, aR1 = {0,0,0,0}, aZ0 = {0,0,0,0}, aZ1 = {0,0,0,0};
        f32x4 aN0 = bn0[0], aN1 = bn0[1];
        __builtin_amdgcn_s_setprio(1);
        #pragma unroll
        for (int kc = 0; kc < 8; ++kc){
            const bf16x8 hb = *(const bf16x8*)((const char*)hb_cur +
                l15 * 512 + ((kc * 64 + quad * 16) ^ swz));
            const bf16x8 w5 = *(const bf16x8*)&wnL[((wv * 8 + kc) << 9) + lane * 8];
            aR0 = MFMA16(wr[0][kc], hb, aR0);
            aR1 = MFMA16(wr[1][kc], hb, aR1);
            aZ0 = MFMA16(wr[2][kc], hb, aZ0);
            aZ1 = MFMA16(wr[3][kc], hb, aZ1);
            aN0 = MFMA16(wr[4][kc], hb, aN0);
            aN1 = MFMA16(w5,        hb, aN1);
        }
        __builtin_amdgcn_s_setprio(0);

        const char* gbase = (const char*)gb_cur + l15 * 1536;
        #pragma unroll
        for (int ii = 0; ii < 2; ++ii){
            const int cb = wv * 64 + ii * 32 + quad * 8;
            const unsigned long long qr = *(const unsigned long long*)(gbase + ((       cb) ^ swz));
            const unsigned long long qz = *(const unsigned long long*)(gbase + ((512  + cb) ^ swz));
            const unsigned long long qn = *(const unsigned long long*)(gbase + ((1024 + cb) ^ swz));
            const f32x4 aR = ii ? aR1 : aR0;
            const f32x4 aZ = ii ? aZ1 : aZ0;
            const f32x4 aN = ii ? aN1 : aN0;
            #pragma unroll
            for (int j = 0; j < 4; ++j){
                const float rr = sig_(aR[j] + bf2f((unsigned short)(qr >> (16 * j))));
                const float zz = sig_(aZ[j] + bf2f((unsigned short)(qz >> (16 * j))));
                const float nn = tanh_(bf2f((unsigned short)(qn >> (16 * j))) + rr * aN[j]);
                hr[ii][j] = (1.0f - zz) * nn + zz * hr[ii][j];
            }
        }

        #pragma unroll
        for (int ii = 0; ii < 2; ++ii){
            const unsigned long long pk = pk4(hr[ii][0], hr[ii][1], hr[ii][2], hr[ii][3]);
            *(unsigned long long*)((char*)hb_nxt + l15 * 512 +
                ((wv * 64 + ii * 32 + quad * 8) ^ swz)) = pk;
            if (h_all)
                *(unsigned long long*)(h_all + ((size_t)t * 512 + m0 + l15) * 256 +
                    wv * 32 + ii * 16 + quad * 4) = pk;
        }

        __syncthreads();
    }

    #pragma unroll
    for (int ii = 0; ii < 2; ++ii)
        *(f32x4*)&hstate[(size_t)(m0 + l15) * 256 + wv * 32 + ii * 16 + quad * 4] = hr[ii];
}

// ---------------------------------------------------------------------------
// gemm role: C[r][768] = A[r][K] @ W[768][K]^T + bias for one 128-row M-tile.
// A resident in LDS (staged once); W streamed per (Nb,k0) 16KB chunk (L2-hot).
// Operand-swapped MFMA: D[m=feature][n=row] -> per-thread 4 consecutive features
// = packed b64 store. 512 thr / 8 waves: wave = (row-half rh, feat-quarter fq).
// shm carve: Ares[128*K] at 0 | Wbuf[128*64] at 32768.
// ---------------------------------------------------------------------------
template<int K, bool XS>
__device__ void gemm_dev(unsigned short* shm, const void* Asrc, const bool isb,
                         const int t0, const unsigned short* __restrict__ W,
                         const float* __restrict__ bias,
                         unsigned short* __restrict__ C, const int mb)
{
    unsigned short* Ares = shm;            // 128*K shorts (<= 32768)
    unsigned short* Wbuf = shm + 32768;    // 8192 shorts

    const int tid = threadIdx.x;           // 0..511
    const int lane = tid & 63, wv = tid >> 6;
    const int l15 = lane & 15, quad = lane >> 4;
    const int rh = wv & 1, fq = wv >> 1;   // row-half (64), feat-quarter (32)

    constexpr int GPT = K / 32;            // A granules per thread (4 or 8)
    constexpr int GPR = K / 8;             // A granules per row

    // ---- stage A tile (128 x K bf16), granule-XOR swizzled by row&7
    if (!XS || isb){
        #pragma unroll
        for (int i = 0; i < GPT; ++i){
            const int g_ = i * 512 + tid;
            const int row = g_ / GPR, cg = g_ % GPR;
            size_t src;
            if (XS){
                const int r = mb * 128 + row;
                const int b = r & 511, tt = r >> 9;
                src = ((size_t)b * 512 + (t0 + tt)) * 128 + ((cg ^ (row & 7)) << 3);
            } else {
                src = (size_t)(mb * 128 + row) * K + ((cg ^ (row & 7)) << 3);
            }
            gl2lds16((const unsigned short*)Asrc + src, &Ares[g_ * 8]);
        }
    } else {
        // fp32 x: reg-stage + cvt_pk + swizzled ds_write
        #pragma unroll
        for (int i = 0; i < GPT; ++i){
            const int g_ = i * 512 + tid;
            const int row = g_ / GPR, cg = g_ % GPR;
            const int r = mb * 128 + row;
            const int b = r & 511, tt = r >> 9;
            const float* p = (const float*)Asrc + ((size_t)b * 512 + (t0 + tt)) * 128 + cg * 8;
            const float4 f0 = *(const float4*)p;
            const float4 f1 = *(const float4*)(p + 4);
            uint4 u;
            u.x = cvtpk(f0.x, f0.y); u.y = cvtpk(f0.z, f0.w);
            u.z = cvtpk(f1.x, f1.y); u.w = cvtpk(f1.z, f1.w);
            *(uint4*)&Ares[(row * GPR + (cg ^ (row & 7))) * 8] = u;
        }
    }

    for (int Nb = 0; Nb < 6; ++Nb){
        f32x4 acc[4][2];
        #pragma unroll
        for (int mi = 0; mi < 4; ++mi){ acc[mi][0] = (f32x4){0,0,0,0}; acc[mi][1] = (f32x4){0,0,0,0}; }

        for (int k0 = 0; k0 < K; k0 += 64){
            __syncthreads();   // prev W chunk fully consumed; (1st iter: A staged too)
            #pragma unroll
            for (int i = 0; i < 2; ++i){
                const int g_ = i * 512 + tid;
                const int row = g_ >> 3, cg = g_ & 7;
                gl2lds16(W + (size_t)(Nb * 128 + row) * K + k0 + ((cg ^ (row & 7)) << 3),
                         &Wbuf[g_ * 8]);
            }
            __syncthreads();   // W chunk staged (barrier drains vmcnt)

            #pragma unroll
            for (int kc = 0; kc < 2; ++kc){
                bf16x8 wf[2], af[4];
                #pragma unroll
                for (int ni = 0; ni < 2; ++ni){
                    const int rf = fq * 32 + ni * 16 + l15;
                    wf[ni] = *(const bf16x8*)((const char*)Wbuf +
                        rf * 128 + (((kc * 4 + quad) ^ (rf & 7)) << 4));
                }
                #pragma unroll
                for (int mi = 0; mi < 4; ++mi){
                    const int ra = rh * 64 + mi * 16 + l15;
                    af[mi] = *(const bf16x8*)((const char*)Ares +
                        ra * (2 * K) + ((((k0 >> 3) + kc * 4 + quad) ^ (ra & 7)) << 4));
                }
                #pragma unroll
                for (int mi = 0; mi < 4; ++mi){
                    acc[mi][0] = MFMA16(wf[0], af[mi], acc[mi][0]);
                    acc[mi][1] = MFMA16(wf[1], af[mi], acc[mi][1]);
                }
            }
        }

        // store with bias (D[m=feat quad*4+j][n=row l15] -> b64 of 4 feats)
        float bs[2][4];
        #pragma unroll
        for (int ni = 0; ni < 2; ++ni)
            #pragma unroll
            for (int j = 0; j < 4; ++j)
                bs[ni][j] = bias[Nb * 128 + fq * 32 + ni * 16 + quad * 4 + j];
        #pragma unroll
        for (int mi = 0; mi < 4; ++mi)
            #pragma unroll
            for (int ni = 0; ni < 2; ++ni){
                const unsigned int lo = cvtpk(acc[mi][ni][0] + bs[ni][0],
                                              acc[mi][ni][1] + bs[ni][1]);
                const unsigned int hi = cvtpk(acc[mi][ni][2] + bs[ni][2],
                                              acc[mi][ni][3] + bs[ni][3]);
                const int row = mb * 128 + rh * 64 + mi * 16 + l15;
                const int col = Nb * 128 + fq * 32 + ni * 16 + quad * 4;
                uint2 st; st.x = lo; st.y = hi;
                *(uint2*)(C + (size_t)row * 768 + col) = st;
            }
    }
}

// ---------------------------------------------------------------------------
// phase kernel: roles by blockIdx. grid = 576, block = 512, 128KB LDS.
//  [0,32)   seq0 chunk p-1     [32,64)  seq1 chunk p-3
//  [64,320) gemmx chunk p      [320,576) gemm1 chunk p-2
// ---------------------------------------------------------------------------
struct PA {
    const void* xv;
    const unsigned int* flag;
    const unsigned short *w0ih, *w0hh, *b0hh, *w1ih, *w1hh, *b1hh;
    const float *bias0, *bias1;
    float *h0s, *h1s;
    unsigned short *gi0a, *gi0b, *haa, *hab, *gi1a, *gi1b;
    int p;
};

__global__ __launch_bounds__(512, 1) void srt_phase(PA a){
    __shared__ __align__(16) unsigned short shm[65536];   // 128 KB
    const int bid = blockIdx.x;
    const int p = a.p;

    if (bid < 32){
        const int c = p - 1; if (c < 0 || c >= NCp) return;
        seq_dev(shm, (c & 1) ? a.gi0b : a.gi0a, a.w0hh, a.b0hh, a.h0s,
                (c & 1) ? a.hab : a.haa, TCp, bid);
    } else if (bid < 64){
        const int c = p - 3; if (c < 0 || c >= NCp) return;
        seq_dev(shm, (c & 1) ? a.gi1b : a.gi1a, a.w1hh, a.b1hh, a.h1s,
                nullptr, TCp, bid - 32);
    } else if (bid < 320){
        const int c = p; if (c >= NCp) return;
        const bool isb = (*a.flag != 0);
        gemm_dev<128, true>(shm, a.xv, isb, c * TCp, a.w0ih, a.bias0,
                            (c & 1) ? a.gi0b : a.gi0a, bid - 64);
    } else {
        const int c = p - 2; if (c < 0 || c >= NCp) return;
        gemm_dev<256, false>(shm, (c & 1) ? a.hab : a.haa, true, 0, a.w1ih, a.bias1,
                             (c & 1) ? a.gi1b : a.gi1a, bid - 320);
    }
}

// ---------------------------------------------------------------------------
// OLD PATH (fallback when ws_size too small): persistent GRU with LLC exchange.
// ---------------------------------------------------------------------------
__global__ __launch_bounds__(256, 1) void srt_gru(
    const void* __restrict__ xv,
    const unsigned short* __restrict__ w0ih,
    const unsigned short* __restrict__ w0hh,
    const unsigned short* __restrict__ b0ih,
    const unsigned short* __restrict__ b0hh,
    const unsigned short* __restrict__ w1ih,
    const unsigned short* __restrict__ w1hh,
    const unsigned short* __restrict__ b1ih,
    const unsigned short* __restrict__ b1hh,
    float* __restrict__ s_out,
    const unsigned int* __restrict__ flagp,
    unsigned int* __restrict__ seq,
    unsigned short* __restrict__ hb)
{
    __shared__ __align__(16) unsigned short w0hhL[4 * 24 * 512];

    const bool isb = (*flagp != 0);
    const int tid  = threadIdx.x;
    const int lane = tid & 63;
    const int wv   = tid >> 6;
    const int l15  = lane & 15;
    const int quad = lane >> 4;
    const int q    = blockIdx.x >> 5;
    const int g    = blockIdx.x & 31;
    const int m0   = g * 16;
    const int c    = q * 64 + wv * 16 + l15;

    bf16x8 w0ihr[3][4];
    #pragma unroll
    for (int u = 0; u < 3; ++u)
        #pragma unroll
        for (int kc = 0; kc < 4; ++kc)
            w0ihr[u][kc] = ldb8g(w0ih + (u * 256 + c) * IN_ + kc * 32 + quad * 8);

    bf16x8 w1ihr[3][8], w1hhr[3][8];
    #pragma unroll
    for (int u = 0; u < 3; ++u)
        #pragma unroll
        for (int kc = 0; kc < 8; ++kc){
            w1ihr[u][kc] = ldb8g(w1ih + (u * 256 + c) * H_ + kc * 32 + quad * 8);
            w1hhr[u][kc] = ldb8g(w1hh + (u * 256 + c) * H_ + kc * 32 + quad * 8);
        }

    const int wl = wv * 12288 + lane * 8;
    #pragma unroll
    for (int u = 0; u < 3; ++u)
        #pragma unroll
        for (int kc = 0; kc < 8; ++kc){
            const bf16x8 f = ldb8g(w0hh + (u * 256 + c) * H_ + kc * 32 + quad * 8);
            *(bf16x8*)&w0hhL[wl + (u * 8 + kc) * 512] = f;
        }

    const float brz0a = bf2f(b0ih[c])       + bf2f(b0hh[c]);
    const float brz0b = bf2f(b0ih[256 + c]) + bf2f(b0hh[256 + c]);
    const float bni0v = bf2f(b0ih[512 + c]);
    const float bnh0v = bf2f(b0hh[512 + c]);
    const float brz1a = bf2f(b1ih[c])       + bf2f(b1hh[c]);
    const float brz1b = bf2f(b1ih[256 + c]) + bf2f(b1hh[256 + c]);
    const float bni1v = bf2f(b1ih[512 + c]);
    const float bnh1v = bf2f(b1hh[512 + c]);
    __syncthreads();

    float h0r[4] = {0.f, 0.f, 0.f, 0.f};
    float h1r[4] = {0.f, 0.f, 0.f, 0.f};

    const size_t xrow = (size_t)(m0 + l15) * (T_ * IN_) + quad * 8;
    const unsigned short* pxb = (const unsigned short*)xv + xrow;
    const float*          pxf = (const float*)xv + xrow;

    unsigned int* sq = seq + g * 32;
    const int wr_row[4] = {(quad * 4 + 0) * 256 + c, (quad * 4 + 1) * 256 + c,
                           (quad * 4 + 2) * 256 + c, (quad * 4 + 3) * 256 + c};

    const f32x4 z4 = {0.f, 0.f, 0.f, 0.f};
    bf16x8 h0A[8], h1A[8];
    #pragma unroll
    for (int kc = 0; kc < 8; ++kc){
        h0A[kc] = (bf16x8)(short)0;
        h1A[kc] = (bf16x8)(short)0;
    }

    #pragma unroll 1
    for (int t = 0; t < T_; ++t){
        const int par = t & 1;
        const unsigned int tgt = 4u * (unsigned)(t + 1);
        unsigned short* plane = hb + par * PL_ + g * (2 * 4096);

        #pragma unroll
        for (int j = 0; j < 4; ++j)
            __hip_atomic_store(&plane[4096 + wr_row[j]], f2bf(h1r[j]),
                               __ATOMIC_RELAXED, __HIP_MEMORY_SCOPE_AGENT);

        bf16x8 ax[4];
        if (isb){
            #pragma unroll
            for (int kc = 0; kc < 4; ++kc) ax[kc] = ldb8g(pxb + t * IN_ + kc * 32);
        } else {
            #pragma unroll
            for (int kc = 0; kc < 4; ++kc){
                const float* p = pxf + t * IN_ + kc * 32;
                const float4 f0 = *(const float4*)p;
                const float4 f1 = *(const float4*)(p + 4);
                bf16x8 a;
                a[0] = (short)f2bf(f0.x); a[1] = (short)f2bf(f0.y);
                a[2] = (short)f2bf(f0.z); a[3] = (short)f2bf(f0.w);
                a[4] = (short)f2bf(f1.x); a[5] = (short)f2bf(f1.y);
                a[6] = (short)f2bf(f1.z); a[7] = (short)f2bf(f1.w);
                ax[kc] = a;
            }
        }

        f32x4 Tr = z4, Tz = z4, Tni = z4, Tnh = z4;
        #pragma unroll
        for (int kc = 0; kc < 4; ++kc){
            Tr  = MFMA16(ax[kc], w0ihr[0][kc], Tr);
            Tz  = MFMA16(ax[kc], w0ihr[1][kc], Tz);
            Tni = MFMA16(ax[kc], w0ihr[2][kc], Tni);
        }
        #pragma unroll
        for (int kc = 0; kc < 8; ++kc){
            const bf16x8 a = h0A[kc];
            Tr  = MFMA16(a, *(const bf16x8*)&w0hhL[wl + (0 * 8 + kc) * 512], Tr);
            Tz  = MFMA16(a, *(const bf16x8*)&w0hhL[wl + (1 * 8 + kc) * 512], Tz);
            Tnh = MFMA16(a, *(const bf16x8*)&w0hhL[wl + (2 * 8 + kc) * 512], Tnh);
        }
        #pragma unroll
        for (int j = 0; j < 4; ++j){
            const float rr = sig_(Tr[j] + brz0a);
            const float zz = sig_(Tz[j] + brz0b);
            const float nn = tanh_(Tni[j] + bni0v + rr * (Tnh[j] + bnh0v));
            h0r[j] = (1.0f - zz) * nn + zz * h0r[j];
        }

        #pragma unroll
        for (int j = 0; j < 4; ++j)
            __hip_atomic_store(&plane[wr_row[j]], f2bf(h0r[j]),
                               __ATOMIC_RELAXED, __HIP_MEMORY_SCOPE_AGENT);

        __syncthreads();
        if (tid == 0)
            __hip_atomic_fetch_add(sq, 1u, __ATOMIC_RELAXED, __HIP_MEMORY_SCOPE_AGENT);
        if (lane == 0){
            while (__hip_atomic_load(sq, __ATOMIC_RELAXED, __HIP_MEMORY_SCOPE_AGENT) < tgt)
                __builtin_amdgcn_s_sleep(1);
        }
        __atomic_signal_fence(__ATOMIC_ACQ_REL);

        {
            const unsigned short* r0 = plane + l15 * 256 + quad * 8;
            #pragma unroll
            for (int kc = 0; kc < 8; ++kc){
                U64x2 u0, u1;
                u0.q[0] = __hip_atomic_load((const unsigned long long*)(r0 + kc * 32),
                                            __ATOMIC_RELAXED, __HIP_MEMORY_SCOPE_AGENT);
                u0.q[1] = __hip_atomic_load((const unsigned long long*)(r0 + kc * 32 + 4),
                                            __ATOMIC_RELAXED, __HIP_MEMORY_SCOPE_AGENT);
                u1.q[0] = __hip_atomic_load((const unsigned long long*)(r0 + 4096 + kc * 32),
                                            __ATOMIC_RELAXED, __HIP_MEMORY_SCOPE_AGENT);
                u1.q[1] = __hip_atomic_load((const unsigned long long*)(r0 + 4096 + kc * 32 + 4),
                                            __ATOMIC_RELAXED, __HIP_MEMORY_SCOPE_AGENT);
                h0A[kc] = u0.v;
                h1A[kc] = u1.v;
            }
        }

        Tr = z4; Tz = z4; Tni = z4; Tnh = z4;
        #pragma unroll
        for (int kc = 0; kc < 8; ++kc){
            const bf16x8 a0 = h0A[kc];
            const bf16x8 a1 = h1A[kc];
            Tr  = MFMA16(a0, w1ihr[0][kc], Tr);
            Tr  = MFMA16(a1, w1hhr[0][kc], Tr);
            Tz  = MFMA16(a0, w1ihr[1][kc], Tz);
            Tz  = MFMA16(a1, w1hhr[1][kc], Tz);
            Tni = MFMA16(a0, w1ihr[2][kc], Tni);
            Tnh = MFMA16(a1, w1hhr[2][kc], Tnh);
        }
        #pragma unroll
        for (int j = 0; j < 4; ++j){
            const float rr = sig_(Tr[j] + brz1a);
            const float zz = sig_(Tz[j] + brz1b);
            const float nn = tanh_(Tni[j] + bni1v + rr * (Tnh[j] + bnh1v));
            h1r[j] = (1.0f - zz) * nn + zz * h1r[j];
        }
    }

    #pragma unroll
    for (int j = 0; j < 4; ++j)
        s_out[(size_t)(m0 + quad * 4 + j) * H_ + c] = h1r[j];
}

// ---------------------------------------------------------------------------
// B-spline basis (uniform grid, GRID_SIZE=5, ORDER=3)
// ---------------------------------------------------------------------------
__device__ __forceinline__ float knot_(int p){ return (float)(p - 3) * 0.4f - 1.0f; }

__device__ __forceinline__ void bspline8(float xv, float* bb8){
    float bb[11];
    #pragma unroll
    for (int p = 0; p < 11; ++p)
        bb[p] = (xv >= knot_(p) && xv < knot_(p + 1)) ? 1.f : 0.f;
    #pragma unroll
    for (int k = 1; k <= 3; ++k){
        #pragma unroll
        for (int p = 0; p <= 10 - k; ++p){
            const float tp = knot_(p), tpk = knot_(p + k);
            const float tp1 = knot_(p + 1), tpk1 = knot_(p + k + 1);
            bb[p] = (xv - tp) / (tpk - tp) * bb[p] + (tpk1 - xv) / (tpk1 - tp1) * bb[p + 1];
        }
    }
    #pragma unroll
    for (int j = 0; j < 8; ++j) bb8[j] = bb[j];
}

// single-step zero-state LSTM unit (gate order i,f,g,o; f unused)
__device__ __forceinline__ float lstm_unit(const float* sxv, const unsigned short* w,
                                           const unsigned short* bi, const unsigned short* bh,
                                           int uu){
    const unsigned short* wi = w + (size_t)uu * 256;
    const unsigned short* wg = w + (size_t)(256 + uu) * 256;
    const unsigned short* wo = w + (size_t)(384 + uu) * 256;
    float ai = 0.f, ag = 0.f, ao = 0.f;
    for (int k = 0; k < 256; k += 8){
        const bf16x8 vi = ldb8g(wi + k);
        const bf16x8 vg = ldb8g(wg + k);
        const bf16x8 vo = ldb8g(wo + k);
        #pragma unroll
        for (int j = 0; j < 8; ++j){
            const float s = sxv[k + j];
            ai += bf2f((unsigned short)vi[j]) * s;
            ag += bf2f((unsigned short)vg[j]) * s;
            ao += bf2f((unsigned short)vo[j]) * s;
        }
    }
    const float gi = ai + bf2f(bi[uu])       + bf2f(bh[uu]);
    const float gg = ag + bf2f(bi[256 + uu]) + bf2f(bh[256 + uu]);
    const float go = ao + bf2f(bi[384 + uu]) + bf2f(bh[384 + uu]);
    return sig_(go) * tanh_(sig_(gi) * tanh_(gg));
}

// ---------------------------------------------------------------------------
// Fused tail: lstm0(fwd+rev) -> lstm1(fwd+rev) -> kan1 -> kan2, all row-local.
// ---------------------------------------------------------------------------
__global__ __launch_bounds__(256) void srt_tail(
    const float* __restrict__ in,
    const unsigned short* __restrict__ w0f, const unsigned short* __restrict__ bi0f,
    const unsigned short* __restrict__ bh0f,
    const unsigned short* __restrict__ w0r, const unsigned short* __restrict__ bi0r,
    const unsigned short* __restrict__ bh0r,
    const unsigned short* __restrict__ w1f, const unsigned short* __restrict__ bi1f,
    const unsigned short* __restrict__ bh1f,
    const unsigned short* __restrict__ w1r, const unsigned short* __restrict__ bi1r,
    const unsigned short* __restrict__ bh1r,
    const unsigned short* __restrict__ k1b, const unsigned short* __restrict__ k1s,
    const unsigned short* __restrict__ k1c,
    const unsigned short* __restrict__ k2b, const unsigned short* __restrict__ k2s,
    const unsigned short* __restrict__ k2c,
    void* __restrict__ outp,
    const unsigned int* __restrict__ flagp)
{
    __shared__ float sx[256];
    __shared__ float sy[256];
    __shared__ float sil[256];
    __shared__ float spl[256][8];
    __shared__ float red[64][4];
    __shared__ float sil2[64];
    __shared__ float spl2[64][8];

    const int b = blockIdx.x, tid = threadIdx.x;
    const int dir = tid >> 7, uu = tid & 127;

    sx[tid] = in[b * 256 + tid];
    __syncthreads();

    sy[tid] = lstm_unit(sx, dir ? w0r : w0f, dir ? bi0r : bi0f, dir ? bh0r : bh0f, uu);
    __syncthreads();

    const float o1v = lstm_unit(sy, dir ? w1r : w1f, dir ? bi1r : bi1f, dir ? bh1r : bh1f, uu);

    sil[tid] = o1v * sig_(o1v);
    float bb[8];
    bspline8(o1v, bb);
    #pragma unroll
    for (int j = 0; j < 8; ++j) spl[tid][j] = bb[j];
    __syncthreads();

    const int o = tid >> 2, qq = tid & 3;
    float acc = 0.f;
    for (int k = qq * 64; k < qq * 64 + 64; ++k){
        acc += sil[k] * bf2f(k1b[o * 256 + k]);
        float t = 0.f;
        #pragma unroll
        for (int j = 0; j < 8; ++j) t += spl[k][j] * bf2f(k1s[(o * 256 + k) * 8 + j]);
        acc += t * bf2f(k1c[o * 256 + k]);
    }
    red[o][qq] = acc;
    __syncthreads();

    if (tid < 64){
        const float zv = red[tid][0] + red[tid][1] + red[tid][2] + red[tid][3];
        sil2[tid] = zv * sig_(zv);
        float b2[8];
        bspline8(zv, b2);
        #pragma unroll
        for (int j = 0; j < 8; ++j) spl2[tid][j] = b2[j];
    }
    __syncthreads();

    if (tid < 10){
        float a2 = 0.f;
        for (int k = 0; k < 64; ++k){
            a2 += sil2[k] * bf2f(k2b[tid * 64 + k]);
            float t = 0.f;
            #pragma unroll
            for (int j = 0; j < 8; ++j) t += spl2[k][j] * bf2f(k2s[(tid * 64 + k) * 8 + j]);
            a2 += t * bf2f(k2c[tid * 64 + k]);
        }
        if (*flagp) ((unsigned short*)outp)[b * 10 + tid] = f2bf(a2);
        else        ((float*)outp)[b * 10 + tid] = a2;
    }
}

extern "C" void kernel_launch(void* const* d_in, const int* in_sizes, int n_in,
                              void* d_out, int out_size, void* d_ws, size_t ws_size,
                              hipStream_t stream)
{
    unsigned int* flag = (unsigned int*)d_ws;
    float* s = (float*)((char*)d_ws + 16);            // final h1 (fp32)
    unsigned short* wb = (unsigned short*)(s + 512 * 256);

    const int idxs[26] = {1,2,3,4,5,6,7,8, 9,11,12, 13,15,16, 17,19,20, 21,23,24,
                          25,26,27, 28,29,30};
    ConvTab ct;
    int off = 0;
    int offs[26];
    for (int j = 0; j < 26; ++j){
        ct.src[j] = d_in[idxs[j]];
        ct.n[j]   = in_sizes[idxs[j]];
        ct.off[j] = off;
        offs[j]   = off;
        off += in_sizes[idxs[j]];
    }
    uintptr_t p = (uintptr_t)(wb + off);
    p = (p + 255) & ~(uintptr_t)255;
    unsigned int* seq = (unsigned int*)p;                 // fallback counters
    unsigned short* hb = (unsigned short*)(seq + 1024);   // fallback exchange buf
    p = (uintptr_t)(hb + 2 * 32 * 2 * 4096);
    p = (p + 255) & ~(uintptr_t)255;
    float* h0s   = (float*)p;                             // 512*256 fp32 layer-0 state
    float* bias0 = h0s + 512 * 256;
    float* bias1 = bias0 + 768;
    p = (uintptr_t)(bias1 + 768);
    p = (p + 255) & ~(uintptr_t)255;
    char* dyn = (char*)p;
    const size_t used = (size_t)(dyn - (char*)d_ws);

    const size_t slab_gi = (size_t)TCp * 512 * 768;   // shorts
    const size_t slab_ha = (size_t)TCp * 512 * 256;
    const size_t pipe_need = used + (4 * slab_gi + 2 * slab_ha) * sizeof(unsigned short);
    const bool pipe_ok = pipe_need <= ws_size;

    const unsigned short *w0ih = wb + offs[0],  *w0hh = wb + offs[1];
    const unsigned short *b0ih = wb + offs[2],  *b0hh = wb + offs[3];
    const unsigned short *w1ih = wb + offs[4],  *w1hh = wb + offs[5];
    const unsigned short *b1ih = wb + offs[6],  *b1hh = wb + offs[7];
    const unsigned short *lwih0  = wb + offs[8],  *lbih0  = wb + offs[9],  *lbhh0  = wb + offs[10];
    const unsigned short *lwih0r = wb + offs[11], *lbih0r = wb + offs[12], *lbhh0r = wb + offs[13];
    const unsigned short *lwih1  = wb + offs[14], *lbih1  = wb + offs[15], *lbhh1  = wb + offs[16];
    const unsigned short *lwih1r = wb + offs[17], *lbih1r = wb + offs[18], *lbhh1r = wb + offs[19];
    const unsigned short *k1b = wb + offs[20], *k1s = wb + offs[21], *k1c = wb + offs[22];
    const unsigned short *k2b = wb + offs[23], *k2s = wb + offs[24], *k2c = wb + offs[25];

    srt_detect<<<1, 64, 0, stream>>>((const unsigned int*)d_in[0], flag);
    srt_conv<<<1024, 256, 0, stream>>>(ct, wb, flag);
    srt_prep<<<512, 256, 0, stream>>>(h0s, s, bias0, bias1, b0ih, b0hh, b1ih, b1hh, seq);

    if (pipe_ok){
        unsigned short* gi0a = (unsigned short*)dyn;
        unsigned short* gi0b = gi0a + slab_gi;
        unsigned short* haa  = gi0b + slab_gi;
        unsigned short* hab  = haa + slab_ha;
        unsigned short* gi1a = hab + slab_ha;
        unsigned short* gi1b = gi1a + slab_gi;

        PA a;
        a.xv = d_in[0]; a.flag = flag;
        a.w0ih = w0ih; a.w0hh = w0hh; a.b0hh = b0hh;
        a.w1ih = w1ih; a.w1hh = w1hh; a.b1hh = b1hh;
        a.bias0 = bias0; a.bias1 = bias1;
        a.h0s = h0s; a.h1s = s;
        a.gi0a = gi0a; a.gi0b = gi0b; a.haa = haa; a.hab = hab;
        a.gi1a = gi1a; a.gi1b = gi1b;
        for (int ph = 0; ph <= NCp + 2; ++ph){
            a.p = ph;
            srt_phase<<<576, 512, 0, stream>>>(a);
        }
    } else {
        srt_gru<<<128, 256, 0, stream>>>(d_in[0], w0ih, w0hh, b0ih, b0hh,
                                         w1ih, w1hh, b1ih, b1hh, s, flag, seq, hb);
    }

    srt_tail<<<512, 256, 0, stream>>>(s,
        lwih0, lbih0, lbhh0, lwih0r, lbih0r, lbhh0r,
        lwih1, lbih1, lbhh1, lwih1r, lbih1r, lbhh1r,
        k1b, k1s, k1c, k2b, k2s, k2c, d_out, flag);
}

// Round 5
// 1752.106 us; speedup vs baseline: 3.8728x; 1.0124x over previous
//
#include <hip/hip_runtime.h>
#include <stdint.h>

// SRTKAN v6:
//  - gemm role: ring-3 W double-buffering with COUNTED vmcnt waits + raw s_barrier
//    (never vmcnt(0) in the loop) so W chunk loads stay in flight across barriers.
//    A resident in LDS. One barrier per 16-MFMA iteration.
//  - srt_tail: 1024 threads, 4-way k-split LSTM dots (LDS partial reduce), 16-way
//    KAN1/KAN2 split. Serial chains /4, occupancy 25%->~100% of grid capacity.
//  - phase pipeline unchanged (seq0 | seq1 | gemmx | gemm1 roles, TCp=64, ring-2 slabs).

constexpr int B_  = 512;
constexpr int T_  = 512;
constexpr int IN_ = 128;
constexpr int H_  = 256;
constexpr int GR_ = 32;                   // batch groups (fallback path)
constexpr int PL_ = GR_ * 2 * 4096;       // elements per parity plane (fallback path)
constexpr int TCp = 64;                   // pipeline chunk (T steps)
constexpr int NCp = 8;                    // chunks

typedef __attribute__((ext_vector_type(8))) short bf16x8;
typedef __attribute__((ext_vector_type(4))) float f32x4;

#define MFMA16(a, b, c) __builtin_amdgcn_mfma_f32_16x16x32_bf16((a), (b), (c), 0, 0, 0)

__device__ __forceinline__ float bf2f(unsigned short u){
    union { unsigned int i; float f; } v; v.i = ((unsigned int)u) << 16; return v.f;
}
__device__ __forceinline__ unsigned short f2bf(float f){
    union { float f; unsigned int i; } v; v.f = f;
    return (unsigned short)((v.i + 0x7FFFu + ((v.i >> 16) & 1u)) >> 16); // RNE
}
__device__ __forceinline__ unsigned int cvtpk(float a, float b){
    unsigned int r;
    asm("v_cvt_pk_bf16_f32 %0, %1, %2" : "=v"(r) : "v"(a), "v"(b));
    return r;
}
__device__ __forceinline__ unsigned long long pk4(float a, float b, float c, float d){
    const unsigned int lo = cvtpk(a, b), hi = cvtpk(c, d);
    return (unsigned long long)lo | ((unsigned long long)hi << 32);
}
__device__ __forceinline__ float sig_(float x){
    return __builtin_amdgcn_rcpf(1.0f + __expf(-x));
}
__device__ __forceinline__ float tanh_(float x){
    return 1.0f - 2.0f * __builtin_amdgcn_rcpf(1.0f + __expf(2.0f * x));
}
__device__ __forceinline__ bf16x8 ldb8g(const unsigned short* p){ return *(const bf16x8*)p; }

union U64x2 { unsigned long long q[2]; bf16x8 v; };

__device__ __forceinline__ void gl2lds16(const void* g, void* l){
    __builtin_amdgcn_global_load_lds(
        (const __attribute__((address_space(1))) unsigned int*)g,
        (__attribute__((address_space(3))) unsigned int*)l, 16, 0, 0);
}

// ---------------------------------------------------------------------------
// dtype detect
// ---------------------------------------------------------------------------
__global__ void srt_detect(const unsigned int* __restrict__ xw, unsigned int* __restrict__ flag){
    int cnt = 0;
    for (int i = threadIdx.x; i < 1024; i += 64){
        const unsigned int lo = xw[i] & 0xFFFFu;
        const int e = (int)((lo >> 7) & 0xFFu);
        if (e >= 100 && e <= 140) cnt++;
    }
    #pragma unroll
    for (int o = 32; o > 0; o >>= 1) cnt += __shfl_down(cnt, o);
    if (threadIdx.x == 0) *flag = (cnt > 614) ? 1u : 0u;   // 1 = bf16 inputs
}

// ---------------------------------------------------------------------------
// stage weights as bf16
// ---------------------------------------------------------------------------
struct ConvTab { const void* src[26]; int n[26]; int off[26]; };

__global__ __launch_bounds__(256) void srt_conv(ConvTab ct, unsigned short* __restrict__ wb,
                                                const unsigned int* __restrict__ flag){
    const bool isb = (*flag != 0);
    const int gsz = gridDim.x * blockDim.x;
    const int gid = blockIdx.x * blockDim.x + threadIdx.x;
    for (int j = 0; j < 26; ++j){
        const int n = ct.n[j];
        unsigned short* o = wb + ct.off[j];
        if (isb){
            const unsigned short* s = (const unsigned short*)ct.src[j];
            for (int i = gid; i < n; i += gsz) o[i] = s[i];
        } else {
            const float* s = (const float*)ct.src[j];
            for (int i = gid; i < n; i += gsz) o[i] = f2bf(s[i]);
        }
    }
}

// ---------------------------------------------------------------------------
// prep: zero states/counters; fold biases: bias[n] = bih[n] + (n<512 ? bhh[n] : 0)
// ---------------------------------------------------------------------------
__global__ __launch_bounds__(256) void srt_prep(
    float* __restrict__ h0s, float* __restrict__ h1s,
    float* __restrict__ bias0, float* __restrict__ bias1,
    const unsigned short* __restrict__ b0ih, const unsigned short* __restrict__ b0hh,
    const unsigned short* __restrict__ b1ih, const unsigned short* __restrict__ b1hh,
    unsigned int* __restrict__ seq)
{
    const int gid = blockIdx.x * blockDim.x + threadIdx.x;  // grid 512*256
    h0s[gid] = 0.f;
    h1s[gid] = 0.f;
    if (gid < 768){
        bias0[gid] = bf2f(b0ih[gid]) + (gid < 512 ? bf2f(b0hh[gid]) : 0.f);
        bias1[gid] = bf2f(b1ih[gid]) + (gid < 512 ? bf2f(b1hh[gid]) : 0.f);
    }
    if (gid < 1024) seq[gid] = 0u;
}

// ---------------------------------------------------------------------------
// seq role: one GRU layer, TC steps, 16 batch rows (group bg), 512 threads.
// (unchanged from v5 — measured 58us/chunk)
// shm carve: wnL[32768] | hbuf[2*4096] | gib[2*12288]
// ---------------------------------------------------------------------------
__device__ void seq_dev(unsigned short* shm,
    const unsigned short* __restrict__ gi,
    const unsigned short* __restrict__ whh,
    const unsigned short* __restrict__ bhh,
    float* __restrict__ hstate,
    unsigned short* __restrict__ h_all,
    const int TC, const int bg)
{
    unsigned short* wnL   = shm;
    unsigned short* hbufB = shm + 32768;
    unsigned short* gibB  = shm + 32768 + 8192;

    const int tid  = threadIdx.x;
    const int lane = tid & 63;
    const int wv   = tid >> 6;
    const int l15  = lane & 15;
    const int quad = lane >> 4;
    const int m0   = bg * 16;
    const int swz  = (l15 & 7) << 4;

    bf16x8 wr[5][8];
    #pragma unroll
    for (int fi = 0; fi < 6; ++fi){
        const int u = fi >> 1, ii = fi & 1;
        const unsigned short* wp =
            whh + (size_t)(u * 256 + wv * 32 + ii * 16 + l15) * 256 + quad * 8;
        if (fi < 5){
            #pragma unroll
            for (int kc = 0; kc < 8; ++kc) wr[fi][kc] = ldb8g(wp + kc * 32);
        } else {
            #pragma unroll
            for (int kc = 0; kc < 8; ++kc)
                *(bf16x8*)&wnL[((wv * 8 + kc) << 9) + lane * 8] = ldb8g(wp + kc * 32);
        }
    }

    f32x4 bn0[2];
    #pragma unroll
    for (int ii = 0; ii < 2; ++ii)
        #pragma unroll
        for (int j = 0; j < 4; ++j)
            bn0[ii][j] = bf2f(bhh[512 + wv * 32 + ii * 16 + quad * 4 + j]);

    f32x4 hr[2];
    #pragma unroll
    for (int ii = 0; ii < 2; ++ii)
        hr[ii] = *(const f32x4*)&hstate[(size_t)(m0 + l15) * 256 + wv * 32 + ii * 16 + quad * 4];

    const unsigned short* gpp[3]; int gdl[3];
    #pragma unroll
    for (int i = 0; i < 3; ++i){
        const int g_  = i * 512 + tid;
        const int row = g_ / 96;
        const int cg  = g_ - row * 96;
        gpp[i] = gi + ((size_t)m0 + row) * 768 + ((cg ^ (row & 7)) << 3);
        gdl[i] = g_ * 8;
    }

    #pragma unroll
    for (int ii = 0; ii < 2; ++ii){
        const unsigned long long pk = pk4(hr[ii][0], hr[ii][1], hr[ii][2], hr[ii][3]);
        *(unsigned long long*)((char*)hbufB + l15 * 512 +
            ((wv * 64 + ii * 32 + quad * 8) ^ swz)) = pk;
    }
    #pragma unroll
    for (int i = 0; i < 3; ++i) gl2lds16(gpp[i], &gibB[gdl[i]]);
    __syncthreads();

    #pragma unroll 1
    for (int t = 0; t < TC; ++t){
        const int par = t & 1;
        unsigned short* hb_cur = hbufB + par * 4096;
        unsigned short* hb_nxt = hbufB + (par ^ 1) * 4096;
        unsigned short* gb_cur = gibB + par * 12288;
        unsigned short* gb_nxt = gibB + (par ^ 1) * 12288;

        if (t + 1 < TC){
            const size_t toff = (size_t)(t + 1) * (512 * 768);
            #pragma unroll
            for (int i = 0; i < 3; ++i) gl2lds16(gpp[i] + toff, &gb_nxt[gdl[i]]);
        }

        f32x4 aR0 = {0,0,0,0}, aR1 = {0,0,0,0}, aZ0 = {0,0,0,0}, aZ1 = {0,0,0,0};
        f32x4 aN0 = bn0[0], aN1 = bn0[1];
        __builtin_amdgcn_s_setprio(1);
        #pragma unroll
        for (int kc = 0; kc < 8; ++kc){
            const bf16x8 hb = *(const bf16x8*)((const char*)hb_cur +
                l15 * 512 + ((kc * 64 + quad * 16) ^ swz));
            const bf16x8 w5 = *(const bf16x8*)&wnL[((wv * 8 + kc) << 9) + lane * 8];
            aR0 = MFMA16(wr[0][kc], hb, aR0);
            aR1 = MFMA16(wr[1][kc], hb, aR1);
            aZ0 = MFMA16(wr[2][kc], hb, aZ0);
            aZ1 = MFMA16(wr[3][kc], hb, aZ1);
            aN0 = MFMA16(wr[4][kc], hb, aN0);
            aN1 = MFMA16(w5,        hb, aN1);
        }
        __builtin_amdgcn_s_setprio(0);

        const char* gbase = (const char*)gb_cur + l15 * 1536;
        #pragma unroll
        for (int ii = 0; ii < 2; ++ii){
            const int cb = wv * 64 + ii * 32 + quad * 8;
            const unsigned long long qr = *(const unsigned long long*)(gbase + ((       cb) ^ swz));
            const unsigned long long qz = *(const unsigned long long*)(gbase + ((512  + cb) ^ swz));
            const unsigned long long qn = *(const unsigned long long*)(gbase + ((1024 + cb) ^ swz));
            const f32x4 aR = ii ? aR1 : aR0;
            const f32x4 aZ = ii ? aZ1 : aZ0;
            const f32x4 aN = ii ? aN1 : aN0;
            #pragma unroll
            for (int j = 0; j < 4; ++j){
                const float rr = sig_(aR[j] + bf2f((unsigned short)(qr >> (16 * j))));
                const float zz = sig_(aZ[j] + bf2f((unsigned short)(qz >> (16 * j))));
                const float nn = tanh_(bf2f((unsigned short)(qn >> (16 * j))) + rr * aN[j]);
                hr[ii][j] = (1.0f - zz) * nn + zz * hr[ii][j];
            }
        }

        #pragma unroll
        for (int ii = 0; ii < 2; ++ii){
            const unsigned long long pk = pk4(hr[ii][0], hr[ii][1], hr[ii][2], hr[ii][3]);
            *(unsigned long long*)((char*)hb_nxt + l15 * 512 +
                ((wv * 64 + ii * 32 + quad * 8) ^ swz)) = pk;
            if (h_all)
                *(unsigned long long*)(h_all + ((size_t)t * 512 + m0 + l15) * 256 +
                    wv * 32 + ii * 16 + quad * 4) = pk;
        }

        __syncthreads();
    }

    #pragma unroll
    for (int ii = 0; ii < 2; ++ii)
        *(f32x4*)&hstate[(size_t)(m0 + l15) * 256 + wv * 32 + ii * 16 + quad * 4] = hr[ii];
}

// ---------------------------------------------------------------------------
// gemm role v2: counted-vmcnt pipeline. C[r][768] = A[r][K] @ W[768][K]^T + bias.
// A resident (staged once); W ring-3 16KB chunks, loads IN FLIGHT across barriers:
// per iter: wait vmcnt(N) [chunk i done, i+1 pending] -> s_barrier -> sched_barrier
// -> issue chunk i+2 -> frag reads + 16 MFMA. Stores pollute vmcnt; Nb-boundary
// iterations use vmcnt(10) (8 stores + 2 loads of chunk i+1 may stay pending).
// shm carve: Ares[128*K] at 0 | Wb[3] 8192-short bufs at 32768(+8192 each).
// ---------------------------------------------------------------------------
template<int K, bool XS>
__device__ void gemm_dev(unsigned short* shm, const void* Asrc, const bool isb,
                         const int t0, const unsigned short* __restrict__ W,
                         const float* __restrict__ bias,
                         unsigned short* __restrict__ C, const int mb)
{
    unsigned short* Ares = shm;            // 128*K shorts (<= 32768)

    const int tid = threadIdx.x;           // 0..511
    const int lane = tid & 63, wv = tid >> 6;
    const int l15 = lane & 15, quad = lane >> 4;
    const int rh = wv & 1, fq = wv >> 1;   // row-half (64), feat-quarter (32)

    constexpr int GPT = K / 32;            // A granules per thread
    constexpr int GPR = K / 8;             // A granules per row
    constexpr int NK  = K / 64;            // W chunks per N-tile
    constexpr int NIT = 6 * NK;

    // ---- stage A tile (128 x K bf16), granule-XOR swizzled by row&7
    if (!XS || isb){
        #pragma unroll
        for (int i = 0; i < GPT; ++i){
            const int g_ = i * 512 + tid;
            const int row = g_ / GPR, cg = g_ % GPR;
            size_t src;
            if (XS){
                const int r = mb * 128 + row;
                const int b = r & 511, tt = r >> 9;
                src = ((size_t)b * 512 + (t0 + tt)) * 128 + ((cg ^ (row & 7)) << 3);
            } else {
                src = (size_t)(mb * 128 + row) * K + ((cg ^ (row & 7)) << 3);
            }
            gl2lds16((const unsigned short*)Asrc + src, &Ares[g_ * 8]);
        }
    } else {
        #pragma unroll
        for (int i = 0; i < GPT; ++i){
            const int g_ = i * 512 + tid;
            const int row = g_ / GPR, cg = g_ % GPR;
            const int r = mb * 128 + row;
            const int b = r & 511, tt = r >> 9;
            const float* p = (const float*)Asrc + ((size_t)b * 512 + (t0 + tt)) * 128 + cg * 8;
            const float4 f0 = *(const float4*)p;
            const float4 f1 = *(const float4*)(p + 4);
            uint4 u;
            u.x = cvtpk(f0.x, f0.y); u.y = cvtpk(f0.z, f0.w);
            u.z = cvtpk(f1.x, f1.y); u.w = cvtpk(f1.z, f1.w);
            *(uint4*)&Ares[(row * GPR + (cg ^ (row & 7))) * 8] = u;
        }
    }

    // W chunk stager: iter i -> Nb = i/NK, k0 = (i%NK)*64, dest ring buf i%3
    auto stageW = [&](int i){
        const int Nb = i / NK, k0 = (i % NK) * 64;
        unsigned short* dst = shm + 32768 + (i % 3) * 8192;
        #pragma unroll
        for (int j = 0; j < 2; ++j){
            const int g_ = j * 512 + tid;
            const int row = g_ >> 3, cg = g_ & 7;
            gl2lds16(W + (size_t)(Nb * 128 + row) * K + k0 + ((cg ^ (row & 7)) << 3),
                     &dst[g_ * 8]);
        }
    };

    stageW(0);
    stageW(1);
    if (XS && !isb) asm volatile("s_waitcnt lgkmcnt(0)" ::: "memory");

    for (int Nb = 0; Nb < 6; ++Nb){
        f32x4 acc[4][2];
        #pragma unroll
        for (int mi = 0; mi < 4; ++mi){
            acc[mi][0] = (f32x4){0,0,0,0};
            acc[mi][1] = (f32x4){0,0,0,0};
        }

        #pragma unroll
        for (int kk = 0; kk < NK; ++kk){
            const int i = Nb * NK + kk;
            // chunk i must be complete; chunk i+1 (2 loads) may stay in flight.
            // At Nb boundaries 8 C-stores (newest) may also be pending.
            if (Nb == 0 && kk == 0)      asm volatile("s_waitcnt vmcnt(2)"  ::: "memory");
            else if (kk == 0)            asm volatile("s_waitcnt vmcnt(10)" ::: "memory");
            else                         asm volatile("s_waitcnt vmcnt(2)"  ::: "memory");
            __builtin_amdgcn_s_barrier();
            __builtin_amdgcn_sched_barrier(0);
            if (i + 2 < NIT) stageW(i + 2);

            const unsigned short* wbuf = shm + 32768 + (i % 3) * 8192;
            #pragma unroll
            for (int kc = 0; kc < 2; ++kc){
                bf16x8 wf[2], af[4];
                #pragma unroll
                for (int ni = 0; ni < 2; ++ni){
                    const int rf = fq * 32 + ni * 16 + l15;
                    wf[ni] = *(const bf16x8*)((const char*)wbuf +
                        rf * 128 + (((kc * 4 + quad) ^ (rf & 7)) << 4));
                }
                #pragma unroll
                for (int mi = 0; mi < 4; ++mi){
                    const int ra = rh * 64 + mi * 16 + l15;
                    af[mi] = *(const bf16x8*)((const char*)Ares +
                        ra * (2 * K) + (((kk * 8 + kc * 4 + quad) ^ (ra & 7)) << 4));
                }
                #pragma unroll
                for (int mi = 0; mi < 4; ++mi){
                    acc[mi][0] = MFMA16(wf[0], af[mi], acc[mi][0]);
                    acc[mi][1] = MFMA16(wf[1], af[mi], acc[mi][1]);
                }
            }
        }

        // store Nb tile: D[m=feat quad*4+j][n=row l15] -> b64 of 4 features
        float bs[2][4];
        #pragma unroll
        for (int ni = 0; ni < 2; ++ni)
            #pragma unroll
            for (int j = 0; j < 4; ++j)
                bs[ni][j] = bias[Nb * 128 + fq * 32 + ni * 16 + quad * 4 + j];
        #pragma unroll
        for (int mi = 0; mi < 4; ++mi)
            #pragma unroll
            for (int ni = 0; ni < 2; ++ni){
                const unsigned int lo = cvtpk(acc[mi][ni][0] + bs[ni][0],
                                              acc[mi][ni][1] + bs[ni][1]);
                const unsigned int hi = cvtpk(acc[mi][ni][2] + bs[ni][2],
                                              acc[mi][ni][3] + bs[ni][3]);
                const int row = mb * 128 + rh * 64 + mi * 16 + l15;
                const int col = Nb * 128 + fq * 32 + ni * 16 + quad * 4;
                uint2 st; st.x = lo; st.y = hi;
                *(uint2*)(C + (size_t)row * 768 + col) = st;
            }
    }
}

// ---------------------------------------------------------------------------
// phase kernel: roles by blockIdx. grid = 576, block = 512, 128KB LDS.
//  [0,32) seq0(p-1) | [32,64) seq1(p-3) | [64,320) gemmx(p) | [320,576) gemm1(p-2)
// ---------------------------------------------------------------------------
struct PA {
    const void* xv;
    const unsigned int* flag;
    const unsigned short *w0ih, *w0hh, *b0hh, *w1ih, *w1hh, *b1hh;
    const float *bias0, *bias1;
    float *h0s, *h1s;
    unsigned short *gi0a, *gi0b, *haa, *hab, *gi1a, *gi1b;
    int p;
};

__global__ __launch_bounds__(512, 1) void srt_phase(PA a){
    __shared__ __align__(16) unsigned short shm[65536];   // 128 KB
    const int bid = blockIdx.x;
    const int p = a.p;

    if (bid < 32){
        const int c = p - 1; if (c < 0 || c >= NCp) return;
        seq_dev(shm, (c & 1) ? a.gi0b : a.gi0a, a.w0hh, a.b0hh, a.h0s,
                (c & 1) ? a.hab : a.haa, TCp, bid);
    } else if (bid < 64){
        const int c = p - 3; if (c < 0 || c >= NCp) return;
        seq_dev(shm, (c & 1) ? a.gi1b : a.gi1a, a.w1hh, a.b1hh, a.h1s,
                nullptr, TCp, bid - 32);
    } else if (bid < 320){
        const int c = p; if (c >= NCp) return;
        const bool isb = (*a.flag != 0);
        gemm_dev<128, true>(shm, a.xv, isb, c * TCp, a.w0ih, a.bias0,
                            (c & 1) ? a.gi0b : a.gi0a, bid - 64);
    } else {
        const int c = p - 2; if (c < 0 || c >= NCp) return;
        gemm_dev<256, false>(shm, (c & 1) ? a.hab : a.haa, true, 0, a.w1ih, a.bias1,
                             (c & 1) ? a.gi1b : a.gi1a, bid - 320);
    }
}

// ---------------------------------------------------------------------------
// OLD PATH (fallback when ws_size too small): persistent GRU with LLC exchange.
// ---------------------------------------------------------------------------
__global__ __launch_bounds__(256, 1) void srt_gru(
    const void* __restrict__ xv,
    const unsigned short* __restrict__ w0ih,
    const unsigned short* __restrict__ w0hh,
    const unsigned short* __restrict__ b0ih,
    const unsigned short* __restrict__ b0hh,
    const unsigned short* __restrict__ w1ih,
    const unsigned short* __restrict__ w1hh,
    const unsigned short* __restrict__ b1ih,
    const unsigned short* __restrict__ b1hh,
    float* __restrict__ s_out,
    const unsigned int* __restrict__ flagp,
    unsigned int* __restrict__ seq,
    unsigned short* __restrict__ hb)
{
    __shared__ __align__(16) unsigned short w0hhL[4 * 24 * 512];

    const bool isb = (*flagp != 0);
    const int tid  = threadIdx.x;
    const int lane = tid & 63;
    const int wv   = tid >> 6;
    const int l15  = lane & 15;
    const int quad = lane >> 4;
    const int q    = blockIdx.x >> 5;
    const int g    = blockIdx.x & 31;
    const int m0   = g * 16;
    const int c    = q * 64 + wv * 16 + l15;

    bf16x8 w0ihr[3][4];
    #pragma unroll
    for (int u = 0; u < 3; ++u)
        #pragma unroll
        for (int kc = 0; kc < 4; ++kc)
            w0ihr[u][kc] = ldb8g(w0ih + (u * 256 + c) * IN_ + kc * 32 + quad * 8);

    bf16x8 w1ihr[3][8], w1hhr[3][8];
    #pragma unroll
    for (int u = 0; u < 3; ++u)
        #pragma unroll
        for (int kc = 0; kc < 8; ++kc){
            w1ihr[u][kc] = ldb8g(w1ih + (u * 256 + c) * H_ + kc * 32 + quad * 8);
            w1hhr[u][kc] = ldb8g(w1hh + (u * 256 + c) * H_ + kc * 32 + quad * 8);
        }

    const int wl = wv * 12288 + lane * 8;
    #pragma unroll
    for (int u = 0; u < 3; ++u)
        #pragma unroll
        for (int kc = 0; kc < 8; ++kc){
            const bf16x8 f = ldb8g(w0hh + (u * 256 + c) * H_ + kc * 32 + quad * 8);
            *(bf16x8*)&w0hhL[wl + (u * 8 + kc) * 512] = f;
        }

    const float brz0a = bf2f(b0ih[c])       + bf2f(b0hh[c]);
    const float brz0b = bf2f(b0ih[256 + c]) + bf2f(b0hh[256 + c]);
    const float bni0v = bf2f(b0ih[512 + c]);
    const float bnh0v = bf2f(b0hh[512 + c]);
    const float brz1a = bf2f(b1ih[c])       + bf2f(b1hh[c]);
    const float brz1b = bf2f(b1ih[256 + c]) + bf2f(b1hh[256 + c]);
    const float bni1v = bf2f(b1ih[512 + c]);
    const float bnh1v = bf2f(b1hh[512 + c]);
    __syncthreads();

    float h0r[4] = {0.f, 0.f, 0.f, 0.f};
    float h1r[4] = {0.f, 0.f, 0.f, 0.f};

    const size_t xrow = (size_t)(m0 + l15) * (T_ * IN_) + quad * 8;
    const unsigned short* pxb = (const unsigned short*)xv + xrow;
    const float*          pxf = (const float*)xv + xrow;

    unsigned int* sq = seq + g * 32;
    const int wr_row[4] = {(quad * 4 + 0) * 256 + c, (quad * 4 + 1) * 256 + c,
                           (quad * 4 + 2) * 256 + c, (quad * 4 + 3) * 256 + c};

    const f32x4 z4 = {0.f, 0.f, 0.f, 0.f};
    bf16x8 h0A[8], h1A[8];
    #pragma unroll
    for (int kc = 0; kc < 8; ++kc){
        h0A[kc] = (bf16x8)(short)0;
        h1A[kc] = (bf16x8)(short)0;
    }

    #pragma unroll 1
    for (int t = 0; t < T_; ++t){
        const int par = t & 1;
        const unsigned int tgt = 4u * (unsigned)(t + 1);
        unsigned short* plane = hb + par * PL_ + g * (2 * 4096);

        #pragma unroll
        for (int j = 0; j < 4; ++j)
            __hip_atomic_store(&plane[4096 + wr_row[j]], f2bf(h1r[j]),
                               __ATOMIC_RELAXED, __HIP_MEMORY_SCOPE_AGENT);

        bf16x8 ax[4];
        if (isb){
            #pragma unroll
            for (int kc = 0; kc < 4; ++kc) ax[kc] = ldb8g(pxb + t * IN_ + kc * 32);
        } else {
            #pragma unroll
            for (int kc = 0; kc < 4; ++kc){
                const float* p = pxf + t * IN_ + kc * 32;
                const float4 f0 = *(const float4*)p;
                const float4 f1 = *(const float4*)(p + 4);
                bf16x8 a;
                a[0] = (short)f2bf(f0.x); a[1] = (short)f2bf(f0.y);
                a[2] = (short)f2bf(f0.z); a[3] = (short)f2bf(f0.w);
                a[4] = (short)f2bf(f1.x); a[5] = (short)f2bf(f1.y);
                a[6] = (short)f2bf(f1.z); a[7] = (short)f2bf(f1.w);
                ax[kc] = a;
            }
        }

        f32x4 Tr = z4, Tz = z4, Tni = z4, Tnh = z4;
        #pragma unroll
        for (int kc = 0; kc < 4; ++kc){
            Tr  = MFMA16(ax[kc], w0ihr[0][kc], Tr);
            Tz  = MFMA16(ax[kc], w0ihr[1][kc], Tz);
            Tni = MFMA16(ax[kc], w0ihr[2][kc], Tni);
        }
        #pragma unroll
        for (int kc = 0; kc < 8; ++kc){
            const bf16x8 a = h0A[kc];
            Tr  = MFMA16(a, *(const bf16x8*)&w0hhL[wl + (0 * 8 + kc) * 512], Tr);
            Tz  = MFMA16(a, *(const bf16x8*)&w0hhL[wl + (1 * 8 + kc) * 512], Tz);
            Tnh = MFMA16(a, *(const bf16x8*)&w0hhL[wl + (2 * 8 + kc) * 512], Tnh);
        }
        #pragma unroll
        for (int j = 0; j < 4; ++j){
            const float rr = sig_(Tr[j] + brz0a);
            const float zz = sig_(Tz[j] + brz0b);
            const float nn = tanh_(Tni[j] + bni0v + rr * (Tnh[j] + bnh0v));
            h0r[j] = (1.0f - zz) * nn + zz * h0r[j];
        }

        #pragma unroll
        for (int j = 0; j < 4; ++j)
            __hip_atomic_store(&plane[wr_row[j]], f2bf(h0r[j]),
                               __ATOMIC_RELAXED, __HIP_MEMORY_SCOPE_AGENT);

        __syncthreads();
        if (tid == 0)
            __hip_atomic_fetch_add(sq, 1u, __ATOMIC_RELAXED, __HIP_MEMORY_SCOPE_AGENT);
        if (lane == 0){
            while (__hip_atomic_load(sq, __ATOMIC_RELAXED, __HIP_MEMORY_SCOPE_AGENT) < tgt)
                __builtin_amdgcn_s_sleep(1);
        }
        __atomic_signal_fence(__ATOMIC_ACQ_REL);

        {
            const unsigned short* r0 = plane + l15 * 256 + quad * 8;
            #pragma unroll
            for (int kc = 0; kc < 8; ++kc){
                U64x2 u0, u1;
                u0.q[0] = __hip_atomic_load((const unsigned long long*)(r0 + kc * 32),
                                            __ATOMIC_RELAXED, __HIP_MEMORY_SCOPE_AGENT);
                u0.q[1] = __hip_atomic_load((const unsigned long long*)(r0 + kc * 32 + 4),
                                            __ATOMIC_RELAXED, __HIP_MEMORY_SCOPE_AGENT);
                u1.q[0] = __hip_atomic_load((const unsigned long long*)(r0 + 4096 + kc * 32),
                                            __ATOMIC_RELAXED, __HIP_MEMORY_SCOPE_AGENT);
                u1.q[1] = __hip_atomic_load((const unsigned long long*)(r0 + 4096 + kc * 32 + 4),
                                            __ATOMIC_RELAXED, __HIP_MEMORY_SCOPE_AGENT);
                h0A[kc] = u0.v;
                h1A[kc] = u1.v;
            }
        }

        Tr = z4; Tz = z4; Tni = z4; Tnh = z4;
        #pragma unroll
        for (int kc = 0; kc < 8; ++kc){
            const bf16x8 a0 = h0A[kc];
            const bf16x8 a1 = h1A[kc];
            Tr  = MFMA16(a0, w1ihr[0][kc], Tr);
            Tr  = MFMA16(a1, w1hhr[0][kc], Tr);
            Tz  = MFMA16(a0, w1ihr[1][kc], Tz);
            Tz  = MFMA16(a1, w1hhr[1][kc], Tz);
            Tni = MFMA16(a0, w1ihr[2][kc], Tni);
            Tnh = MFMA16(a1, w1hhr[2][kc], Tnh);
        }
        #pragma unroll
        for (int j = 0; j < 4; ++j){
            const float rr = sig_(Tr[j] + brz1a);
            const float zz = sig_(Tz[j] + brz1b);
            const float nn = tanh_(Tni[j] + bni1v + rr * (Tnh[j] + bnh1v));
            h1r[j] = (1.0f - zz) * nn + zz * h1r[j];
        }
    }

    #pragma unroll
    for (int j = 0; j < 4; ++j)
        s_out[(size_t)(m0 + quad * 4 + j) * H_ + c] = h1r[j];
}

// ---------------------------------------------------------------------------
// B-spline basis (uniform grid, GRID_SIZE=5, ORDER=3)
// ---------------------------------------------------------------------------
__device__ __forceinline__ float knot_(int p){ return (float)(p - 3) * 0.4f - 1.0f; }

__device__ __forceinline__ void bspline8(float xv, float* bb8){
    float bb[11];
    #pragma unroll
    for (int p = 0; p < 11; ++p)
        bb[p] = (xv >= knot_(p) && xv < knot_(p + 1)) ? 1.f : 0.f;
    #pragma unroll
    for (int k = 1; k <= 3; ++k){
        #pragma unroll
        for (int p = 0; p <= 10 - k; ++p){
            const float tp = knot_(p), tpk = knot_(p + k);
            const float tp1 = knot_(p + 1), tpk1 = knot_(p + k + 1);
            bb[p] = (xv - tp) / (tpk - tp) * bb[p] + (tpk1 - xv) / (tpk1 - tp1) * bb[p + 1];
        }
    }
    #pragma unroll
    for (int j = 0; j < 8; ++j) bb8[j] = bb[j];
}

// partial LSTM dots over k in [k0, k0+64) for 3 gates (i,g,o) of unit uu
__device__ __forceinline__ void lstm_part(const float* sxv, const unsigned short* w,
                                          int uu, int k0, float* out3){
    const unsigned short* wi = w + (size_t)uu * 256 + k0;
    const unsigned short* wg = w + (size_t)(256 + uu) * 256 + k0;
    const unsigned short* wo = w + (size_t)(384 + uu) * 256 + k0;
    float ai = 0.f, ag = 0.f, ao = 0.f;
    for (int k = 0; k < 64; k += 8){
        const bf16x8 vi = ldb8g(wi + k);
        const bf16x8 vg = ldb8g(wg + k);
        const bf16x8 vo = ldb8g(wo + k);
        #pragma unroll
        for (int j = 0; j < 8; ++j){
            const float s = sxv[k0 + k + j];
            ai += bf2f((unsigned short)vi[j]) * s;
            ag += bf2f((unsigned short)vg[j]) * s;
            ao += bf2f((unsigned short)vo[j]) * s;
        }
    }
    out3[0] = ai; out3[1] = ag; out3[2] = ao;
}

// ---------------------------------------------------------------------------
// Fused tail v2: 1024 threads, 4-way k-split LSTMs + 16-way KAN splits.
// grid = 512 (one block per batch row).
// ---------------------------------------------------------------------------
__global__ __launch_bounds__(1024) void srt_tail(
    const float* __restrict__ in,
    const unsigned short* __restrict__ w0f, const unsigned short* __restrict__ bi0f,
    const unsigned short* __restrict__ bh0f,
    const unsigned short* __restrict__ w0r, const unsigned short* __restrict__ bi0r,
    const unsigned short* __restrict__ bh0r,
    const unsigned short* __restrict__ w1f, const unsigned short* __restrict__ bi1f,
    const unsigned short* __restrict__ bh1f,
    const unsigned short* __restrict__ w1r, const unsigned short* __restrict__ bi1r,
    const unsigned short* __restrict__ bh1r,
    const unsigned short* __restrict__ k1b, const unsigned short* __restrict__ k1s,
    const unsigned short* __restrict__ k1c,
    const unsigned short* __restrict__ k2b, const unsigned short* __restrict__ k2s,
    const unsigned short* __restrict__ k2c,
    void* __restrict__ outp,
    const unsigned int* __restrict__ flagp)
{
    __shared__ float sx[256];
    __shared__ float sy[256];
    __shared__ float part[4][256][3];      // 12 KB
    __shared__ float sil[256];
    __shared__ float spl[256][8];
    __shared__ float red16[64][16];        // 4 KB
    __shared__ float sil2[64];
    __shared__ float spl2[64][8];
    __shared__ float red2[10][16];

    const int b = blockIdx.x, tid = threadIdx.x;
    const int qr = tid >> 8, sub = tid & 255;
    const int dir = sub >> 7, uu = sub & 127;

    if (tid < 256) sx[tid] = in[b * 256 + tid];
    __syncthreads();

    // ---- layer 0 (4-way k split)
    float p3[3];
    lstm_part(sx, dir ? w0r : w0f, uu, qr * 64, p3);
    part[qr][sub][0] = p3[0]; part[qr][sub][1] = p3[1]; part[qr][sub][2] = p3[2];
    __syncthreads();
    if (tid < 256){
        const unsigned short* bi = dir ? bi0r : bi0f;
        const unsigned short* bh = dir ? bh0r : bh0f;
        const float ai = part[0][sub][0] + part[1][sub][0] + part[2][sub][0] + part[3][sub][0];
        const float ag = part[0][sub][1] + part[1][sub][1] + part[2][sub][1] + part[3][sub][1];
        const float ao = part[0][sub][2] + part[1][sub][2] + part[2][sub][2] + part[3][sub][2];
        const float gi = ai + bf2f(bi[uu])       + bf2f(bh[uu]);
        const float gg = ag + bf2f(bi[256 + uu]) + bf2f(bh[256 + uu]);
        const float go = ao + bf2f(bi[384 + uu]) + bf2f(bh[384 + uu]);
        sy[sub] = sig_(go) * tanh_(sig_(gi) * tanh_(gg));
    }
    __syncthreads();

    // ---- layer 1
    lstm_part(sy, dir ? w1r : w1f, uu, qr * 64, p3);
    part[qr][sub][0] = p3[0]; part[qr][sub][1] = p3[1]; part[qr][sub][2] = p3[2];
    __syncthreads();
    if (tid < 256){
        const unsigned short* bi = dir ? bi1r : bi1f;
        const unsigned short* bh = dir ? bh1r : bh1f;
        const float ai = part[0][sub][0] + part[1][sub][0] + part[2][sub][0] + part[3][sub][0];
        const float ag = part[0][sub][1] + part[1][sub][1] + part[2][sub][1] + part[3][sub][1];
        const float ao = part[0][sub][2] + part[1][sub][2] + part[2][sub][2] + part[3][sub][2];
        const float gi = ai + bf2f(bi[uu])       + bf2f(bh[uu]);
        const float gg = ag + bf2f(bi[256 + uu]) + bf2f(bh[256 + uu]);
        const float go = ao + bf2f(bi[384 + uu]) + bf2f(bh[384 + uu]);
        const float o1v = sig_(go) * tanh_(sig_(gi) * tanh_(gg));
        sil[sub] = o1v * sig_(o1v);
        float bb[8];
        bspline8(o1v, bb);
        #pragma unroll
        for (int j = 0; j < 8; ++j) spl[sub][j] = bb[j];
    }
    __syncthreads();

    // ---- kan1: 64 outputs x 16 k-slices (16 k each)
    {
        const int o = tid >> 4, q16 = tid & 15;
        float acc = 0.f;
        for (int k = q16 * 16; k < q16 * 16 + 16; ++k){
            acc += sil[k] * bf2f(k1b[o * 256 + k]);
            float t = 0.f;
            #pragma unroll
            for (int j = 0; j < 8; ++j) t += spl[k][j] * bf2f(k1s[(o * 256 + k) * 8 + j]);
            acc += t * bf2f(k1c[o * 256 + k]);
        }
        red16[o][q16] = acc;
    }
    __syncthreads();
    if (tid < 64){
        float zv = 0.f;
        #pragma unroll
        for (int i = 0; i < 16; ++i) zv += red16[tid][i];
        sil2[tid] = zv * sig_(zv);
        float b2[8];
        bspline8(zv, b2);
        #pragma unroll
        for (int j = 0; j < 8; ++j) spl2[tid][j] = b2[j];
    }
    __syncthreads();

    // ---- kan2: 10 outputs x 16 k-slices (4 k each)
    if (tid < 160){
        const int o2 = tid >> 4, q = tid & 15;
        float a2 = 0.f;
        for (int k = q * 4; k < q * 4 + 4; ++k){
            a2 += sil2[k] * bf2f(k2b[o2 * 64 + k]);
            float t = 0.f;
            #pragma unroll
            for (int j = 0; j < 8; ++j) t += spl2[k][j] * bf2f(k2s[(o2 * 64 + k) * 8 + j]);
            a2 += t * bf2f(k2c[o2 * 64 + k]);
        }
        red2[o2][q] = a2;
    }
    __syncthreads();
    if (tid < 10){
        float a2 = 0.f;
        #pragma unroll
        for (int i = 0; i < 16; ++i) a2 += red2[tid][i];
        if (*flagp) ((unsigned short*)outp)[b * 10 + tid] = f2bf(a2);
        else        ((float*)outp)[b * 10 + tid] = a2;
    }
}

extern "C" void kernel_launch(void* const* d_in, const int* in_sizes, int n_in,
                              void* d_out, int out_size, void* d_ws, size_t ws_size,
                              hipStream_t stream)
{
    unsigned int* flag = (unsigned int*)d_ws;
    float* s = (float*)((char*)d_ws + 16);            // final h1 (fp32)
    unsigned short* wb = (unsigned short*)(s + 512 * 256);

    const int idxs[26] = {1,2,3,4,5,6,7,8, 9,11,12, 13,15,16, 17,19,20, 21,23,24,
                          25,26,27, 28,29,30};
    ConvTab ct;
    int off = 0;
    int offs[26];
    for (int j = 0; j < 26; ++j){
        ct.src[j] = d_in[idxs[j]];
        ct.n[j]   = in_sizes[idxs[j]];
        ct.off[j] = off;
        offs[j]   = off;
        off += in_sizes[idxs[j]];
    }
    uintptr_t p = (uintptr_t)(wb + off);
    p = (p + 255) & ~(uintptr_t)255;
    unsigned int* seq = (unsigned int*)p;                 // fallback counters
    unsigned short* hb = (unsigned short*)(seq + 1024);   // fallback exchange buf
    p = (uintptr_t)(hb + 2 * 32 * 2 * 4096);
    p = (p + 255) & ~(uintptr_t)255;
    float* h0s   = (float*)p;                             // 512*256 fp32 layer-0 state
    float* bias0 = h0s + 512 * 256;
    float* bias1 = bias0 + 768;
    p = (uintptr_t)(bias1 + 768);
    p = (p + 255) & ~(uintptr_t)255;
    char* dyn = (char*)p;
    const size_t used = (size_t)(dyn - (char*)d_ws);

    const size_t slab_gi = (size_t)TCp * 512 * 768;   // shorts
    const size_t slab_ha = (size_t)TCp * 512 * 256;
    const size_t pipe_need = used + (4 * slab_gi + 2 * slab_ha) * sizeof(unsigned short);
    const bool pipe_ok = pipe_need <= ws_size;

    const unsigned short *w0ih = wb + offs[0],  *w0hh = wb + offs[1];
    const unsigned short *b0ih = wb + offs[2],  *b0hh = wb + offs[3];
    const unsigned short *w1ih = wb + offs[4],  *w1hh = wb + offs[5];
    const unsigned short *b1ih = wb + offs[6],  *b1hh = wb + offs[7];
    const unsigned short *lwih0  = wb + offs[8],  *lbih0  = wb + offs[9],  *lbhh0  = wb + offs[10];
    const unsigned short *lwih0r = wb + offs[11], *lbih0r = wb + offs[12], *lbhh0r = wb + offs[13];
    const unsigned short *lwih1  = wb + offs[14], *lbih1  = wb + offs[15], *lbhh1  = wb + offs[16];
    const unsigned short *lwih1r = wb + offs[17], *lbih1r = wb + offs[18], *lbhh1r = wb + offs[19];
    const unsigned short *k1b = wb + offs[20], *k1s = wb + offs[21], *k1c = wb + offs[22];
    const unsigned short *k2b = wb + offs[23], *k2s = wb + offs[24], *k2c = wb + offs[25];

    srt_detect<<<1, 64, 0, stream>>>((const unsigned int*)d_in[0], flag);
    srt_conv<<<1024, 256, 0, stream>>>(ct, wb, flag);
    srt_prep<<<512, 256, 0, stream>>>(h0s, s, bias0, bias1, b0ih, b0hh, b1ih, b1hh, seq);

    if (pipe_ok){
        unsigned short* gi0a = (unsigned short*)dyn;
        unsigned short* gi0b = gi0a + slab_gi;
        unsigned short* haa  = gi0b + slab_gi;
        unsigned short* hab  = haa + slab_ha;
        unsigned short* gi1a = hab + slab_ha;
        unsigned short* gi1b = gi1a + slab_gi;

        PA a;
        a.xv = d_in[0]; a.flag = flag;
        a.w0ih = w0ih; a.w0hh = w0hh; a.b0hh = b0hh;
        a.w1ih = w1ih; a.w1hh = w1hh; a.b1hh = b1hh;
        a.bias0 = bias0; a.bias1 = bias1;
        a.h0s = h0s; a.h1s = s;
        a.gi0a = gi0a; a.gi0b = gi0b; a.haa = haa; a.hab = hab;
        a.gi1a = gi1a; a.gi1b = gi1b;
        for (int ph = 0; ph <= NCp + 2; ++ph){
            a.p = ph;
            srt_phase<<<576, 512, 0, stream>>>(a);
        }
    } else {
        srt_gru<<<128, 256, 0, stream>>>(d_in[0], w0ih, w0hh, b0ih, b0hh,
                                         w1ih, w1hh, b1ih, b1hh, s, flag, seq, hb);
    }

    srt_tail<<<512, 1024, 0, stream>>>(s,
        lwih0, lbih0, lbhh0, lwih0r, lbih0r, lbhh0r,
        lwih1, lbih1, lbhh1, lwih1r, lbih1r, lbhh1r,
        k1b, k1s, k1c, k2b, k2s, k2c, d_out, flag);
}